// Round 2
// 1952.402 us; speedup vs baseline: 1.0002x; 1.0002x over previous
//
#include <hip/hip_runtime.h>
#include <hip/hip_bf16.h>
#include <math.h>

#define B 2

__device__ __forceinline__ float toF(float x) { return x; }
__device__ __forceinline__ float toF(__hip_bfloat16 x) { return __bfloat162float(x); }
__device__ __forceinline__ void stF(float* p, float v) { *p = v; }
__device__ __forceinline__ void stF(__hip_bfloat16* p, float v) { *p = __float2bfloat16(v); }

typedef __attribute__((ext_vector_type(8))) short bf16x8;
typedef __attribute__((ext_vector_type(4))) float f32x4;

// ---------------- dtype probe: flag=1 if buffer is bf16, 0 if f32 ----------------
__global__ void probe_kernel(const unsigned short* __restrict__ x, int* __restrict__ flag) {
  if (threadIdx.x == 0 && blockIdx.x == 0) {
    int sane = 0;
    for (int i = 0; i < 512; ++i) {
      int e = (x[i] >> 7) & 0xFF;
      if (e >= 97 && e <= 157) ++sane;
    }
    flag[0] = (sane >= 480) ? 1 : 0;
  }
}

// ---------------- conv5 (f32 fallback): 3x3 conv split-K scalar path ----------------
template <typename TP>
__global__ __launch_bounds__(256) void conv5_kernel(
    const TP* __restrict__ c4, const TP* __restrict__ w,
    float* __restrict__ part, const int* __restrict__ flag, int want)
{
  if (flag[0] != want) return;
  const int ks  = blockIdx.x;
  const int oc0 = blockIdx.y * 4;
  const int n   = blockIdx.z;
  const int tid = threadIdx.x;
  const int x = tid & 15, y = tid >> 4;

  __shared__ float xs[8][18][18];
  __shared__ float wt[4][8][9];

  float* xsf = &xs[0][0][0];
  for (int i = tid; i < 8 * 18 * 18; i += 256) xsf[i] = 0.f;

  float acc[4] = {0.f, 0.f, 0.f, 0.f};
  __syncthreads();

  for (int cc = 0; cc < 64; ++cc) {
    const int c0 = ks * 512 + cc * 8;
#pragma unroll
    for (int i = 0; i < 8; ++i)
      xs[i][1 + y][1 + x] = toF(c4[(((size_t)n * 2048 + c0 + i) << 8) + tid]);
    for (int e = tid; e < 288; e += 256) {
      int o = e / 72, r = e % 72, i = r / 9, kk = r % 9;
      wt[o][i][kk] = toF(w[((size_t)(oc0 + o) * 2048 + (c0 + i)) * 9 + kk]);
    }
    __syncthreads();
#pragma unroll
    for (int i = 0; i < 8; ++i) {
      float t0 = xs[i][y    ][x], t1 = xs[i][y    ][x + 1], t2 = xs[i][y    ][x + 2];
      float t3 = xs[i][y + 1][x], t4 = xs[i][y + 1][x + 1], t5 = xs[i][y + 1][x + 2];
      float t6 = xs[i][y + 2][x], t7 = xs[i][y + 2][x + 1], t8 = xs[i][y + 2][x + 2];
#pragma unroll
      for (int o = 0; o < 4; ++o) {
        acc[o] = fmaf(t0, wt[o][i][0], acc[o]);
        acc[o] = fmaf(t1, wt[o][i][1], acc[o]);
        acc[o] = fmaf(t2, wt[o][i][2], acc[o]);
        acc[o] = fmaf(t3, wt[o][i][3], acc[o]);
        acc[o] = fmaf(t4, wt[o][i][4], acc[o]);
        acc[o] = fmaf(t5, wt[o][i][5], acc[o]);
        acc[o] = fmaf(t6, wt[o][i][6], acc[o]);
        acc[o] = fmaf(t7, wt[o][i][7], acc[o]);
        acc[o] = fmaf(t8, wt[o][i][8], acc[o]);
      }
    }
    __syncthreads();
  }
#pragma unroll
  for (int o = 0; o < 4; ++o)
    part[(size_t)ks * 262144 + ((size_t)n * 512 + oc0 + o) * 256 + tid] = acc[o];
}

// ---------------- conv5 bf16 path: im2col + MFMA GEMM ----------------
// Xcol[r = n*256+px][K = c*9 + ky*3 + kx], 512 x 18432 bf16 (raw ushort).
__global__ __launch_bounds__(256) void im2col_kernel(
    const unsigned short* __restrict__ c4, unsigned short* __restrict__ xcol,
    const int* __restrict__ flag, int want)
{
  if (flag[0] != want) return;
  int idx = blockIdx.x * 256 + threadIdx.x;       // 512*18432 = 9437184 total
  if (idx >= 512 * 18432) return;
  int K = idx % 18432;
  int r = idx / 18432;
  int c = K / 9, t = K % 9;
  int n = r >> 8, px = r & 255;
  int x = px & 15, y = px >> 4;
  int yy = y + (t / 3) - 1, xx = x + (t % 3) - 1;  // 3x3, pad 1, dilation 1
  unsigned short v = 0;
  if (yy >= 0 && yy < 16 && xx >= 0 && xx < 16)
    v = c4[(((size_t)n * 2048 + c) << 8) + yy * 16 + xx];
  xcol[idx] = v;
}

// LDS XOR swizzle (G4 recipe): permute 16B slots within each 128B row.
__device__ __forceinline__ int swz(int b) { return b ^ (((b >> 7) & 7) << 4); }

// GEMM: C[oc][r] = sum_K W[oc][K] * Xcol[r][K]. M=N=512, K=18432.
// 64x64 tiles, BK=64, split-K=4 -> part[ks] (reuses finalize5).
__global__ __launch_bounds__(256) void conv5_mfma_kernel(
    const unsigned short* __restrict__ W, const unsigned short* __restrict__ Xcol,
    float* __restrict__ part, const int* __restrict__ flag, int want)
{
  if (flag[0] != want) return;
  const int tile = blockIdx.x;            // 0..63 over 8x8 tiles
  const int ks   = blockIdx.y;            // 0..3 split-K
  const int mo = (tile >> 3) * 64;        // oc tile base
  const int no = (tile & 7) * 64;         // r tile base
  const int k0 = ks * 4608;
  const int tid = threadIdx.x;
  const int w = tid >> 6, lane = tid & 63;
  const int wr = w >> 1, wc = w & 1;      // 2x2 wave grid, each wave 32x32 out

  __shared__ unsigned short As[64 * 64];  // 8 KB, [row][64 K] swizzled
  __shared__ unsigned short Bs[64 * 64];  // 8 KB

  // staging map: thread -> (row, 16B slot); covers rows row0 and row0+32
  const int row0 = tid >> 3, slot = tid & 7;
  const unsigned short* pa0 = W    + (size_t)(mo + row0) * 18432 + k0 + slot * 8;
  const unsigned short* pa1 = pa0  + (size_t)32 * 18432;
  const unsigned short* pb0 = Xcol + (size_t)(no + row0) * 18432 + k0 + slot * 8;
  const unsigned short* pb1 = pb0  + (size_t)32 * 18432;
  const int wa0 = swz(row0 * 128 + slot * 16);
  const int wa1 = swz((row0 + 32) * 128 + slot * 16);

  f32x4 acc[2][2];
#pragma unroll
  for (int m = 0; m < 2; ++m)
#pragma unroll
    for (int nn = 0; nn < 2; ++nn) acc[m][nn] = (f32x4){0.f, 0.f, 0.f, 0.f};

  // prefetch first BK
  bf16x8 ra0 = *(const bf16x8*)pa0;
  bf16x8 ra1 = *(const bf16x8*)pa1;
  bf16x8 rb0 = *(const bf16x8*)pb0;
  bf16x8 rb1 = *(const bf16x8*)pb1;

  const int arow = wr * 32 + (lane & 15);
  const int brow = wc * 32 + (lane & 15);
  const int cb = (lane >> 4) * 16;        // 16B column offset within K-step

  for (int kk = 0; kk < 4608; kk += 64) {
    // write staged regs to LDS (swizzled)
    *(bf16x8*)((char*)As + wa0) = ra0;
    *(bf16x8*)((char*)As + wa1) = ra1;
    *(bf16x8*)((char*)Bs + wa0) = rb0;
    *(bf16x8*)((char*)Bs + wa1) = rb1;
    // issue next-BK global loads early; they fly under the MFMA phase
    if (kk + 64 < 4608) {
      ra0 = *(const bf16x8*)(pa0 + kk + 64);
      ra1 = *(const bf16x8*)(pa1 + kk + 64);
      rb0 = *(const bf16x8*)(pb0 + kk + 64);
      rb1 = *(const bf16x8*)(pb1 + kk + 64);
    }
    __syncthreads();
#pragma unroll
    for (int ks2 = 0; ks2 < 2; ++ks2) {
      const int colb = ks2 * 64 + cb;
      bf16x8 af[2], bfv[2];
#pragma unroll
      for (int m = 0; m < 2; ++m)
        af[m] = *(const bf16x8*)((char*)As + swz((arow + m * 16) * 128 + colb));
#pragma unroll
      for (int nn = 0; nn < 2; ++nn)
        bfv[nn] = *(const bf16x8*)((char*)Bs + swz((brow + nn * 16) * 128 + colb));
#pragma unroll
      for (int m = 0; m < 2; ++m)
#pragma unroll
        for (int nn = 0; nn < 2; ++nn)
          acc[m][nn] = __builtin_amdgcn_mfma_f32_16x16x32_bf16(af[m], bfv[nn], acc[m][nn], 0, 0, 0);
    }
    __syncthreads();
  }

  // C/D layout: col = lane&15 (-> r), row = (lane>>4)*4 + j (-> oc)
#pragma unroll
  for (int m = 0; m < 2; ++m)
#pragma unroll
    for (int nn = 0; nn < 2; ++nn) {
      const int r = no + wc * 32 + nn * 16 + (lane & 15);
      const int n = r >> 8, px = r & 255;
#pragma unroll
      for (int j = 0; j < 4; ++j) {
        const int oc = mo + wr * 32 + m * 16 + (lane >> 4) * 4 + j;
        part[(size_t)ks * 262144 + ((size_t)n * 512 + oc) * 256 + px] = acc[m][nn][j];
      }
    }
}

template <typename TP>
__global__ __launch_bounds__(256) void finalize5_kernel(
    const float* __restrict__ part, const TP* __restrict__ bn,
    float* __restrict__ t5, const int* __restrict__ flag, int want)
{
  if (flag[0] != want) return;
  int idx = blockIdx.x * 256 + threadIdx.x;   // 262144 total
  int oc = (idx >> 8) & 511;
  float s = part[idx] + part[idx + 262144] + part[idx + 2 * 262144] + part[idx + 3 * 262144];
  float g = toF(bn[oc]), b = toF(bn[512 + oc]), m = toF(bn[1024 + oc]), v = toF(bn[1536 + oc]);
  float sc = g * rsqrtf(v + 1e-5f);
  float val = s * sc + (b - m * sc);
  t5[idx] = fmaxf(val, 0.f);
}

// ---------------- generic 1x1 conv (+optional BN) ----------------
template <typename TX, typename TP>
__global__ __launch_bounds__(256) void conv1x1_kernel(
    const TX* __restrict__ X, const TP* __restrict__ Wm,
    const TP* __restrict__ bn,
    float* __restrict__ Y, int C, int O, int S,
    const int* __restrict__ flag, int want)
{
  if (flag[0] != want) return;
  const int tid = threadIdx.x;
  const int sg = tid & 15, og = tid >> 4;
  const int s0 = blockIdx.x * 64;
  const int o0 = blockIdx.y * 64;
  const int n  = blockIdx.z;

  __shared__ float xs[16][64];
  __shared__ float wsT[16][68];

  float acc[4][4];
#pragma unroll
  for (int i = 0; i < 4; ++i)
#pragma unroll
    for (int j = 0; j < 4; ++j) acc[i][j] = 0.f;

  for (int c0 = 0; c0 < C; c0 += 16) {
#pragma unroll
    for (int r = 0; r < 4; ++r) {
      int e = tid + r * 256, cc = e >> 6, ssv = e & 63;
      xs[cc][ssv] = toF(X[((size_t)n * C + c0 + cc) * S + s0 + ssv]);
    }
#pragma unroll
    for (int r = 0; r < 4; ++r) {
      int e = tid + r * 256, oo = e >> 4, cc = e & 15;
      int o = o0 + oo;
      wsT[cc][oo] = (o < O) ? toF(Wm[(size_t)o * C + c0 + cc]) : 0.f;
    }
    __syncthreads();
#pragma unroll
    for (int c = 0; c < 16; ++c) {
      const float4 xv = *(const float4*)&xs[c][sg * 4];
      const float4 wv = *(const float4*)&wsT[c][og * 4];
      acc[0][0] = fmaf(wv.x, xv.x, acc[0][0]);
      acc[0][1] = fmaf(wv.x, xv.y, acc[0][1]);
      acc[0][2] = fmaf(wv.x, xv.z, acc[0][2]);
      acc[0][3] = fmaf(wv.x, xv.w, acc[0][3]);
      acc[1][0] = fmaf(wv.y, xv.x, acc[1][0]);
      acc[1][1] = fmaf(wv.y, xv.y, acc[1][1]);
      acc[1][2] = fmaf(wv.y, xv.z, acc[1][2]);
      acc[1][3] = fmaf(wv.y, xv.w, acc[1][3]);
      acc[2][0] = fmaf(wv.z, xv.x, acc[2][0]);
      acc[2][1] = fmaf(wv.z, xv.y, acc[2][1]);
      acc[2][2] = fmaf(wv.z, xv.z, acc[2][2]);
      acc[2][3] = fmaf(wv.z, xv.w, acc[2][3]);
      acc[3][0] = fmaf(wv.w, xv.x, acc[3][0]);
      acc[3][1] = fmaf(wv.w, xv.y, acc[3][1]);
      acc[3][2] = fmaf(wv.w, xv.z, acc[3][2]);
      acc[3][3] = fmaf(wv.w, xv.w, acc[3][3]);
    }
    __syncthreads();
  }

#pragma unroll
  for (int i = 0; i < 4; ++i) {
    int o = o0 + og * 4 + i;
    if (o < O) {
      float sc = 1.f, sh = 0.f;
      if (bn) {
        float g = toF(bn[o]), bb = toF(bn[O + o]), m = toF(bn[2 * O + o]), v = toF(bn[3 * O + o]);
        sc = g * rsqrtf(v + 1e-5f);
        sh = bb - m * sc;
      }
      float4 r;
      r.x = acc[i][0] * sc + sh;
      r.y = acc[i][1] * sc + sh;
      r.z = acc[i][2] * sc + sh;
      r.w = acc[i][3] * sc + sh;
      *(float4*)(Y + ((size_t)n * O + o) * S + s0 + sg * 4) = r;
    }
  }
}

// ---------------- bilinear 2x upsample, align_corners=True (fp32 intermediates) ------
__global__ __launch_bounds__(256) void upsample2x_kernel(
    const float* __restrict__ in, float* __restrict__ out,
    int h, int w, int total)
{
  int idx = blockIdx.x * 256 + threadIdx.x;
  if (idx >= total) return;
  const int Wd = 2 * w, Hd = 2 * h;
  int xo = idx % Wd;
  int t  = idx / Wd;
  int yo = t % Hd;
  int pl = t / Hd;
  const float rh = (float)(h - 1) / (float)(Hd - 1);
  const float rw = (float)(w - 1) / (float)(Wd - 1);
  float fy = yo * rh, fx = xo * rw;
  int y0 = (int)fy; if (y0 > h - 1) y0 = h - 1;
  int x0 = (int)fx; if (x0 > w - 1) x0 = w - 1;
  int y1 = min(y0 + 1, h - 1), x1 = min(x0 + 1, w - 1);
  float wy = fy - y0, wx = fx - x0;
  const float* p = in + (size_t)pl * h * w;
  float v00 = p[y0 * w + x0], v01 = p[y0 * w + x1];
  float v10 = p[y1 * w + x0], v11 = p[y1 * w + x1];
  out[idx] = (v00 * (1.f - wy) + v10 * wy) * (1.f - wx) +
             (v01 * (1.f - wy) + v11 * wy) * wx;
}

// ---------------- 9-tap local attention logits + softmax ----------------
__global__ __launch_bounds__(256) void att_kernel(
    const float* __restrict__ q, const float* __restrict__ k,
    float* __restrict__ att, int kd, int H, int Wd, int total)
{
  int idx = blockIdx.x * 256 + threadIdx.x;
  if (idx >= total) return;
  const int S = H * Wd;
  int p = idx % S, n = idx / S;
  int x = p % Wd, y = p / Wd;
  int off[9]; bool ok[9];
#pragma unroll
  for (int j = 0; j < 9; ++j) {
    int dy = (j / 3) * 2 - 2, dx = (j % 3) * 2 - 2;
    int yy = y + dy, xx = x + dx;
    ok[j] = (yy >= 0 && yy < H && xx >= 0 && xx < Wd);
    off[j] = yy * Wd + xx;
  }
  float dot[9] = {0.f,0.f,0.f,0.f,0.f,0.f,0.f,0.f,0.f};
  const float* qp = q + (size_t)n * kd * S + p;
  const float* kp = k + (size_t)n * kd * S;
  for (int c = 0; c < kd; ++c) {
    float qv = qp[(size_t)c * S];
    const float* kc = kp + (size_t)c * S;
#pragma unroll
    for (int j = 0; j < 9; ++j)
      if (ok[j]) dot[j] = fmaf(qv, kc[off[j]], dot[j]);
  }
  float m = dot[0];
#pragma unroll
  for (int j = 1; j < 9; ++j) m = fmaxf(m, dot[j]);
  float e[9], ssum = 0.f;
#pragma unroll
  for (int j = 0; j < 9; ++j) { e[j] = __expf(dot[j] - m); ssum += e[j]; }
  float inv = 1.f / ssum;
#pragma unroll
  for (int j = 0; j < 9; ++j)
    att[((size_t)n * 9 + j) * S + p] = e[j] * inv;
}

// -------- fused: out[n,c,p] = sum_j att[n,j,p] * bilerp(prev[n,c], tap_j(p)) --------
__global__ __launch_bounds__(256) void apply_up_kernel(
    const float* __restrict__ att, const float* __restrict__ prev,
    float* __restrict__ out, int C, int H, int Wd, int h2, int w2, int total)
{
  int idx = blockIdx.x * 256 + threadIdx.x;
  if (idx >= total) return;
  const int S = H * Wd;
  int p = idx % S;
  int t = idx / S;
  int c = t % C, n = t / C;
  int x = p % Wd, y = p / Wd;
  const float rh = (float)(h2 - 1) / (float)(H - 1);
  const float rw = (float)(w2 - 1) / (float)(Wd - 1);
  const float* ap = att + (size_t)n * 9 * S + p;
  const float* pc = prev + ((size_t)n * C + c) * h2 * w2;
  float v = 0.f;
#pragma unroll
  for (int j = 0; j < 9; ++j) {
    int dy = (j / 3) * 2 - 2, dx = (j % 3) * 2 - 2;
    int yy = y + dy, xx = x + dx;
    if (yy >= 0 && yy < H && xx >= 0 && xx < Wd) {
      float fy = yy * rh, fx = xx * rw;
      int y0 = (int)fy; if (y0 > h2 - 1) y0 = h2 - 1;
      int x0 = (int)fx; if (x0 > w2 - 1) x0 = w2 - 1;
      int y1 = min(y0 + 1, h2 - 1), x1 = min(x0 + 1, w2 - 1);
      float wy = fy - y0, wx = fx - x0;
      float v00 = pc[y0 * w2 + x0], v01 = pc[y0 * w2 + x1];
      float v10 = pc[y1 * w2 + x0], v11 = pc[y1 * w2 + x1];
      float b = (v00 * (1.f - wy) + v10 * wy) * (1.f - wx) +
                (v01 * (1.f - wy) + v11 * wy) * wx;
      v = fmaf(ap[(size_t)j * S], b, v);
    }
  }
  out[idx] = v;
}

// -------- final: d_out[n,o,p] = b[o] + sum_j att2[j,p] * bilerp(v6s[n,o], tap_j(p)) --
template <typename TP>
__global__ __launch_bounds__(256) void final_kernel(
    const float* __restrict__ att, const float* __restrict__ v6s,
    const TP* __restrict__ bias, TP* __restrict__ out, int total,
    const int* __restrict__ flag, int want)
{
  if (flag[0] != want) return;
  int idx = blockIdx.x * 256 + threadIdx.x;
  if (idx >= total) return;
  const int H = 128, Wd = 128, h2 = 64, w2 = 64;
  const int S = H * Wd;
  int p = idx % S;
  int t = idx / S;
  int o = t % 19, n = t / 19;
  int x = p % Wd, y = p / Wd;
  const float rh = (float)(h2 - 1) / (float)(H - 1);
  const float rw = (float)(w2 - 1) / (float)(Wd - 1);
  const float* ap = att + (size_t)n * 9 * S + p;
  const float* pc = v6s + ((size_t)n * 19 + o) * h2 * w2;
  float v = toF(bias[o]);
#pragma unroll
  for (int j = 0; j < 9; ++j) {
    int dy = (j / 3) * 2 - 2, dx = (j % 3) * 2 - 2;
    int yy = y + dy, xx = x + dx;
    if (yy >= 0 && yy < H && xx >= 0 && xx < Wd) {
      float fy = yy * rh, fx = xx * rw;
      int y0 = (int)fy; if (y0 > h2 - 1) y0 = h2 - 1;
      int x0 = (int)fx; if (x0 > w2 - 1) x0 = w2 - 1;
      int y1 = min(y0 + 1, h2 - 1), x1 = min(x0 + 1, w2 - 1);
      float wy = fy - y0, wx = fx - x0;
      float v00 = pc[y0 * w2 + x0], v01 = pc[y0 * w2 + x1];
      float v10 = pc[y1 * w2 + x0], v11 = pc[y1 * w2 + x1];
      float b = (v00 * (1.f - wy) + v10 * wy) * (1.f - wx) +
                (v01 * (1.f - wy) + v11 * wy) * wx;
      v = fmaf(ap[(size_t)j * S], b, v);
    }
  }
  stF(&out[idx], v);
}

typedef __hip_bfloat16 bf16;

extern "C" void kernel_launch(void* const* d_in, const int* in_sizes, int n_in,
                              void* d_out, int out_size, void* d_ws, size_t ws_size,
                              hipStream_t stream) {
  (void)in_sizes; (void)n_in; (void)out_size; (void)ws_size;

  float* ws = (float*)d_ws;   // disjoint fp32 workspace, 13,584,385 floats = 51.8 MiB
  float* p5   = ws + 0;          // 1,048,576
  float* t5   = ws + 1048576;    //   262,144
  float* q4   = ws + 1310720;    //   262,144
  float* k4s  = ws + 1572864;    //    65,536
  float* k4   = ws + 1638400;    //   262,144
  float* att4 = ws + 1900544;    //    18,432
  float* o4   = ws + 1918976;    // 1,048,576
  float* q3   = ws + 2967552;    //   524,288
  float* k3s  = ws + 3491840;    //   131,072
  float* k3   = ws + 3622912;    //   524,288
  float* att3 = ws + 4147200;    //    73,728
  float* o3   = ws + 4220928;    // 4,194,304
  float* v6s  = ws + 8415232;    //   155,648
  float* q2   = ws + 8570880;    // 2,097,152
  float* k2s  = ws + 10668032;   //   524,288
  float* k2   = ws + 11192320;   // 2,097,152
  float* att2 = ws + 13289472;   //   294,912
  int*   flag = (int*)(ws + 13584384);

  // Xcol scratch for conv5-MFMA: 9,437,184 ushorts = 4,718,592 floats.
  // Temporally free: overlaps o3/v6s/q2, all of which are written AFTER
  // conv5 (GEMM consumes Xcol before finalize5; o3/v6s/q2 written later).
  unsigned short* xcol = (unsigned short*)(ws + 4220928);

  probe_kernel<<<1, 64, 0, stream>>>((const unsigned short*)d_in[0], flag);

  // Launch both dtype variants; the probe flag selects which one executes.
#define DUAL(CALL_BF, CALL_F32) do { CALL_BF; CALL_F32; } while (0)

  // ---- conv5 + BN + ReLU ----
  // bf16 path: im2col + MFMA GEMM (split-K=4 into part). f32 path: scalar.
  im2col_kernel<<<36864, 256, 0, stream>>>((const unsigned short*)d_in[3], xcol, flag, 1);
  conv5_mfma_kernel<<<dim3(64, 4), 256, 0, stream>>>(
      (const unsigned short*)d_in[7], xcol, p5, flag, 1);
  conv5_kernel<float><<<dim3(4, 128, B), 256, 0, stream>>>(
      (const float*)d_in[3], (const float*)d_in[7], p5, flag, 0);
  DUAL(
    (finalize5_kernel<bf16><<<1024, 256, 0, stream>>>(p5, (const bf16*)d_in[8], t5, flag, 1)),
    (finalize5_kernel<float><<<1024, 256, 0, stream>>>(p5, (const float*)d_in[8], t5, flag, 0)));

  // ---- localUp stage 4 (H=32, kd=128): c_hi=c3, c_lo=c40, prev=t5 ----
  DUAL(
    (conv1x1_kernel<bf16, bf16><<<dim3(16, 2, B), 256, 0, stream>>>((const bf16*)d_in[2], (const bf16*)d_in[11], (const bf16*)d_in[12], q4, 1024, 128, 1024, flag, 1)),
    (conv1x1_kernel<float, float><<<dim3(16, 2, B), 256, 0, stream>>>((const float*)d_in[2], (const float*)d_in[11], (const float*)d_in[12], q4, 1024, 128, 1024, flag, 0)));
  DUAL(
    (conv1x1_kernel<bf16, bf16><<<dim3(4, 2, B), 256, 0, stream>>>((const bf16*)d_in[6], (const bf16*)d_in[13], (const bf16*)d_in[14], k4s, 2048, 128, 256, flag, 1)),
    (conv1x1_kernel<float, float><<<dim3(4, 2, B), 256, 0, stream>>>((const float*)d_in[6], (const float*)d_in[13], (const float*)d_in[14], k4s, 2048, 128, 256, flag, 0)));
  upsample2x_kernel<<<1024, 256, 0, stream>>>(k4s, k4, 16, 16, B * 128 * 1024);
  att_kernel<<<8, 256, 0, stream>>>(q4, k4, att4, 128, 32, 32, B * 1024);
  apply_up_kernel<<<4096, 256, 0, stream>>>(att4, t5, o4, 512, 32, 32, 16, 16, B * 512 * 1024);

  // ---- localUp stage 3 (H=64, kd=64): c_hi=c2, c_lo=c30, prev=o4 ----
  DUAL(
    (conv1x1_kernel<bf16, bf16><<<dim3(64, 1, B), 256, 0, stream>>>((const bf16*)d_in[1], (const bf16*)d_in[15], (const bf16*)d_in[16], q3, 512, 64, 4096, flag, 1)),
    (conv1x1_kernel<float, float><<<dim3(64, 1, B), 256, 0, stream>>>((const float*)d_in[1], (const float*)d_in[15], (const float*)d_in[16], q3, 512, 64, 4096, flag, 0)));
  DUAL(
    (conv1x1_kernel<bf16, bf16><<<dim3(16, 1, B), 256, 0, stream>>>((const bf16*)d_in[5], (const bf16*)d_in[17], (const bf16*)d_in[18], k3s, 1024, 64, 1024, flag, 1)),
    (conv1x1_kernel<float, float><<<dim3(16, 1, B), 256, 0, stream>>>((const float*)d_in[5], (const float*)d_in[17], (const float*)d_in[18], k3s, 1024, 64, 1024, flag, 0)));
  upsample2x_kernel<<<2048, 256, 0, stream>>>(k3s, k3, 32, 32, B * 64 * 4096);
  att_kernel<<<32, 256, 0, stream>>>(q3, k3, att3, 64, 64, 64, B * 4096);
  apply_up_kernel<<<16384, 256, 0, stream>>>(att3, o4, o3, 512, 64, 64, 32, 32, B * 512 * 4096);

  // ---- localUp stage 2 (H=128, kd=64): c_hi=c1, c_lo=c2, prev=o3; conv6 commuted ----
  DUAL(
    (conv1x1_kernel<bf16, bf16><<<dim3(256, 1, B), 256, 0, stream>>>((const bf16*)d_in[0], (const bf16*)d_in[19], (const bf16*)d_in[20], q2, 256, 64, 16384, flag, 1)),
    (conv1x1_kernel<float, float><<<dim3(256, 1, B), 256, 0, stream>>>((const float*)d_in[0], (const float*)d_in[19], (const float*)d_in[20], q2, 256, 64, 16384, flag, 0)));
  DUAL(
    (conv1x1_kernel<bf16, bf16><<<dim3(64, 1, B), 256, 0, stream>>>((const bf16*)d_in[1], (const bf16*)d_in[21], (const bf16*)d_in[22], k2s, 512, 64, 4096, flag, 1)),
    (conv1x1_kernel<float, float><<<dim3(64, 1, B), 256, 0, stream>>>((const float*)d_in[1], (const float*)d_in[21], (const float*)d_in[22], k2s, 512, 64, 4096, flag, 0)));
  upsample2x_kernel<<<8192, 256, 0, stream>>>(k2s, k2, 64, 64, B * 64 * 16384);
  att_kernel<<<128, 256, 0, stream>>>(q2, k2, att2, 64, 128, 128, B * 16384);
  // v6s = conv6(o3) at 64x64 (conv6 commutes with upsample AND the 9-tap gather)
  DUAL(
    (conv1x1_kernel<float, bf16><<<dim3(64, 1, B), 256, 0, stream>>>(o3, (const bf16*)d_in[9], (const bf16*)nullptr, v6s, 512, 19, 4096, flag, 1)),
    (conv1x1_kernel<float, float><<<dim3(64, 1, B), 256, 0, stream>>>(o3, (const float*)d_in[9], (const float*)nullptr, v6s, 512, 19, 4096, flag, 0)));
  DUAL(
    (final_kernel<bf16><<<2432, 256, 0, stream>>>(att2, v6s, (const bf16*)d_in[10], (bf16*)d_out, B * 19 * 16384, flag, 1)),
    (final_kernel<float><<<2432, 256, 0, stream>>>(att2, v6s, (const float*)d_in[10], (float*)d_out, B * 19 * 16384, flag, 0)));
}

// Round 3
// 1492.014 us; speedup vs baseline: 1.3089x; 1.3086x over previous
//
#include <hip/hip_runtime.h>
#include <hip/hip_bf16.h>
#include <math.h>

#define B 2

__device__ __forceinline__ float toF(float x) { return x; }
__device__ __forceinline__ float toF(__hip_bfloat16 x) { return __bfloat162float(x); }
__device__ __forceinline__ void stF(float* p, float v) { *p = v; }
__device__ __forceinline__ void stF(__hip_bfloat16* p, float v) { *p = __float2bfloat16(v); }

typedef __attribute__((ext_vector_type(8))) short bf16x8;
typedef __attribute__((ext_vector_type(4))) float f32x4;

// bf16 RNE on raw bits (no __hip_bfloat16 ABI dependence; inputs have no NaN/Inf)
__device__ __forceinline__ unsigned short f2bf(float f) {
  unsigned int u = __float_as_uint(f);
  return (unsigned short)((u + 0x7FFFu + ((u >> 16) & 1u)) >> 16);
}
__device__ __forceinline__ float bf2f(unsigned short h) {
  return __uint_as_float((unsigned int)h << 16);
}

// ---------------- dtype probe: flag=1 if buffer is bf16, 0 if f32 ----------------
__global__ void probe_kernel(const unsigned short* __restrict__ x, int* __restrict__ flag) {
  if (threadIdx.x == 0 && blockIdx.x == 0) {
    int sane = 0;
    for (int i = 0; i < 512; ++i) {
      int e = (x[i] >> 7) & 0xFF;
      if (e >= 97 && e <= 157) ++sane;
    }
    flag[0] = (sane >= 480) ? 1 : 0;
  }
}

// =============== conv5 via split-bf16 MFMA (works for f32 AND bf16 inputs) ===========
// f32 x -> hi = bf16(x), lo = bf16(x - hi); A.B ~= Ah.Bh + Ah.Bl + Al.Bh  (lo.lo dropped)
// Two K-phases (K-half = 9216) so the 4 split buffers fit the workspace.

// ---- W split: Whi/Wlo[row=oc][kl], kl in [0,9216), src K = k0+kl of [oc][c*9+tap] ----
__global__ __launch_bounds__(256) void split_w_f32(
    const float* __restrict__ w, unsigned short* __restrict__ hi,
    unsigned short* __restrict__ lo, int k0, const int* __restrict__ flag)
{
  if (flag[0] != 0) return;
  int e = (blockIdx.x * 256 + threadIdx.x) * 4;     // 4,718,592 total elements
  int row = e / 9216, kl = e % 9216;
  float4 x = *(const float4*)(w + (size_t)row * 18432 + k0 + kl);
  float xs[4] = {x.x, x.y, x.z, x.w};
  ushort4 h, l;
  unsigned short hs[4], ls[4];
#pragma unroll
  for (int i = 0; i < 4; ++i) {
    hs[i] = f2bf(xs[i]);
    ls[i] = f2bf(xs[i] - bf2f(hs[i]));
  }
  h.x = hs[0]; h.y = hs[1]; h.z = hs[2]; h.w = hs[3];
  l.x = ls[0]; l.y = ls[1]; l.z = ls[2]; l.w = ls[3];
  *(ushort4*)(hi + e) = h;
  *(ushort4*)(lo + e) = l;
}

__global__ __launch_bounds__(256) void split_w_bf16(
    const unsigned short* __restrict__ w, unsigned short* __restrict__ hi,
    unsigned short* __restrict__ lo, int k0, const int* __restrict__ flag)
{
  if (flag[0] != 1) return;
  int e = (blockIdx.x * 256 + threadIdx.x) * 4;
  int row = e / 9216, kl = e % 9216;
  ushort4 x = *(const ushort4*)(w + (size_t)row * 18432 + k0 + kl);
  *(ushort4*)(hi + e) = x;
  ushort4 z; z.x = 0; z.y = 0; z.z = 0; z.w = 0;
  *(ushort4*)(lo + e) = z;
}

// ---- im2col split: Xhi/Xlo[r=n*256+px][kl], K=k0+kl=c*9+t, 3x3 pad 1 ----
__global__ __launch_bounds__(256) void im2col_split_f32(
    const float* __restrict__ c4, unsigned short* __restrict__ xhi,
    unsigned short* __restrict__ xlo, int k0, const int* __restrict__ flag)
{
  if (flag[0] != 0) return;
  int idx = blockIdx.x * 256 + threadIdx.x;         // 4,718,592 total
  int kl = idx % 9216, r = idx / 9216;
  int K = k0 + kl;
  int c = K / 9, t = K - c * 9;
  int n = r >> 8, px = r & 255;
  int x = px & 15, y = px >> 4;
  int yy = y + t / 3 - 1, xx = x + t % 3 - 1;
  float v = 0.f;
  if (yy >= 0 && yy < 16 && xx >= 0 && xx < 16)
    v = c4[(((size_t)n * 2048 + c) << 8) + yy * 16 + xx];
  unsigned short h = f2bf(v);
  xhi[idx] = h;
  xlo[idx] = f2bf(v - bf2f(h));
}

__global__ __launch_bounds__(256) void im2col_split_bf16(
    const unsigned short* __restrict__ c4, unsigned short* __restrict__ xhi,
    unsigned short* __restrict__ xlo, int k0, const int* __restrict__ flag)
{
  if (flag[0] != 1) return;
  int idx = blockIdx.x * 256 + threadIdx.x;
  int kl = idx % 9216, r = idx / 9216;
  int K = k0 + kl;
  int c = K / 9, t = K - c * 9;
  int n = r >> 8, px = r & 255;
  int x = px & 15, y = px >> 4;
  int yy = y + t / 3 - 1, xx = x + t % 3 - 1;
  unsigned short v = 0;
  if (yy >= 0 && yy < 16 && xx >= 0 && xx < 16)
    v = c4[(((size_t)n * 2048 + c) << 8) + yy * 16 + xx];
  xhi[idx] = v;
  xlo[idx] = 0;
}

// LDS XOR swizzle: permute 16B slots within each 128B row (involution, both sides).
__device__ __forceinline__ int swz(int b) { return b ^ (((b >> 7) & 7) << 4); }

// GEMM: part[q][oc][r] = sum_kl Ah/Al[oc][kb+kl] * Bh/Bl[r][kb+kl], 3-pass split.
// M=N=512, K=4608 per block (ks selects half of the 9216 phase-K). 64x64 tiles.
__global__ __launch_bounds__(256) void conv5_gemm_kernel(
    const unsigned short* __restrict__ Ah, const unsigned short* __restrict__ Al,
    const unsigned short* __restrict__ Bh, const unsigned short* __restrict__ Bl,
    float* __restrict__ part, int qbase)
{
  const int tile = blockIdx.x;            // 0..63 over 8x8 tiles
  const int ks   = blockIdx.y;            // 0..1
  const int mo = (tile >> 3) * 64;        // oc tile base
  const int no = (tile & 7) * 64;         // r tile base
  const int kb = ks * 4608;
  const int tid = threadIdx.x;
  const int w = tid >> 6, lane = tid & 63;
  const int wr = w >> 1, wc = w & 1;      // 2x2 wave grid, each wave 32x32 out

  __shared__ unsigned short sAh[4096], sAl[4096], sBh[4096], sBl[4096];  // 32 KB

  const int row0 = tid >> 3, slot = tid & 7;
  const size_t a0 = (size_t)(mo + row0) * 9216 + kb + slot * 8;
  const size_t a1 = a0 + (size_t)32 * 9216;
  const size_t b0 = (size_t)(no + row0) * 9216 + kb + slot * 8;
  const size_t b1 = b0 + (size_t)32 * 9216;
  const int w0 = swz(row0 * 128 + slot * 16);
  const int w1 = swz((row0 + 32) * 128 + slot * 16);

  f32x4 acc[2][2];
#pragma unroll
  for (int m = 0; m < 2; ++m)
#pragma unroll
    for (int nn = 0; nn < 2; ++nn) acc[m][nn] = (f32x4){0.f, 0.f, 0.f, 0.f};

  bf16x8 rah0 = *(const bf16x8*)(Ah + a0), rah1 = *(const bf16x8*)(Ah + a1);
  bf16x8 ral0 = *(const bf16x8*)(Al + a0), ral1 = *(const bf16x8*)(Al + a1);
  bf16x8 rbh0 = *(const bf16x8*)(Bh + b0), rbh1 = *(const bf16x8*)(Bh + b1);
  bf16x8 rbl0 = *(const bf16x8*)(Bl + b0), rbl1 = *(const bf16x8*)(Bl + b1);

  const int arow = wr * 32 + (lane & 15);
  const int brow = wc * 32 + (lane & 15);
  const int cb = (lane >> 4) * 16;        // 16B chunk within the K=32 MFMA slice

  for (int kk = 0; kk < 4608; kk += 64) {
    *(bf16x8*)((char*)sAh + w0) = rah0;  *(bf16x8*)((char*)sAh + w1) = rah1;
    *(bf16x8*)((char*)sAl + w0) = ral0;  *(bf16x8*)((char*)sAl + w1) = ral1;
    *(bf16x8*)((char*)sBh + w0) = rbh0;  *(bf16x8*)((char*)sBh + w1) = rbh1;
    *(bf16x8*)((char*)sBl + w0) = rbl0;  *(bf16x8*)((char*)sBl + w1) = rbl1;
    if (kk + 64 < 4608) {
      rah0 = *(const bf16x8*)(Ah + a0 + kk + 64);
      rah1 = *(const bf16x8*)(Ah + a1 + kk + 64);
      ral0 = *(const bf16x8*)(Al + a0 + kk + 64);
      ral1 = *(const bf16x8*)(Al + a1 + kk + 64);
      rbh0 = *(const bf16x8*)(Bh + b0 + kk + 64);
      rbh1 = *(const bf16x8*)(Bh + b1 + kk + 64);
      rbl0 = *(const bf16x8*)(Bl + b0 + kk + 64);
      rbl1 = *(const bf16x8*)(Bl + b1 + kk + 64);
    }
    __syncthreads();
#pragma unroll
    for (int k2 = 0; k2 < 2; ++k2) {
      const int colb = k2 * 64 + cb;
      bf16x8 fah[2], fal[2], fbh[2], fbl[2];
#pragma unroll
      for (int m = 0; m < 2; ++m) {
        fah[m] = *(const bf16x8*)((char*)sAh + swz((arow + m * 16) * 128 + colb));
        fal[m] = *(const bf16x8*)((char*)sAl + swz((arow + m * 16) * 128 + colb));
      }
#pragma unroll
      for (int nn = 0; nn < 2; ++nn) {
        fbh[nn] = *(const bf16x8*)((char*)sBh + swz((brow + nn * 16) * 128 + colb));
        fbl[nn] = *(const bf16x8*)((char*)sBl + swz((brow + nn * 16) * 128 + colb));
      }
#pragma unroll
      for (int m = 0; m < 2; ++m)
#pragma unroll
        for (int nn = 0; nn < 2; ++nn) {
          acc[m][nn] = __builtin_amdgcn_mfma_f32_16x16x32_bf16(fah[m], fbh[nn], acc[m][nn], 0, 0, 0);
          acc[m][nn] = __builtin_amdgcn_mfma_f32_16x16x32_bf16(fah[m], fbl[nn], acc[m][nn], 0, 0, 0);
          acc[m][nn] = __builtin_amdgcn_mfma_f32_16x16x32_bf16(fal[m], fbh[nn], acc[m][nn], 0, 0, 0);
        }
    }
    __syncthreads();
  }

  // C/D layout: col = lane&15 (-> r), row = (lane>>4)*4 + j (-> oc)
  const int quarter = qbase + ks;
#pragma unroll
  for (int m = 0; m < 2; ++m)
#pragma unroll
    for (int nn = 0; nn < 2; ++nn) {
      const int r = no + wc * 32 + nn * 16 + (lane & 15);
      const int n = r >> 8, px = r & 255;
#pragma unroll
      for (int j = 0; j < 4; ++j) {
        const int oc = mo + wr * 32 + m * 16 + (lane >> 4) * 4 + j;
        part[(size_t)quarter * 262144 + ((size_t)n * 512 + oc) * 256 + px] = acc[m][nn][j];
      }
    }
}

template <typename TP>
__global__ __launch_bounds__(256) void finalize5_kernel(
    const float* __restrict__ part, const TP* __restrict__ bn,
    float* __restrict__ t5, const int* __restrict__ flag, int want)
{
  if (flag[0] != want) return;
  int idx = blockIdx.x * 256 + threadIdx.x;   // 262144 total
  int oc = (idx >> 8) & 511;
  float s = part[idx] + part[idx + 262144] + part[idx + 2 * 262144] + part[idx + 3 * 262144];
  float g = toF(bn[oc]), b = toF(bn[512 + oc]), m = toF(bn[1024 + oc]), v = toF(bn[1536 + oc]);
  float sc = g * rsqrtf(v + 1e-5f);
  float val = s * sc + (b - m * sc);
  t5[idx] = fmaxf(val, 0.f);
}

// ---------------- generic 1x1 conv (+optional BN) ----------------
template <typename TX, typename TP>
__global__ __launch_bounds__(256) void conv1x1_kernel(
    const TX* __restrict__ X, const TP* __restrict__ Wm,
    const TP* __restrict__ bn,
    float* __restrict__ Y, int C, int O, int S,
    const int* __restrict__ flag, int want)
{
  if (flag[0] != want) return;
  const int tid = threadIdx.x;
  const int sg = tid & 15, og = tid >> 4;
  const int s0 = blockIdx.x * 64;
  const int o0 = blockIdx.y * 64;
  const int n  = blockIdx.z;

  __shared__ float xs[16][64];
  __shared__ float wsT[16][68];

  float acc[4][4];
#pragma unroll
  for (int i = 0; i < 4; ++i)
#pragma unroll
    for (int j = 0; j < 4; ++j) acc[i][j] = 0.f;

  for (int c0 = 0; c0 < C; c0 += 16) {
#pragma unroll
    for (int r = 0; r < 4; ++r) {
      int e = tid + r * 256, cc = e >> 6, ssv = e & 63;
      xs[cc][ssv] = toF(X[((size_t)n * C + c0 + cc) * S + s0 + ssv]);
    }
#pragma unroll
    for (int r = 0; r < 4; ++r) {
      int e = tid + r * 256, oo = e >> 4, cc = e & 15;
      int o = o0 + oo;
      wsT[cc][oo] = (o < O) ? toF(Wm[(size_t)o * C + c0 + cc]) : 0.f;
    }
    __syncthreads();
#pragma unroll
    for (int c = 0; c < 16; ++c) {
      const float4 xv = *(const float4*)&xs[c][sg * 4];
      const float4 wv = *(const float4*)&wsT[c][og * 4];
      acc[0][0] = fmaf(wv.x, xv.x, acc[0][0]);
      acc[0][1] = fmaf(wv.x, xv.y, acc[0][1]);
      acc[0][2] = fmaf(wv.x, xv.z, acc[0][2]);
      acc[0][3] = fmaf(wv.x, xv.w, acc[0][3]);
      acc[1][0] = fmaf(wv.y, xv.x, acc[1][0]);
      acc[1][1] = fmaf(wv.y, xv.y, acc[1][1]);
      acc[1][2] = fmaf(wv.y, xv.z, acc[1][2]);
      acc[1][3] = fmaf(wv.y, xv.w, acc[1][3]);
      acc[2][0] = fmaf(wv.z, xv.x, acc[2][0]);
      acc[2][1] = fmaf(wv.z, xv.y, acc[2][1]);
      acc[2][2] = fmaf(wv.z, xv.z, acc[2][2]);
      acc[2][3] = fmaf(wv.z, xv.w, acc[2][3]);
      acc[3][0] = fmaf(wv.w, xv.x, acc[3][0]);
      acc[3][1] = fmaf(wv.w, xv.y, acc[3][1]);
      acc[3][2] = fmaf(wv.w, xv.z, acc[3][2]);
      acc[3][3] = fmaf(wv.w, xv.w, acc[3][3]);
    }
    __syncthreads();
  }

#pragma unroll
  for (int i = 0; i < 4; ++i) {
    int o = o0 + og * 4 + i;
    if (o < O) {
      float sc = 1.f, sh = 0.f;
      if (bn) {
        float g = toF(bn[o]), bb = toF(bn[O + o]), m = toF(bn[2 * O + o]), v = toF(bn[3 * O + o]);
        sc = g * rsqrtf(v + 1e-5f);
        sh = bb - m * sc;
      }
      float4 r;
      r.x = acc[i][0] * sc + sh;
      r.y = acc[i][1] * sc + sh;
      r.z = acc[i][2] * sc + sh;
      r.w = acc[i][3] * sc + sh;
      *(float4*)(Y + ((size_t)n * O + o) * S + s0 + sg * 4) = r;
    }
  }
}

// ---------------- bilinear 2x upsample, align_corners=True (fp32 intermediates) ------
__global__ __launch_bounds__(256) void upsample2x_kernel(
    const float* __restrict__ in, float* __restrict__ out,
    int h, int w, int total)
{
  int idx = blockIdx.x * 256 + threadIdx.x;
  if (idx >= total) return;
  const int Wd = 2 * w, Hd = 2 * h;
  int xo = idx % Wd;
  int t  = idx / Wd;
  int yo = t % Hd;
  int pl = t / Hd;
  const float rh = (float)(h - 1) / (float)(Hd - 1);
  const float rw = (float)(w - 1) / (float)(Wd - 1);
  float fy = yo * rh, fx = xo * rw;
  int y0 = (int)fy; if (y0 > h - 1) y0 = h - 1;
  int x0 = (int)fx; if (x0 > w - 1) x0 = w - 1;
  int y1 = min(y0 + 1, h - 1), x1 = min(x0 + 1, w - 1);
  float wy = fy - y0, wx = fx - x0;
  const float* p = in + (size_t)pl * h * w;
  float v00 = p[y0 * w + x0], v01 = p[y0 * w + x1];
  float v10 = p[y1 * w + x0], v11 = p[y1 * w + x1];
  out[idx] = (v00 * (1.f - wy) + v10 * wy) * (1.f - wx) +
             (v01 * (1.f - wy) + v11 * wy) * wx;
}

// ---------------- 9-tap local attention logits + softmax ----------------
__global__ __launch_bounds__(256) void att_kernel(
    const float* __restrict__ q, const float* __restrict__ k,
    float* __restrict__ att, int kd, int H, int Wd, int total)
{
  int idx = blockIdx.x * 256 + threadIdx.x;
  if (idx >= total) return;
  const int S = H * Wd;
  int p = idx % S, n = idx / S;
  int x = p % Wd, y = p / Wd;
  int off[9]; bool ok[9];
#pragma unroll
  for (int j = 0; j < 9; ++j) {
    int dy = (j / 3) * 2 - 2, dx = (j % 3) * 2 - 2;
    int yy = y + dy, xx = x + dx;
    ok[j] = (yy >= 0 && yy < H && xx >= 0 && xx < Wd);
    off[j] = yy * Wd + xx;
  }
  float dot[9] = {0.f,0.f,0.f,0.f,0.f,0.f,0.f,0.f,0.f};
  const float* qp = q + (size_t)n * kd * S + p;
  const float* kp = k + (size_t)n * kd * S;
  for (int c = 0; c < kd; ++c) {
    float qv = qp[(size_t)c * S];
    const float* kc = kp + (size_t)c * S;
#pragma unroll
    for (int j = 0; j < 9; ++j)
      if (ok[j]) dot[j] = fmaf(qv, kc[off[j]], dot[j]);
  }
  float m = dot[0];
#pragma unroll
  for (int j = 1; j < 9; ++j) m = fmaxf(m, dot[j]);
  float e[9], ssum = 0.f;
#pragma unroll
  for (int j = 0; j < 9; ++j) { e[j] = __expf(dot[j] - m); ssum += e[j]; }
  float inv = 1.f / ssum;
#pragma unroll
  for (int j = 0; j < 9; ++j)
    att[((size_t)n * 9 + j) * S + p] = e[j] * inv;
}

// -------- fused: out[n,c,p] = sum_j att[n,j,p] * bilerp(prev[n,c], tap_j(p)) --------
__global__ __launch_bounds__(256) void apply_up_kernel(
    const float* __restrict__ att, const float* __restrict__ prev,
    float* __restrict__ out, int C, int H, int Wd, int h2, int w2, int total)
{
  int idx = blockIdx.x * 256 + threadIdx.x;
  if (idx >= total) return;
  const int S = H * Wd;
  int p = idx % S;
  int t = idx / S;
  int c = t % C, n = t / C;
  int x = p % Wd, y = p / Wd;
  const float rh = (float)(h2 - 1) / (float)(H - 1);
  const float rw = (float)(w2 - 1) / (float)(Wd - 1);
  const float* ap = att + (size_t)n * 9 * S + p;
  const float* pc = prev + ((size_t)n * C + c) * h2 * w2;
  float v = 0.f;
#pragma unroll
  for (int j = 0; j < 9; ++j) {
    int dy = (j / 3) * 2 - 2, dx = (j % 3) * 2 - 2;
    int yy = y + dy, xx = x + dx;
    if (yy >= 0 && yy < H && xx >= 0 && xx < Wd) {
      float fy = yy * rh, fx = xx * rw;
      int y0 = (int)fy; if (y0 > h2 - 1) y0 = h2 - 1;
      int x0 = (int)fx; if (x0 > w2 - 1) x0 = w2 - 1;
      int y1 = min(y0 + 1, h2 - 1), x1 = min(x0 + 1, w2 - 1);
      float wy = fy - y0, wx = fx - x0;
      float v00 = pc[y0 * w2 + x0], v01 = pc[y0 * w2 + x1];
      float v10 = pc[y1 * w2 + x0], v11 = pc[y1 * w2 + x1];
      float b = (v00 * (1.f - wy) + v10 * wy) * (1.f - wx) +
                (v01 * (1.f - wy) + v11 * wy) * wx;
      v = fmaf(ap[(size_t)j * S], b, v);
    }
  }
  out[idx] = v;
}

// -------- final: d_out[n,o,p] = b[o] + sum_j att2[j,p] * bilerp(v6s[n,o], tap_j(p)) --
template <typename TP>
__global__ __launch_bounds__(256) void final_kernel(
    const float* __restrict__ att, const float* __restrict__ v6s,
    const TP* __restrict__ bias, TP* __restrict__ out, int total,
    const int* __restrict__ flag, int want)
{
  if (flag[0] != want) return;
  int idx = blockIdx.x * 256 + threadIdx.x;
  if (idx >= total) return;
  const int H = 128, Wd = 128, h2 = 64, w2 = 64;
  const int S = H * Wd;
  int p = idx % S;
  int t = idx / S;
  int o = t % 19, n = t / 19;
  int x = p % Wd, y = p / Wd;
  const float rh = (float)(h2 - 1) / (float)(H - 1);
  const float rw = (float)(w2 - 1) / (float)(Wd - 1);
  const float* ap = att + (size_t)n * 9 * S + p;
  const float* pc = v6s + ((size_t)n * 19 + o) * h2 * w2;
  float v = toF(bias[o]);
#pragma unroll
  for (int j = 0; j < 9; ++j) {
    int dy = (j / 3) * 2 - 2, dx = (j % 3) * 2 - 2;
    int yy = y + dy, xx = x + dx;
    if (yy >= 0 && yy < H && xx >= 0 && xx < Wd) {
      float fy = yy * rh, fx = xx * rw;
      int y0 = (int)fy; if (y0 > h2 - 1) y0 = h2 - 1;
      int x0 = (int)fx; if (x0 > w2 - 1) x0 = w2 - 1;
      int y1 = min(y0 + 1, h2 - 1), x1 = min(x0 + 1, w2 - 1);
      float wy = fy - y0, wx = fx - x0;
      float v00 = pc[y0 * w2 + x0], v01 = pc[y0 * w2 + x1];
      float v10 = pc[y1 * w2 + x0], v11 = pc[y1 * w2 + x1];
      float b = (v00 * (1.f - wy) + v10 * wy) * (1.f - wx) +
                (v01 * (1.f - wy) + v11 * wy) * wx;
      v = fmaf(ap[(size_t)j * S], b, v);
    }
  }
  stF(&out[idx], v);
}

typedef __hip_bfloat16 bf16;

extern "C" void kernel_launch(void* const* d_in, const int* in_sizes, int n_in,
                              void* d_out, int out_size, void* d_ws, size_t ws_size,
                              hipStream_t stream) {
  (void)in_sizes; (void)n_in; (void)out_size; (void)ws_size;

  float* ws = (float*)d_ws;   // fp32 workspace, 13,584,385 floats = 51.8 MiB
  float* p5   = ws + 0;          // 1,048,576
  float* t5   = ws + 1048576;    //   262,144
  float* q4   = ws + 1310720;    //   262,144
  float* k4s  = ws + 1572864;    //    65,536
  float* k4   = ws + 1638400;    //   262,144
  float* att4 = ws + 1900544;    //    18,432
  float* o4   = ws + 1918976;    // 1,048,576
  float* q3   = ws + 2967552;    //   524,288
  float* k3s  = ws + 3491840;    //   131,072
  float* k3   = ws + 3622912;    //   524,288
  float* att3 = ws + 4147200;    //    73,728
  float* o3   = ws + 4220928;    // 4,194,304
  float* v6s  = ws + 8415232;    //   155,648
  float* q2   = ws + 8570880;    // 2,097,152
  float* k2s  = ws + 10668032;   //   524,288
  float* k2   = ws + 11192320;   // 2,097,152
  float* att2 = ws + 13289472;   //   294,912
  int*   flag = (int*)(ws + 13584384);

  // conv5 split buffers (each 2,359,296 float-units = 4,718,592 bf16).
  // Live only during conv5; overlap q4..o3 regions (all written later).
  unsigned short* whi = (unsigned short*)(ws + 1310720);
  unsigned short* wlo = (unsigned short*)(ws + 3670016);
  unsigned short* xhi = (unsigned short*)(ws + 6029312);
  unsigned short* xlo = (unsigned short*)(ws + 8388608);   // ends at 10,747,904

  probe_kernel<<<1, 64, 0, stream>>>((const unsigned short*)d_in[0], flag);

  // Launch both dtype variants; the probe flag selects which one executes.
#define DUAL(CALL_BF, CALL_F32) do { CALL_BF; CALL_F32; } while (0)

  // ---- conv5 + BN + ReLU: split-bf16 MFMA GEMM, two K-phases ----
  for (int ph = 0; ph < 2; ++ph) {
    const int k0 = ph * 9216;
    split_w_f32 <<<4608, 256, 0, stream>>>((const float*)d_in[7], whi, wlo, k0, flag);
    split_w_bf16<<<4608, 256, 0, stream>>>((const unsigned short*)d_in[7], whi, wlo, k0, flag);
    im2col_split_f32 <<<18432, 256, 0, stream>>>((const float*)d_in[3], xhi, xlo, k0, flag);
    im2col_split_bf16<<<18432, 256, 0, stream>>>((const unsigned short*)d_in[3], xhi, xlo, k0, flag);
    conv5_gemm_kernel<<<dim3(64, 2), 256, 0, stream>>>(whi, wlo, xhi, xlo, p5, ph * 2);
  }
  DUAL(
    (finalize5_kernel<bf16><<<1024, 256, 0, stream>>>(p5, (const bf16*)d_in[8], t5, flag, 1)),
    (finalize5_kernel<float><<<1024, 256, 0, stream>>>(p5, (const float*)d_in[8], t5, flag, 0)));

  // ---- localUp stage 4 (H=32, kd=128): c_hi=c3, c_lo=c40, prev=t5 ----
  DUAL(
    (conv1x1_kernel<bf16, bf16><<<dim3(16, 2, B), 256, 0, stream>>>((const bf16*)d_in[2], (const bf16*)d_in[11], (const bf16*)d_in[12], q4, 1024, 128, 1024, flag, 1)),
    (conv1x1_kernel<float, float><<<dim3(16, 2, B), 256, 0, stream>>>((const float*)d_in[2], (const float*)d_in[11], (const float*)d_in[12], q4, 1024, 128, 1024, flag, 0)));
  DUAL(
    (conv1x1_kernel<bf16, bf16><<<dim3(4, 2, B), 256, 0, stream>>>((const bf16*)d_in[6], (const bf16*)d_in[13], (const bf16*)d_in[14], k4s, 2048, 128, 256, flag, 1)),
    (conv1x1_kernel<float, float><<<dim3(4, 2, B), 256, 0, stream>>>((const float*)d_in[6], (const float*)d_in[13], (const float*)d_in[14], k4s, 2048, 128, 256, flag, 0)));
  upsample2x_kernel<<<1024, 256, 0, stream>>>(k4s, k4, 16, 16, B * 128 * 1024);
  att_kernel<<<8, 256, 0, stream>>>(q4, k4, att4, 128, 32, 32, B * 1024);
  apply_up_kernel<<<4096, 256, 0, stream>>>(att4, t5, o4, 512, 32, 32, 16, 16, B * 512 * 1024);

  // ---- localUp stage 3 (H=64, kd=64): c_hi=c2, c_lo=c30, prev=o4 ----
  DUAL(
    (conv1x1_kernel<bf16, bf16><<<dim3(64, 1, B), 256, 0, stream>>>((const bf16*)d_in[1], (const bf16*)d_in[15], (const bf16*)d_in[16], q3, 512, 64, 4096, flag, 1)),
    (conv1x1_kernel<float, float><<<dim3(64, 1, B), 256, 0, stream>>>((const float*)d_in[1], (const float*)d_in[15], (const float*)d_in[16], q3, 512, 64, 4096, flag, 0)));
  DUAL(
    (conv1x1_kernel<bf16, bf16><<<dim3(16, 1, B), 256, 0, stream>>>((const bf16*)d_in[5], (const bf16*)d_in[17], (const bf16*)d_in[18], k3s, 1024, 64, 1024, flag, 1)),
    (conv1x1_kernel<float, float><<<dim3(16, 1, B), 256, 0, stream>>>((const float*)d_in[5], (const float*)d_in[17], (const float*)d_in[18], k3s, 1024, 64, 1024, flag, 0)));
  upsample2x_kernel<<<2048, 256, 0, stream>>>(k3s, k3, 32, 32, B * 64 * 4096);
  att_kernel<<<32, 256, 0, stream>>>(q3, k3, att3, 64, 64, 64, B * 4096);
  apply_up_kernel<<<16384, 256, 0, stream>>>(att3, o4, o3, 512, 64, 64, 32, 32, B * 512 * 4096);

  // ---- localUp stage 2 (H=128, kd=64): c_hi=c1, c_lo=c2, prev=o3; conv6 commuted ----
  DUAL(
    (conv1x1_kernel<bf16, bf16><<<dim3(256, 1, B), 256, 0, stream>>>((const bf16*)d_in[0], (const bf16*)d_in[19], (const bf16*)d_in[20], q2, 256, 64, 16384, flag, 1)),
    (conv1x1_kernel<float, float><<<dim3(256, 1, B), 256, 0, stream>>>((const float*)d_in[0], (const float*)d_in[19], (const float*)d_in[20], q2, 256, 64, 16384, flag, 0)));
  DUAL(
    (conv1x1_kernel<bf16, bf16><<<dim3(64, 1, B), 256, 0, stream>>>((const bf16*)d_in[1], (const bf16*)d_in[21], (const bf16*)d_in[22], k2s, 512, 64, 4096, flag, 1)),
    (conv1x1_kernel<float, float><<<dim3(64, 1, B), 256, 0, stream>>>((const float*)d_in[1], (const float*)d_in[21], (const float*)d_in[22], k2s, 512, 64, 4096, flag, 0)));
  upsample2x_kernel<<<8192, 256, 0, stream>>>(k2s, k2, 64, 64, B * 64 * 16384);
  att_kernel<<<128, 256, 0, stream>>>(q2, k2, att2, 64, 128, 128, B * 16384);
  // v6s = conv6(o3) at 64x64 (conv6 commutes with upsample AND the 9-tap gather)
  DUAL(
    (conv1x1_kernel<float, bf16><<<dim3(64, 1, B), 256, 0, stream>>>(o3, (const bf16*)d_in[9], (const bf16*)nullptr, v6s, 512, 19, 4096, flag, 1)),
    (conv1x1_kernel<float, float><<<dim3(64, 1, B), 256, 0, stream>>>(o3, (const float*)d_in[9], (const float*)nullptr, v6s, 512, 19, 4096, flag, 0)));
  DUAL(
    (final_kernel<bf16><<<2432, 256, 0, stream>>>(att2, v6s, (const bf16*)d_in[10], (bf16*)d_out, B * 19 * 16384, flag, 1)),
    (final_kernel<float><<<2432, 256, 0, stream>>>(att2, v6s, (const float*)d_in[10], (float*)d_out, B * 19 * 16384, flag, 0)));
}

// Round 4
// 747.204 us; speedup vs baseline: 2.6135x; 1.9968x over previous
//
#include <hip/hip_runtime.h>
#include <hip/hip_bf16.h>
#include <math.h>

#define B 2

__device__ __forceinline__ float toF(float x) { return x; }
__device__ __forceinline__ float toF(__hip_bfloat16 x) { return __bfloat162float(x); }
__device__ __forceinline__ void stF(float* p, float v) { *p = v; }
__device__ __forceinline__ void stF(__hip_bfloat16* p, float v) { *p = __float2bfloat16(v); }

typedef __attribute__((ext_vector_type(8))) short bf16x8;
typedef __attribute__((ext_vector_type(4))) float f32x4;

// bf16 RNE on raw bits (no __hip_bfloat16 ABI dependence; inputs have no NaN/Inf)
__device__ __forceinline__ unsigned short f2bf(float f) {
  unsigned int u = __float_as_uint(f);
  return (unsigned short)((u + 0x7FFFu + ((u >> 16) & 1u)) >> 16);
}
__device__ __forceinline__ float bf2f(unsigned short h) {
  return __uint_as_float((unsigned int)h << 16);
}

// ---------------- dtype probe: flag=1 if buffer is bf16, 0 if f32 ----------------
__global__ void probe_kernel(const unsigned short* __restrict__ x, int* __restrict__ flag) {
  if (threadIdx.x == 0 && blockIdx.x == 0) {
    int sane = 0;
    for (int i = 0; i < 512; ++i) {
      int e = (x[i] >> 7) & 0xFF;
      if (e >= 97 && e <= 157) ++sane;
    }
    flag[0] = (sane >= 480) ? 1 : 0;
  }
}

// =============== conv5 via split-bf16 MFMA (works for f32 AND bf16 inputs) ===========
__global__ __launch_bounds__(256) void split_w_f32(
    const float* __restrict__ w, unsigned short* __restrict__ hi,
    unsigned short* __restrict__ lo, int k0, const int* __restrict__ flag)
{
  if (flag[0] != 0) return;
  int e = (blockIdx.x * 256 + threadIdx.x) * 4;     // 4,718,592 total elements
  int row = e / 9216, kl = e % 9216;
  float4 x = *(const float4*)(w + (size_t)row * 18432 + k0 + kl);
  float xs[4] = {x.x, x.y, x.z, x.w};
  ushort4 h, l;
  unsigned short hs[4], ls[4];
#pragma unroll
  for (int i = 0; i < 4; ++i) {
    hs[i] = f2bf(xs[i]);
    ls[i] = f2bf(xs[i] - bf2f(hs[i]));
  }
  h.x = hs[0]; h.y = hs[1]; h.z = hs[2]; h.w = hs[3];
  l.x = ls[0]; l.y = ls[1]; l.z = ls[2]; l.w = ls[3];
  *(ushort4*)(hi + e) = h;
  *(ushort4*)(lo + e) = l;
}

__global__ __launch_bounds__(256) void split_w_bf16(
    const unsigned short* __restrict__ w, unsigned short* __restrict__ hi,
    unsigned short* __restrict__ lo, int k0, const int* __restrict__ flag)
{
  if (flag[0] != 1) return;
  int e = (blockIdx.x * 256 + threadIdx.x) * 4;
  int row = e / 9216, kl = e % 9216;
  ushort4 x = *(const ushort4*)(w + (size_t)row * 18432 + k0 + kl);
  *(ushort4*)(hi + e) = x;
  ushort4 z; z.x = 0; z.y = 0; z.z = 0; z.w = 0;
  *(ushort4*)(lo + e) = z;
}

__global__ __launch_bounds__(256) void im2col_split_f32(
    const float* __restrict__ c4, unsigned short* __restrict__ xhi,
    unsigned short* __restrict__ xlo, int k0, const int* __restrict__ flag)
{
  if (flag[0] != 0) return;
  int idx = blockIdx.x * 256 + threadIdx.x;         // 4,718,592 total
  int kl = idx % 9216, r = idx / 9216;
  int K = k0 + kl;
  int c = K / 9, t = K - c * 9;
  int n = r >> 8, px = r & 255;
  int x = px & 15, y = px >> 4;
  int yy = y + t / 3 - 1, xx = x + t % 3 - 1;
  float v = 0.f;
  if (yy >= 0 && yy < 16 && xx >= 0 && xx < 16)
    v = c4[(((size_t)n * 2048 + c) << 8) + yy * 16 + xx];
  unsigned short h = f2bf(v);
  xhi[idx] = h;
  xlo[idx] = f2bf(v - bf2f(h));
}

__global__ __launch_bounds__(256) void im2col_split_bf16(
    const unsigned short* __restrict__ c4, unsigned short* __restrict__ xhi,
    unsigned short* __restrict__ xlo, int k0, const int* __restrict__ flag)
{
  if (flag[0] != 1) return;
  int idx = blockIdx.x * 256 + threadIdx.x;
  int kl = idx % 9216, r = idx / 9216;
  int K = k0 + kl;
  int c = K / 9, t = K - c * 9;
  int n = r >> 8, px = r & 255;
  int x = px & 15, y = px >> 4;
  int yy = y + t / 3 - 1, xx = x + t % 3 - 1;
  unsigned short v = 0;
  if (yy >= 0 && yy < 16 && xx >= 0 && xx < 16)
    v = c4[(((size_t)n * 2048 + c) << 8) + yy * 16 + xx];
  xhi[idx] = v;
  xlo[idx] = 0;
}

// LDS XOR swizzle: permute 16B slots within each 128B row (involution, both sides).
__device__ __forceinline__ int swz(int b) { return b ^ (((b >> 7) & 7) << 4); }

__global__ __launch_bounds__(256) void conv5_gemm_kernel(
    const unsigned short* __restrict__ Ah, const unsigned short* __restrict__ Al,
    const unsigned short* __restrict__ Bh, const unsigned short* __restrict__ Bl,
    float* __restrict__ part, int qbase)
{
  const int tile = blockIdx.x;            // 0..63 over 8x8 tiles
  const int ks   = blockIdx.y;            // 0..1
  const int mo = (tile >> 3) * 64;        // oc tile base
  const int no = (tile & 7) * 64;         // r tile base
  const int kb = ks * 4608;
  const int tid = threadIdx.x;
  const int w = tid >> 6, lane = tid & 63;
  const int wr = w >> 1, wc = w & 1;      // 2x2 wave grid, each wave 32x32 out

  __shared__ unsigned short sAh[4096], sAl[4096], sBh[4096], sBl[4096];  // 32 KB

  const int row0 = tid >> 3, slot = tid & 7;
  const size_t a0 = (size_t)(mo + row0) * 9216 + kb + slot * 8;
  const size_t a1 = a0 + (size_t)32 * 9216;
  const size_t b0 = (size_t)(no + row0) * 9216 + kb + slot * 8;
  const size_t b1 = b0 + (size_t)32 * 9216;
  const int w0 = swz(row0 * 128 + slot * 16);
  const int w1 = swz((row0 + 32) * 128 + slot * 16);

  f32x4 acc[2][2];
#pragma unroll
  for (int m = 0; m < 2; ++m)
#pragma unroll
    for (int nn = 0; nn < 2; ++nn) acc[m][nn] = (f32x4){0.f, 0.f, 0.f, 0.f};

  bf16x8 rah0 = *(const bf16x8*)(Ah + a0), rah1 = *(const bf16x8*)(Ah + a1);
  bf16x8 ral0 = *(const bf16x8*)(Al + a0), ral1 = *(const bf16x8*)(Al + a1);
  bf16x8 rbh0 = *(const bf16x8*)(Bh + b0), rbh1 = *(const bf16x8*)(Bh + b1);
  bf16x8 rbl0 = *(const bf16x8*)(Bl + b0), rbl1 = *(const bf16x8*)(Bl + b1);

  const int arow = wr * 32 + (lane & 15);
  const int brow = wc * 32 + (lane & 15);
  const int cb = (lane >> 4) * 16;        // 16B chunk within the K=32 MFMA slice

  for (int kk = 0; kk < 4608; kk += 64) {
    *(bf16x8*)((char*)sAh + w0) = rah0;  *(bf16x8*)((char*)sAh + w1) = rah1;
    *(bf16x8*)((char*)sAl + w0) = ral0;  *(bf16x8*)((char*)sAl + w1) = ral1;
    *(bf16x8*)((char*)sBh + w0) = rbh0;  *(bf16x8*)((char*)sBh + w1) = rbh1;
    *(bf16x8*)((char*)sBl + w0) = rbl0;  *(bf16x8*)((char*)sBl + w1) = rbl1;
    if (kk + 64 < 4608) {
      rah0 = *(const bf16x8*)(Ah + a0 + kk + 64);
      rah1 = *(const bf16x8*)(Ah + a1 + kk + 64);
      ral0 = *(const bf16x8*)(Al + a0 + kk + 64);
      ral1 = *(const bf16x8*)(Al + a1 + kk + 64);
      rbh0 = *(const bf16x8*)(Bh + b0 + kk + 64);
      rbh1 = *(const bf16x8*)(Bh + b1 + kk + 64);
      rbl0 = *(const bf16x8*)(Bl + b0 + kk + 64);
      rbl1 = *(const bf16x8*)(Bl + b1 + kk + 64);
    }
    __syncthreads();
#pragma unroll
    for (int k2 = 0; k2 < 2; ++k2) {
      const int colb = k2 * 64 + cb;
      bf16x8 fah[2], fal[2], fbh[2], fbl[2];
#pragma unroll
      for (int m = 0; m < 2; ++m) {
        fah[m] = *(const bf16x8*)((char*)sAh + swz((arow + m * 16) * 128 + colb));
        fal[m] = *(const bf16x8*)((char*)sAl + swz((arow + m * 16) * 128 + colb));
      }
#pragma unroll
      for (int nn = 0; nn < 2; ++nn) {
        fbh[nn] = *(const bf16x8*)((char*)sBh + swz((brow + nn * 16) * 128 + colb));
        fbl[nn] = *(const bf16x8*)((char*)sBl + swz((brow + nn * 16) * 128 + colb));
      }
#pragma unroll
      for (int m = 0; m < 2; ++m)
#pragma unroll
        for (int nn = 0; nn < 2; ++nn) {
          acc[m][nn] = __builtin_amdgcn_mfma_f32_16x16x32_bf16(fah[m], fbh[nn], acc[m][nn], 0, 0, 0);
          acc[m][nn] = __builtin_amdgcn_mfma_f32_16x16x32_bf16(fah[m], fbl[nn], acc[m][nn], 0, 0, 0);
          acc[m][nn] = __builtin_amdgcn_mfma_f32_16x16x32_bf16(fal[m], fbh[nn], acc[m][nn], 0, 0, 0);
        }
    }
    __syncthreads();
  }

  // C/D layout: col = lane&15 (-> r), row = (lane>>4)*4 + j (-> oc)
  const int quarter = qbase + ks;
#pragma unroll
  for (int m = 0; m < 2; ++m)
#pragma unroll
    for (int nn = 0; nn < 2; ++nn) {
      const int r = no + wc * 32 + nn * 16 + (lane & 15);
      const int n = r >> 8, px = r & 255;
#pragma unroll
      for (int j = 0; j < 4; ++j) {
        const int oc = mo + wr * 32 + m * 16 + (lane >> 4) * 4 + j;
        part[(size_t)quarter * 262144 + ((size_t)n * 512 + oc) * 256 + px] = acc[m][nn][j];
      }
    }
}

template <typename TP>
__global__ __launch_bounds__(256) void finalize5_kernel(
    const float* __restrict__ part, const TP* __restrict__ bn,
    float* __restrict__ t5, const int* __restrict__ flag, int want)
{
  if (flag[0] != want) return;
  int idx = blockIdx.x * 256 + threadIdx.x;   // 262144 total
  int oc = (idx >> 8) & 511;
  float s = part[idx] + part[idx + 262144] + part[idx + 2 * 262144] + part[idx + 3 * 262144];
  float g = toF(bn[oc]), b = toF(bn[512 + oc]), m = toF(bn[1024 + oc]), v = toF(bn[1536 + oc]);
  float sc = g * rsqrtf(v + 1e-5f);
  float val = s * sc + (b - m * sc);
  t5[idx] = fmaxf(val, 0.f);
}

// ---------------- generic 1x1 conv (+optional BN), direct path ----------------
template <typename TX, typename TP>
__global__ __launch_bounds__(256) void conv1x1_kernel(
    const TX* __restrict__ X, const TP* __restrict__ Wm,
    const TP* __restrict__ bn,
    float* __restrict__ Y, int C, int O, int S,
    const int* __restrict__ flag, int want)
{
  if (flag[0] != want) return;
  const int tid = threadIdx.x;
  const int sg = tid & 15, og = tid >> 4;
  const int s0 = blockIdx.x * 64;
  const int o0 = blockIdx.y * 64;
  const int n  = blockIdx.z;

  __shared__ float xs[16][64];
  __shared__ float wsT[16][68];

  float acc[4][4];
#pragma unroll
  for (int i = 0; i < 4; ++i)
#pragma unroll
    for (int j = 0; j < 4; ++j) acc[i][j] = 0.f;

  for (int c0 = 0; c0 < C; c0 += 16) {
#pragma unroll
    for (int r = 0; r < 4; ++r) {
      int e = tid + r * 256, cc = e >> 6, ssv = e & 63;
      xs[cc][ssv] = toF(X[((size_t)n * C + c0 + cc) * S + s0 + ssv]);
    }
#pragma unroll
    for (int r = 0; r < 4; ++r) {
      int e = tid + r * 256, oo = e >> 4, cc = e & 15;
      int o = o0 + oo;
      wsT[cc][oo] = (o < O) ? toF(Wm[(size_t)o * C + c0 + cc]) : 0.f;
    }
    __syncthreads();
#pragma unroll
    for (int c = 0; c < 16; ++c) {
      const float4 xv = *(const float4*)&xs[c][sg * 4];
      const float4 wv = *(const float4*)&wsT[c][og * 4];
      acc[0][0] = fmaf(wv.x, xv.x, acc[0][0]);
      acc[0][1] = fmaf(wv.x, xv.y, acc[0][1]);
      acc[0][2] = fmaf(wv.x, xv.z, acc[0][2]);
      acc[0][3] = fmaf(wv.x, xv.w, acc[0][3]);
      acc[1][0] = fmaf(wv.y, xv.x, acc[1][0]);
      acc[1][1] = fmaf(wv.y, xv.y, acc[1][1]);
      acc[1][2] = fmaf(wv.y, xv.z, acc[1][2]);
      acc[1][3] = fmaf(wv.y, xv.w, acc[1][3]);
      acc[2][0] = fmaf(wv.z, xv.x, acc[2][0]);
      acc[2][1] = fmaf(wv.z, xv.y, acc[2][1]);
      acc[2][2] = fmaf(wv.z, xv.z, acc[2][2]);
      acc[2][3] = fmaf(wv.z, xv.w, acc[2][3]);
      acc[3][0] = fmaf(wv.w, xv.x, acc[3][0]);
      acc[3][1] = fmaf(wv.w, xv.y, acc[3][1]);
      acc[3][2] = fmaf(wv.w, xv.z, acc[3][2]);
      acc[3][3] = fmaf(wv.w, xv.w, acc[3][3]);
    }
    __syncthreads();
  }

#pragma unroll
  for (int i = 0; i < 4; ++i) {
    int o = o0 + og * 4 + i;
    if (o < O) {
      float sc = 1.f, sh = 0.f;
      if (bn) {
        float g = toF(bn[o]), bb = toF(bn[O + o]), m = toF(bn[2 * O + o]), v = toF(bn[3 * O + o]);
        sc = g * rsqrtf(v + 1e-5f);
        sh = bb - m * sc;
      }
      float4 r;
      r.x = acc[i][0] * sc + sh;
      r.y = acc[i][1] * sc + sh;
      r.z = acc[i][2] * sc + sh;
      r.w = acc[i][3] * sc + sh;
      *(float4*)(Y + ((size_t)n * O + o) * S + s0 + sg * 4) = r;
    }
  }
}

// ---------------- split-C 1x1 conv: partials over C-chunks (occupancy fix) ----------
// blockIdx.z = n*KS + kc; each block reduces C/KS channels; raw partials out.
// part layout: part[kc*(B*O*S) + (n*O + o)*S + s]
template <typename TX, typename TP>
__global__ __launch_bounds__(256) void conv1x1_part_kernel(
    const TX* __restrict__ X, const TP* __restrict__ Wm,
    float* __restrict__ part, int C, int O, int S, int KS,
    const int* __restrict__ flag, int want)
{
  if (flag[0] != want) return;
  const int tid = threadIdx.x;
  const int sg = tid & 15, og = tid >> 4;
  const int s0 = blockIdx.x * 64;
  const int o0 = blockIdx.y * 64;
  const int n  = blockIdx.z / KS;
  const int kc = blockIdx.z % KS;
  const int CC = C / KS;
  const int cbase = kc * CC;

  __shared__ float xs[16][64];
  __shared__ float wsT[16][68];

  float acc[4][4];
#pragma unroll
  for (int i = 0; i < 4; ++i)
#pragma unroll
    for (int j = 0; j < 4; ++j) acc[i][j] = 0.f;

  for (int c0 = cbase; c0 < cbase + CC; c0 += 16) {
#pragma unroll
    for (int r = 0; r < 4; ++r) {
      int e = tid + r * 256, cc = e >> 6, ssv = e & 63;
      xs[cc][ssv] = toF(X[((size_t)n * C + c0 + cc) * S + s0 + ssv]);
    }
#pragma unroll
    for (int r = 0; r < 4; ++r) {
      int e = tid + r * 256, oo = e >> 4, cc = e & 15;
      int o = o0 + oo;
      wsT[cc][oo] = (o < O) ? toF(Wm[(size_t)o * C + c0 + cc]) : 0.f;
    }
    __syncthreads();
#pragma unroll
    for (int c = 0; c < 16; ++c) {
      const float4 xv = *(const float4*)&xs[c][sg * 4];
      const float4 wv = *(const float4*)&wsT[c][og * 4];
      acc[0][0] = fmaf(wv.x, xv.x, acc[0][0]);
      acc[0][1] = fmaf(wv.x, xv.y, acc[0][1]);
      acc[0][2] = fmaf(wv.x, xv.z, acc[0][2]);
      acc[0][3] = fmaf(wv.x, xv.w, acc[0][3]);
      acc[1][0] = fmaf(wv.y, xv.x, acc[1][0]);
      acc[1][1] = fmaf(wv.y, xv.y, acc[1][1]);
      acc[1][2] = fmaf(wv.y, xv.z, acc[1][2]);
      acc[1][3] = fmaf(wv.y, xv.w, acc[1][3]);
      acc[2][0] = fmaf(wv.z, xv.x, acc[2][0]);
      acc[2][1] = fmaf(wv.z, xv.y, acc[2][1]);
      acc[2][2] = fmaf(wv.z, xv.z, acc[2][2]);
      acc[2][3] = fmaf(wv.z, xv.w, acc[2][3]);
      acc[3][0] = fmaf(wv.w, xv.x, acc[3][0]);
      acc[3][1] = fmaf(wv.w, xv.y, acc[3][1]);
      acc[3][2] = fmaf(wv.w, xv.z, acc[3][2]);
      acc[3][3] = fmaf(wv.w, xv.w, acc[3][3]);
    }
    __syncthreads();
  }

  const size_t BOS = (size_t)B * O * S;
#pragma unroll
  for (int i = 0; i < 4; ++i) {
    int o = o0 + og * 4 + i;
    if (o < O) {
      float4 r;
      r.x = acc[i][0]; r.y = acc[i][1]; r.z = acc[i][2]; r.w = acc[i][3];
      *(float4*)(part + (size_t)kc * BOS + ((size_t)n * O + o) * S + s0 + sg * 4) = r;
    }
  }
}

// sum KS partials + optional BN -> Y.  total = B*O*S (== partial stride)
template <typename TP>
__global__ __launch_bounds__(256) void reduce_bn_kernel(
    const float* __restrict__ part, const TP* __restrict__ bn,
    float* __restrict__ Y, int O, int S, int KS, int total,
    const int* __restrict__ flag, int want)
{
  if (flag[0] != want) return;
  int idx = blockIdx.x * 256 + threadIdx.x;
  if (idx >= total) return;
  float s = 0.f;
  for (int kc = 0; kc < KS; ++kc) s += part[(size_t)kc * total + idx];
  float sc = 1.f, sh = 0.f;
  if (bn) {
    int o = (idx / S) % O;
    float g = toF(bn[o]), bb = toF(bn[O + o]), m = toF(bn[2 * O + o]), v = toF(bn[3 * O + o]);
    sc = g * rsqrtf(v + 1e-5f);
    sh = bb - m * sc;
  }
  Y[idx] = s * sc + sh;
}

// ---------------- bilinear 2x upsample, align_corners=True (fp32 intermediates) ------
__global__ __launch_bounds__(256) void upsample2x_kernel(
    const float* __restrict__ in, float* __restrict__ out,
    int h, int w, int total)
{
  int idx = blockIdx.x * 256 + threadIdx.x;
  if (idx >= total) return;
  const int Wd = 2 * w, Hd = 2 * h;
  int xo = idx % Wd;
  int t  = idx / Wd;
  int yo = t % Hd;
  int pl = t / Hd;
  const float rh = (float)(h - 1) / (float)(Hd - 1);
  const float rw = (float)(w - 1) / (float)(Wd - 1);
  float fy = yo * rh, fx = xo * rw;
  int y0 = (int)fy; if (y0 > h - 1) y0 = h - 1;
  int x0 = (int)fx; if (x0 > w - 1) x0 = w - 1;
  int y1 = min(y0 + 1, h - 1), x1 = min(x0 + 1, w - 1);
  float wy = fy - y0, wx = fx - x0;
  const float* p = in + (size_t)pl * h * w;
  float v00 = p[y0 * w + x0], v01 = p[y0 * w + x1];
  float v10 = p[y1 * w + x0], v11 = p[y1 * w + x1];
  out[idx] = (v00 * (1.f - wy) + v10 * wy) * (1.f - wx) +
             (v01 * (1.f - wy) + v11 * wy) * wx;
}

// ---------------- 9-tap local attention logits + softmax (direct, stage 2) ----------
__global__ __launch_bounds__(256) void att_kernel(
    const float* __restrict__ q, const float* __restrict__ k,
    float* __restrict__ att, int kd, int H, int Wd, int total)
{
  int idx = blockIdx.x * 256 + threadIdx.x;
  if (idx >= total) return;
  const int S = H * Wd;
  int p = idx % S, n = idx / S;
  int x = p % Wd, y = p / Wd;
  int off[9]; bool ok[9];
#pragma unroll
  for (int j = 0; j < 9; ++j) {
    int dy = (j / 3) * 2 - 2, dx = (j % 3) * 2 - 2;
    int yy = y + dy, xx = x + dx;
    ok[j] = (yy >= 0 && yy < H && xx >= 0 && xx < Wd);
    off[j] = yy * Wd + xx;
  }
  float dot[9] = {0.f,0.f,0.f,0.f,0.f,0.f,0.f,0.f,0.f};
  const float* qp = q + (size_t)n * kd * S + p;
  const float* kp = k + (size_t)n * kd * S;
  for (int c = 0; c < kd; ++c) {
    float qv = qp[(size_t)c * S];
    const float* kc = kp + (size_t)c * S;
#pragma unroll
    for (int j = 0; j < 9; ++j)
      if (ok[j]) dot[j] = fmaf(qv, kc[off[j]], dot[j]);
  }
  float m = dot[0];
#pragma unroll
  for (int j = 1; j < 9; ++j) m = fmaxf(m, dot[j]);
  float e[9], ssum = 0.f;
#pragma unroll
  for (int j = 0; j < 9; ++j) { e[j] = __expf(dot[j] - m); ssum += e[j]; }
  float inv = 1.f / ssum;
#pragma unroll
  for (int j = 0; j < 9; ++j)
    att[((size_t)n * 9 + j) * S + p] = e[j] * inv;
}

// ---- kd-split attention: partial dots (occupancy fix for small-S stages) ----
// pd layout: pd[((kc*B + n)*9 + j)*S + p];  total = KC*B*S
__global__ __launch_bounds__(256) void att_part_kernel(
    const float* __restrict__ q, const float* __restrict__ k,
    float* __restrict__ pd, int kd, int H, int Wd, int KC, int total)
{
  int idx = blockIdx.x * 256 + threadIdx.x;
  if (idx >= total) return;
  const int S = H * Wd;
  int p = idx % S;
  int t = idx / S;
  int n = t % B, kc = t / B;
  int x = p % Wd, y = p / Wd;
  int off[9]; bool ok[9];
#pragma unroll
  for (int j = 0; j < 9; ++j) {
    int dy = (j / 3) * 2 - 2, dx = (j % 3) * 2 - 2;
    int yy = y + dy, xx = x + dx;
    ok[j] = (yy >= 0 && yy < H && xx >= 0 && xx < Wd);
    off[j] = yy * Wd + xx;
  }
  float dot[9] = {0.f,0.f,0.f,0.f,0.f,0.f,0.f,0.f,0.f};
  const int cc = kd / KC;
  const int c0 = kc * cc;
  const float* qp = q + (size_t)n * kd * S + p;
  const float* kp = k + (size_t)n * kd * S;
  for (int c = c0; c < c0 + cc; ++c) {
    float qv = qp[(size_t)c * S];
    const float* kcp = kp + (size_t)c * S;
#pragma unroll
    for (int j = 0; j < 9; ++j)
      if (ok[j]) dot[j] = fmaf(qv, kcp[off[j]], dot[j]);
  }
  float* o = pd + ((size_t)(kc * B + n) * 9) * S + p;
#pragma unroll
  for (int j = 0; j < 9; ++j) o[(size_t)j * S] = dot[j];
}

// sum partial dots + softmax.  total = B*S
__global__ __launch_bounds__(256) void att_fin_kernel(
    const float* __restrict__ pd, float* __restrict__ att,
    int KC, int S, int total)
{
  int idx = blockIdx.x * 256 + threadIdx.x;
  if (idx >= total) return;
  int p = idx % S, n = idx / S;
  float dot[9] = {0.f,0.f,0.f,0.f,0.f,0.f,0.f,0.f,0.f};
  for (int kc = 0; kc < KC; ++kc) {
    const float* o = pd + ((size_t)(kc * B + n) * 9) * S + p;
#pragma unroll
    for (int j = 0; j < 9; ++j) dot[j] += o[(size_t)j * S];
  }
  float m = dot[0];
#pragma unroll
  for (int j = 1; j < 9; ++j) m = fmaxf(m, dot[j]);
  float e[9], ssum = 0.f;
#pragma unroll
  for (int j = 0; j < 9; ++j) { e[j] = __expf(dot[j] - m); ssum += e[j]; }
  float inv = 1.f / ssum;
#pragma unroll
  for (int j = 0; j < 9; ++j)
    att[((size_t)n * 9 + j) * S + p] = e[j] * inv;
}

// -------- fused: out[n,c,p] = sum_j att[n,j,p] * bilerp(prev[n,c], tap_j(p)) --------
__global__ __launch_bounds__(256) void apply_up_kernel(
    const float* __restrict__ att, const float* __restrict__ prev,
    float* __restrict__ out, int C, int H, int Wd, int h2, int w2, int total)
{
  int idx = blockIdx.x * 256 + threadIdx.x;
  if (idx >= total) return;
  const int S = H * Wd;
  int p = idx % S;
  int t = idx / S;
  int c = t % C, n = t / C;
  int x = p % Wd, y = p / Wd;
  const float rh = (float)(h2 - 1) / (float)(H - 1);
  const float rw = (float)(w2 - 1) / (float)(Wd - 1);
  const float* ap = att + (size_t)n * 9 * S + p;
  const float* pc = prev + ((size_t)n * C + c) * h2 * w2;
  float v = 0.f;
#pragma unroll
  for (int j = 0; j < 9; ++j) {
    int dy = (j / 3) * 2 - 2, dx = (j % 3) * 2 - 2;
    int yy = y + dy, xx = x + dx;
    if (yy >= 0 && yy < H && xx >= 0 && xx < Wd) {
      float fy = yy * rh, fx = xx * rw;
      int y0 = (int)fy; if (y0 > h2 - 1) y0 = h2 - 1;
      int x0 = (int)fx; if (x0 > w2 - 1) x0 = w2 - 1;
      int y1 = min(y0 + 1, h2 - 1), x1 = min(x0 + 1, w2 - 1);
      float wy = fy - y0, wx = fx - x0;
      float v00 = pc[y0 * w2 + x0], v01 = pc[y0 * w2 + x1];
      float v10 = pc[y1 * w2 + x0], v11 = pc[y1 * w2 + x1];
      float b = (v00 * (1.f - wy) + v10 * wy) * (1.f - wx) +
                (v01 * (1.f - wy) + v11 * wy) * wx;
      v = fmaf(ap[(size_t)j * S], b, v);
    }
  }
  out[idx] = v;
}

// -------- final: d_out[n,o,p] = b[o] + sum_j att2[j,p] * bilerp(v6s[n,o], tap_j(p)) --
template <typename TP>
__global__ __launch_bounds__(256) void final_kernel(
    const float* __restrict__ att, const float* __restrict__ v6s,
    const TP* __restrict__ bias, TP* __restrict__ out, int total,
    const int* __restrict__ flag, int want)
{
  if (flag[0] != want) return;
  int idx = blockIdx.x * 256 + threadIdx.x;
  if (idx >= total) return;
  const int H = 128, Wd = 128, h2 = 64, w2 = 64;
  const int S = H * Wd;
  int p = idx % S;
  int t = idx / S;
  int o = t % 19, n = t / 19;
  int x = p % Wd, y = p / Wd;
  const float rh = (float)(h2 - 1) / (float)(H - 1);
  const float rw = (float)(w2 - 1) / (float)(Wd - 1);
  const float* ap = att + (size_t)n * 9 * S + p;
  const float* pc = v6s + ((size_t)n * 19 + o) * h2 * w2;
  float v = toF(bias[o]);
#pragma unroll
  for (int j = 0; j < 9; ++j) {
    int dy = (j / 3) * 2 - 2, dx = (j % 3) * 2 - 2;
    int yy = y + dy, xx = x + dx;
    if (yy >= 0 && yy < H && xx >= 0 && xx < Wd) {
      float fy = yy * rh, fx = xx * rw;
      int y0 = (int)fy; if (y0 > h2 - 1) y0 = h2 - 1;
      int x0 = (int)fx; if (x0 > w2 - 1) x0 = w2 - 1;
      int y1 = min(y0 + 1, h2 - 1), x1 = min(x0 + 1, w2 - 1);
      float wy = fy - y0, wx = fx - x0;
      float v00 = pc[y0 * w2 + x0], v01 = pc[y0 * w2 + x1];
      float v10 = pc[y1 * w2 + x0], v11 = pc[y1 * w2 + x1];
      float b = (v00 * (1.f - wy) + v10 * wy) * (1.f - wx) +
                (v01 * (1.f - wy) + v11 * wy) * wx;
      v = fmaf(ap[(size_t)j * S], b, v);
    }
  }
  stF(&out[idx], v);
}

typedef __hip_bfloat16 bf16;

extern "C" void kernel_launch(void* const* d_in, const int* in_sizes, int n_in,
                              void* d_out, int out_size, void* d_ws, size_t ws_size,
                              hipStream_t stream) {
  (void)in_sizes; (void)n_in; (void)out_size; (void)ws_size;

  float* ws = (float*)d_ws;   // fp32 workspace, 13,584,385 floats = 51.8 MiB
  float* p5   = ws + 0;          // 1,048,576
  float* t5   = ws + 1048576;    //   262,144
  float* q4   = ws + 1310720;    //   262,144
  float* k4s  = ws + 1572864;    //    65,536
  float* k4   = ws + 1638400;    //   262,144
  float* att4 = ws + 1900544;    //    18,432
  float* o4   = ws + 1918976;    // 1,048,576
  float* q3   = ws + 2967552;    //   524,288
  float* k3s  = ws + 3491840;    //   131,072
  float* k3   = ws + 3622912;    //   524,288
  float* att3 = ws + 4147200;    //    73,728
  float* o3   = ws + 4220928;    // 4,194,304
  float* v6s  = ws + 8415232;    //   155,648
  float* q2   = ws + 8570880;    // 2,097,152
  float* k2s  = ws + 10668032;   //   524,288
  float* k2   = ws + 11192320;   // 2,097,152
  float* att2 = ws + 13289472;   //   294,912
  int*   flag = (int*)(ws + 13584384);

  // conv5 split buffers (each 2,359,296 float-units = 4,718,592 bf16).
  // Live only during conv5; overlap q4..o3 regions (all written later).
  unsigned short* whi = (unsigned short*)(ws + 1310720);
  unsigned short* wlo = (unsigned short*)(ws + 3670016);
  unsigned short* xhi = (unsigned short*)(ws + 6029312);
  unsigned short* xlo = (unsigned short*)(ws + 8388608);   // ends at 10,747,904

  // split-C conv scratch (temporally dead regions, verified against dataflow):
  float* scQ4  = ws + 4220928;   // 2,097,152  (o3 region; o3 written in stage 3)
  float* scK4s = ws + 6318080;   // 1,048,576  (o3 region)
  float* scQ3  = ws + 8570880;   // 2,097,152  (q2 region; q2 written in stage 2)
  float* scK3s = ws + 11192320;  // 1,048,576  (k2 region; k2 written in stage 2)
  float* scK2s = ws + 11192320;  // 2,097,152  (k2 region; k2 written after k2s reduce)
  float* scV6  = ws + 8570880;   //   622,592  (q2 region; q2 dead after att2)
  float* scAtt = ws + 0;         //  <=294,912 (p5 region; p5 dead after finalize5)

  probe_kernel<<<1, 64, 0, stream>>>((const unsigned short*)d_in[0], flag);

  // Launch both dtype variants; the probe flag selects which one executes.
#define DUAL(CALL_BF, CALL_F32) do { CALL_BF; CALL_F32; } while (0)

  // ---- conv5 + BN + ReLU: split-bf16 MFMA GEMM, two K-phases ----
  for (int ph = 0; ph < 2; ++ph) {
    const int k0 = ph * 9216;
    split_w_f32 <<<4608, 256, 0, stream>>>((const float*)d_in[7], whi, wlo, k0, flag);
    split_w_bf16<<<4608, 256, 0, stream>>>((const unsigned short*)d_in[7], whi, wlo, k0, flag);
    im2col_split_f32 <<<18432, 256, 0, stream>>>((const float*)d_in[3], xhi, xlo, k0, flag);
    im2col_split_bf16<<<18432, 256, 0, stream>>>((const unsigned short*)d_in[3], xhi, xlo, k0, flag);
    conv5_gemm_kernel<<<dim3(64, 2), 256, 0, stream>>>(whi, wlo, xhi, xlo, p5, ph * 2);
  }
  DUAL(
    (finalize5_kernel<bf16><<<1024, 256, 0, stream>>>(p5, (const bf16*)d_in[8], t5, flag, 1)),
    (finalize5_kernel<float><<<1024, 256, 0, stream>>>(p5, (const float*)d_in[8], t5, flag, 0)));

  // ---- localUp stage 4 (H=32, kd=128): c_hi=c3, c_lo=c40, prev=t5 ----
  // q4 = BN(conv1x1(c3)) : C=1024, O=128, S=1024, KS=8 -> 512 blocks
  DUAL(
    (conv1x1_part_kernel<bf16, bf16><<<dim3(16, 2, B * 8), 256, 0, stream>>>((const bf16*)d_in[2], (const bf16*)d_in[11], scQ4, 1024, 128, 1024, 8, flag, 1)),
    (conv1x1_part_kernel<float, float><<<dim3(16, 2, B * 8), 256, 0, stream>>>((const float*)d_in[2], (const float*)d_in[11], scQ4, 1024, 128, 1024, 8, flag, 0)));
  DUAL(
    (reduce_bn_kernel<bf16><<<1024, 256, 0, stream>>>(scQ4, (const bf16*)d_in[12], q4, 128, 1024, 8, 262144, flag, 1)),
    (reduce_bn_kernel<float><<<1024, 256, 0, stream>>>(scQ4, (const float*)d_in[12], q4, 128, 1024, 8, 262144, flag, 0)));
  // k4s = BN(conv1x1(c40)) : C=2048, O=128, S=256, KS=16 -> 256 blocks
  DUAL(
    (conv1x1_part_kernel<bf16, bf16><<<dim3(4, 2, B * 16), 256, 0, stream>>>((const bf16*)d_in[6], (const bf16*)d_in[13], scK4s, 2048, 128, 256, 16, flag, 1)),
    (conv1x1_part_kernel<float, float><<<dim3(4, 2, B * 16), 256, 0, stream>>>((const float*)d_in[6], (const float*)d_in[13], scK4s, 2048, 128, 256, 16, flag, 0)));
  DUAL(
    (reduce_bn_kernel<bf16><<<256, 256, 0, stream>>>(scK4s, (const bf16*)d_in[14], k4s, 128, 256, 16, 65536, flag, 1)),
    (reduce_bn_kernel<float><<<256, 256, 0, stream>>>(scK4s, (const float*)d_in[14], k4s, 128, 256, 16, 65536, flag, 0)));
  upsample2x_kernel<<<1024, 256, 0, stream>>>(k4s, k4, 16, 16, B * 128 * 1024);
  // att4: kd=128, S=1024; KC=8 -> 64 blocks part + fin
  att_part_kernel<<<64, 256, 0, stream>>>(q4, k4, scAtt, 128, 32, 32, 8, 8 * B * 1024);
  att_fin_kernel<<<8, 256, 0, stream>>>(scAtt, att4, 8, 1024, B * 1024);
  apply_up_kernel<<<4096, 256, 0, stream>>>(att4, t5, o4, 512, 32, 32, 16, 16, B * 512 * 1024);

  // ---- localUp stage 3 (H=64, kd=64): c_hi=c2, c_lo=c30, prev=o4 ----
  // q3 : C=512, O=64, S=4096, KS=4 -> 512 blocks
  DUAL(
    (conv1x1_part_kernel<bf16, bf16><<<dim3(64, 1, B * 4), 256, 0, stream>>>((const bf16*)d_in[1], (const bf16*)d_in[15], scQ3, 512, 64, 4096, 4, flag, 1)),
    (conv1x1_part_kernel<float, float><<<dim3(64, 1, B * 4), 256, 0, stream>>>((const float*)d_in[1], (const float*)d_in[15], scQ3, 512, 64, 4096, 4, flag, 0)));
  DUAL(
    (reduce_bn_kernel<bf16><<<2048, 256, 0, stream>>>(scQ3, (const bf16*)d_in[16], q3, 64, 4096, 4, 524288, flag, 1)),
    (reduce_bn_kernel<float><<<2048, 256, 0, stream>>>(scQ3, (const float*)d_in[16], q3, 64, 4096, 4, 524288, flag, 0)));
  // k3s : C=1024, O=64, S=1024, KS=8 -> 256 blocks
  DUAL(
    (conv1x1_part_kernel<bf16, bf16><<<dim3(16, 1, B * 8), 256, 0, stream>>>((const bf16*)d_in[5], (const bf16*)d_in[17], scK3s, 1024, 64, 1024, 8, flag, 1)),
    (conv1x1_part_kernel<float, float><<<dim3(16, 1, B * 8), 256, 0, stream>>>((const float*)d_in[5], (const float*)d_in[17], scK3s, 1024, 64, 1024, 8, flag, 0)));
  DUAL(
    (reduce_bn_kernel<bf16><<<512, 256, 0, stream>>>(scK3s, (const bf16*)d_in[18], k3s, 64, 1024, 8, 131072, flag, 1)),
    (reduce_bn_kernel<float><<<512, 256, 0, stream>>>(scK3s, (const float*)d_in[18], k3s, 64, 1024, 8, 131072, flag, 0)));
  upsample2x_kernel<<<2048, 256, 0, stream>>>(k3s, k3, 32, 32, B * 64 * 4096);
  // att3: kd=64, S=4096; KC=4 -> 128 blocks part + fin
  att_part_kernel<<<128, 256, 0, stream>>>(q3, k3, scAtt, 64, 64, 64, 4, 4 * B * 4096);
  att_fin_kernel<<<32, 256, 0, stream>>>(scAtt, att3, 4, 4096, B * 4096);
  apply_up_kernel<<<16384, 256, 0, stream>>>(att3, o4, o3, 512, 64, 64, 32, 32, B * 512 * 4096);

  // ---- localUp stage 2 (H=128, kd=64): c_hi=c1, c_lo=c2, prev=o3; conv6 commuted ----
  // q2 : C=256, S=16384 -> 512 blocks direct (occupancy OK)
  DUAL(
    (conv1x1_kernel<bf16, bf16><<<dim3(256, 1, B), 256, 0, stream>>>((const bf16*)d_in[0], (const bf16*)d_in[19], (const bf16*)d_in[20], q2, 256, 64, 16384, flag, 1)),
    (conv1x1_kernel<float, float><<<dim3(256, 1, B), 256, 0, stream>>>((const float*)d_in[0], (const float*)d_in[19], (const float*)d_in[20], q2, 256, 64, 16384, flag, 0)));
  // k2s : C=512, O=64, S=4096, KS=4 -> 512 blocks
  DUAL(
    (conv1x1_part_kernel<bf16, bf16><<<dim3(64, 1, B * 4), 256, 0, stream>>>((const bf16*)d_in[1], (const bf16*)d_in[21], scK2s, 512, 64, 4096, 4, flag, 1)),
    (conv1x1_part_kernel<float, float><<<dim3(64, 1, B * 4), 256, 0, stream>>>((const float*)d_in[1], (const float*)d_in[21], scK2s, 512, 64, 4096, 4, flag, 0)));
  DUAL(
    (reduce_bn_kernel<bf16><<<2048, 256, 0, stream>>>(scK2s, (const bf16*)d_in[22], k2s, 64, 4096, 4, 524288, flag, 1)),
    (reduce_bn_kernel<float><<<2048, 256, 0, stream>>>(scK2s, (const float*)d_in[22], k2s, 64, 4096, 4, 524288, flag, 0)));
  upsample2x_kernel<<<8192, 256, 0, stream>>>(k2s, k2, 64, 64, B * 64 * 16384);
  att_kernel<<<128, 256, 0, stream>>>(q2, k2, att2, 64, 128, 128, B * 16384);
  // v6s = conv6(o3) at 64x64 : C=512, O=19, S=4096, KS=4 -> 512 blocks (no BN)
  DUAL(
    (conv1x1_part_kernel<float, bf16><<<dim3(64, 1, B * 4), 256, 0, stream>>>(o3, (const bf16*)d_in[9], scV6, 512, 19, 4096, 4, flag, 1)),
    (conv1x1_part_kernel<float, float><<<dim3(64, 1, B * 4), 256, 0, stream>>>(o3, (const float*)d_in[9], scV6, 512, 19, 4096, 4, flag, 0)));
  DUAL(
    (reduce_bn_kernel<bf16><<<608, 256, 0, stream>>>(scV6, (const bf16*)nullptr, v6s, 19, 4096, 4, 155648, flag, 1)),
    (reduce_bn_kernel<float><<<608, 256, 0, stream>>>(scV6, (const float*)nullptr, v6s, 19, 4096, 4, 155648, flag, 0)));
  DUAL(
    (final_kernel<bf16><<<2432, 256, 0, stream>>>(att2, v6s, (const bf16*)d_in[10], (bf16*)d_out, B * 19 * 16384, flag, 1)),
    (final_kernel<float><<<2432, 256, 0, stream>>>(att2, v6s, (const float*)d_in[10], (float*)d_out, B * 19 * 16384, flag, 0)));
}

// Round 5
// 678.027 us; speedup vs baseline: 2.8802x; 1.1020x over previous
//
#include <hip/hip_runtime.h>
#include <hip/hip_bf16.h>
#include <math.h>

#define B 2

typedef __attribute__((ext_vector_type(8))) short bf16x8;
typedef __attribute__((ext_vector_type(4))) float f32x4;

// bf16 RNE on raw bits (inputs have no NaN/Inf)
__device__ __forceinline__ unsigned short f2bf(float f) {
  unsigned int u = __float_as_uint(f);
  return (unsigned short)((u + 0x7FFFu + ((u >> 16) & 1u)) >> 16);
}
__device__ __forceinline__ float bf2f(unsigned short h) {
  return __uint_as_float((unsigned int)h << 16);
}

// ---------------- dtype probe: flag=1 if buffer is bf16, 0 if f32 ----------------
__global__ void probe_kernel(const unsigned short* __restrict__ x, int* __restrict__ flag) {
  if (threadIdx.x == 0 && blockIdx.x == 0) {
    int sane = 0;
    for (int i = 0; i < 512; ++i) {
      int e = (x[i] >> 7) & 0xFF;
      if (e >= 97 && e <= 157) ++sane;
    }
    flag[0] = (sane >= 480) ? 1 : 0;
  }
}

// =============== conv5 via split-bf16 MFMA (f32 AND bf16 inputs, unified) ===========
// x -> hi = bf16(x), lo = bf16(x - hi); A.B ~= Ah.Bh + Ah.Bl + Al.Bh

__global__ __launch_bounds__(256) void split_w_kernel(
    const float* __restrict__ wf, const unsigned short* __restrict__ wb,
    unsigned short* __restrict__ hi, unsigned short* __restrict__ lo,
    int k0, const int* __restrict__ flag)
{
  const int isbf = flag[0];
  int e = (blockIdx.x * 256 + threadIdx.x) * 4;     // 4,718,592 total elements
  int row = e / 9216, kl = e % 9216;
  size_t src = (size_t)row * 18432 + k0 + kl;
  ushort4 h, l;
  if (isbf) {
    h = *(const ushort4*)(wb + src);
    l.x = 0; l.y = 0; l.z = 0; l.w = 0;
  } else {
    float4 x = *(const float4*)(wf + src);
    float xs[4] = {x.x, x.y, x.z, x.w};
    unsigned short hs[4], ls[4];
#pragma unroll
    for (int i = 0; i < 4; ++i) {
      hs[i] = f2bf(xs[i]);
      ls[i] = f2bf(xs[i] - bf2f(hs[i]));
    }
    h.x = hs[0]; h.y = hs[1]; h.z = hs[2]; h.w = hs[3];
    l.x = ls[0]; l.y = ls[1]; l.z = ls[2]; l.w = ls[3];
  }
  *(ushort4*)(hi + e) = h;
  *(ushort4*)(lo + e) = l;
}

// im2col split: X[r=n*256+px][kl], K=k0+kl=c*9+t, 3x3 pad 1
__global__ __launch_bounds__(256) void im2col_split_kernel(
    const float* __restrict__ cf, const unsigned short* __restrict__ cb,
    unsigned short* __restrict__ xhi, unsigned short* __restrict__ xlo,
    int k0, const int* __restrict__ flag)
{
  const int isbf = flag[0];
  int idx = blockIdx.x * 256 + threadIdx.x;         // 4,718,592 total
  int kl = idx % 9216, r = idx / 9216;
  int K = k0 + kl;
  int c = K / 9, t = K - c * 9;
  int n = r >> 8, px = r & 255;
  int x = px & 15, y = px >> 4;
  int yy = y + t / 3 - 1, xx = x + t % 3 - 1;
  bool in = (yy >= 0 && yy < 16 && xx >= 0 && xx < 16);
  size_t src = (((size_t)n * 2048 + c) << 8) + yy * 16 + xx;
  unsigned short h, l;
  if (isbf) {
    h = in ? cb[src] : (unsigned short)0;
    l = 0;
  } else {
    float v = in ? cf[src] : 0.f;
    h = f2bf(v);
    l = f2bf(v - bf2f(h));
  }
  xhi[idx] = h;
  xlo[idx] = l;
}

// LDS XOR swizzle: permute 16B slots within each 128B row (involution, both sides).
__device__ __forceinline__ int swz(int b) { return b ^ (((b >> 7) & 7) << 4); }

// GEMM: part[q][oc][r] += over K-slice; M=N=512, slice K=2304 (36 steps). 64x64 tiles.
__global__ __launch_bounds__(256) void conv5_gemm_kernel(
    const unsigned short* __restrict__ Ah, const unsigned short* __restrict__ Al,
    const unsigned short* __restrict__ Bh, const unsigned short* __restrict__ Bl,
    float* __restrict__ part, int qbase)
{
  const int tile = blockIdx.x;            // 0..63 over 8x8 tiles
  const int ks   = blockIdx.y;            // 0..3 split-K within phase
  const int mo = (tile >> 3) * 64;        // oc tile base
  const int no = (tile & 7) * 64;         // r tile base
  const int kb = ks * 2304;
  const int tid = threadIdx.x;
  const int w = tid >> 6, lane = tid & 63;
  const int wr = w >> 1, wc = w & 1;      // 2x2 wave grid, each wave 32x32 out

  __shared__ unsigned short sAh[4096], sAl[4096], sBh[4096], sBl[4096];  // 32 KB

  const int row0 = tid >> 3, slot = tid & 7;
  const size_t a0 = (size_t)(mo + row0) * 9216 + kb + slot * 8;
  const size_t a1 = a0 + (size_t)32 * 9216;
  const size_t b0 = (size_t)(no + row0) * 9216 + kb + slot * 8;
  const size_t b1 = b0 + (size_t)32 * 9216;
  const int w0 = swz(row0 * 128 + slot * 16);
  const int w1 = swz((row0 + 32) * 128 + slot * 16);

  f32x4 acc[2][2];
#pragma unroll
  for (int m = 0; m < 2; ++m)
#pragma unroll
    for (int nn = 0; nn < 2; ++nn) acc[m][nn] = (f32x4){0.f, 0.f, 0.f, 0.f};

  bf16x8 rah0 = *(const bf16x8*)(Ah + a0), rah1 = *(const bf16x8*)(Ah + a1);
  bf16x8 ral0 = *(const bf16x8*)(Al + a0), ral1 = *(const bf16x8*)(Al + a1);
  bf16x8 rbh0 = *(const bf16x8*)(Bh + b0), rbh1 = *(const bf16x8*)(Bh + b1);
  bf16x8 rbl0 = *(const bf16x8*)(Bl + b0), rbl1 = *(const bf16x8*)(Bl + b1);

  const int arow = wr * 32 + (lane & 15);
  const int brow = wc * 32 + (lane & 15);
  const int cb = (lane >> 4) * 16;

  for (int kk = 0; kk < 2304; kk += 64) {
    *(bf16x8*)((char*)sAh + w0) = rah0;  *(bf16x8*)((char*)sAh + w1) = rah1;
    *(bf16x8*)((char*)sAl + w0) = ral0;  *(bf16x8*)((char*)sAl + w1) = ral1;
    *(bf16x8*)((char*)sBh + w0) = rbh0;  *(bf16x8*)((char*)sBh + w1) = rbh1;
    *(bf16x8*)((char*)sBl + w0) = rbl0;  *(bf16x8*)((char*)sBl + w1) = rbl1;
    if (kk + 64 < 2304) {
      rah0 = *(const bf16x8*)(Ah + a0 + kk + 64);
      rah1 = *(const bf16x8*)(Ah + a1 + kk + 64);
      ral0 = *(const bf16x8*)(Al + a0 + kk + 64);
      ral1 = *(const bf16x8*)(Al + a1 + kk + 64);
      rbh0 = *(const bf16x8*)(Bh + b0 + kk + 64);
      rbh1 = *(const bf16x8*)(Bh + b1 + kk + 64);
      rbl0 = *(const bf16x8*)(Bl + b0 + kk + 64);
      rbl1 = *(const bf16x8*)(Bl + b1 + kk + 64);
    }
    __syncthreads();
#pragma unroll
    for (int k2 = 0; k2 < 2; ++k2) {
      const int colb = k2 * 64 + cb;
      bf16x8 fah[2], fal[2], fbh[2], fbl[2];
#pragma unroll
      for (int m = 0; m < 2; ++m) {
        fah[m] = *(const bf16x8*)((char*)sAh + swz((arow + m * 16) * 128 + colb));
        fal[m] = *(const bf16x8*)((char*)sAl + swz((arow + m * 16) * 128 + colb));
      }
#pragma unroll
      for (int nn = 0; nn < 2; ++nn) {
        fbh[nn] = *(const bf16x8*)((char*)sBh + swz((brow + nn * 16) * 128 + colb));
        fbl[nn] = *(const bf16x8*)((char*)sBl + swz((brow + nn * 16) * 128 + colb));
      }
#pragma unroll
      for (int m = 0; m < 2; ++m)
#pragma unroll
        for (int nn = 0; nn < 2; ++nn) {
          acc[m][nn] = __builtin_amdgcn_mfma_f32_16x16x32_bf16(fah[m], fbh[nn], acc[m][nn], 0, 0, 0);
          acc[m][nn] = __builtin_amdgcn_mfma_f32_16x16x32_bf16(fah[m], fbl[nn], acc[m][nn], 0, 0, 0);
          acc[m][nn] = __builtin_amdgcn_mfma_f32_16x16x32_bf16(fal[m], fbh[nn], acc[m][nn], 0, 0, 0);
        }
    }
    __syncthreads();
  }

  // C/D layout: col = lane&15 (-> r), row = (lane>>4)*4 + j (-> oc)
  const int quarter = qbase + ks;       // 0..7
#pragma unroll
  for (int m = 0; m < 2; ++m)
#pragma unroll
    for (int nn = 0; nn < 2; ++nn) {
      const int r = no + wc * 32 + nn * 16 + (lane & 15);
      const int n = r >> 8, px = r & 255;
#pragma unroll
      for (int j = 0; j < 4; ++j) {
        const int oc = mo + wr * 32 + m * 16 + (lane >> 4) * 4 + j;
        part[(size_t)quarter * 262144 + ((size_t)n * 512 + oc) * 256 + px] = acc[m][nn][j];
      }
    }
}

// sum 8 K-slices + BN + ReLU -> t5
__global__ __launch_bounds__(256) void finalize5_kernel(
    const float* __restrict__ part, const float* __restrict__ bnf,
    const unsigned short* __restrict__ bnb, float* __restrict__ t5,
    const int* __restrict__ flag)
{
  int idx = blockIdx.x * 256 + threadIdx.x;   // 262144 total
  int oc = (idx >> 8) & 511;
  float s = 0.f;
#pragma unroll
  for (int q = 0; q < 8; ++q) s += part[(size_t)q * 262144 + idx];
  float g, b, m, v;
  if (flag[0]) {
    g = bf2f(bnb[oc]); b = bf2f(bnb[512 + oc]);
    m = bf2f(bnb[1024 + oc]); v = bf2f(bnb[1536 + oc]);
  } else {
    g = bnf[oc]; b = bnf[512 + oc]; m = bnf[1024 + oc]; v = bnf[1536 + oc];
  }
  float sc = g * rsqrtf(v + 1e-5f);
  float val = s * sc + (b - m * sc);
  t5[idx] = fmaxf(val, 0.f);
}

// ---------------- split-C 1x1 conv partials (unified dtype) ----------------
// blockIdx.z = n*KS + kc; part[kc*(B*O*S) + (n*O + o)*S + s]
__global__ __launch_bounds__(256) void conv1x1_part_kernel(
    const float* __restrict__ Xf, const unsigned short* __restrict__ Xb,
    const float* __restrict__ Wf, const unsigned short* __restrict__ Wb,
    float* __restrict__ part, int C, int O, int S, int KS, int xf32,
    const int* __restrict__ flag)
{
  const int isbf = flag[0];
  const int xbf = xf32 ? 0 : isbf;
  const int tid = threadIdx.x;
  const int sg = tid & 15, og = tid >> 4;
  const int s0 = blockIdx.x * 64;
  const int o0 = blockIdx.y * 64;
  const int n  = blockIdx.z / KS;
  const int kc = blockIdx.z % KS;
  const int CC = C / KS;
  const int cbase = kc * CC;

  __shared__ float xs[16][64];
  __shared__ float wsT[16][68];

  float acc[4][4];
#pragma unroll
  for (int i = 0; i < 4; ++i)
#pragma unroll
    for (int j = 0; j < 4; ++j) acc[i][j] = 0.f;

  for (int c0 = cbase; c0 < cbase + CC; c0 += 16) {
    if (xbf) {
#pragma unroll
      for (int r = 0; r < 4; ++r) {
        int e = tid + r * 256, cc = e >> 6, ssv = e & 63;
        xs[cc][ssv] = bf2f(Xb[((size_t)n * C + c0 + cc) * S + s0 + ssv]);
      }
    } else {
#pragma unroll
      for (int r = 0; r < 4; ++r) {
        int e = tid + r * 256, cc = e >> 6, ssv = e & 63;
        xs[cc][ssv] = Xf[((size_t)n * C + c0 + cc) * S + s0 + ssv];
      }
    }
    if (isbf) {
#pragma unroll
      for (int r = 0; r < 4; ++r) {
        int e = tid + r * 256, oo = e >> 4, cc = e & 15;
        int o = o0 + oo;
        wsT[cc][oo] = (o < O) ? bf2f(Wb[(size_t)o * C + c0 + cc]) : 0.f;
      }
    } else {
#pragma unroll
      for (int r = 0; r < 4; ++r) {
        int e = tid + r * 256, oo = e >> 4, cc = e & 15;
        int o = o0 + oo;
        wsT[cc][oo] = (o < O) ? Wf[(size_t)o * C + c0 + cc] : 0.f;
      }
    }
    __syncthreads();
#pragma unroll
    for (int c = 0; c < 16; ++c) {
      const float4 xv = *(const float4*)&xs[c][sg * 4];
      const float4 wv = *(const float4*)&wsT[c][og * 4];
      acc[0][0] = fmaf(wv.x, xv.x, acc[0][0]);
      acc[0][1] = fmaf(wv.x, xv.y, acc[0][1]);
      acc[0][2] = fmaf(wv.x, xv.z, acc[0][2]);
      acc[0][3] = fmaf(wv.x, xv.w, acc[0][3]);
      acc[1][0] = fmaf(wv.y, xv.x, acc[1][0]);
      acc[1][1] = fmaf(wv.y, xv.y, acc[1][1]);
      acc[1][2] = fmaf(wv.y, xv.z, acc[1][2]);
      acc[1][3] = fmaf(wv.y, xv.w, acc[1][3]);
      acc[2][0] = fmaf(wv.z, xv.x, acc[2][0]);
      acc[2][1] = fmaf(wv.z, xv.y, acc[2][1]);
      acc[2][2] = fmaf(wv.z, xv.z, acc[2][2]);
      acc[2][3] = fmaf(wv.z, xv.w, acc[2][3]);
      acc[3][0] = fmaf(wv.w, xv.x, acc[3][0]);
      acc[3][1] = fmaf(wv.w, xv.y, acc[3][1]);
      acc[3][2] = fmaf(wv.w, xv.z, acc[3][2]);
      acc[3][3] = fmaf(wv.w, xv.w, acc[3][3]);
    }
    __syncthreads();
  }

  const size_t BOS = (size_t)B * O * S;
#pragma unroll
  for (int i = 0; i < 4; ++i) {
    int o = o0 + og * 4 + i;
    if (o < O) {
      float4 r;
      r.x = acc[i][0]; r.y = acc[i][1]; r.z = acc[i][2]; r.w = acc[i][3];
      *(float4*)(part + (size_t)kc * BOS + ((size_t)n * O + o) * S + s0 + sg * 4) = r;
    }
  }
}

// sum KS partials + optional BN -> Y.  total = B*O*S
__global__ __launch_bounds__(256) void reduce_bn_kernel(
    const float* __restrict__ part, const float* __restrict__ bnf,
    const unsigned short* __restrict__ bnb, int hasbn,
    float* __restrict__ Y, int O, int S, int KS, int total,
    const int* __restrict__ flag)
{
  int idx = blockIdx.x * 256 + threadIdx.x;
  if (idx >= total) return;
  float s = 0.f;
  for (int kc = 0; kc < KS; ++kc) s += part[(size_t)kc * total + idx];
  float sc = 1.f, sh = 0.f;
  if (hasbn) {
    int o = (idx / S) % O;
    float g, b, m, v;
    if (flag[0]) {
      g = bf2f(bnb[o]); b = bf2f(bnb[O + o]);
      m = bf2f(bnb[2 * O + o]); v = bf2f(bnb[3 * O + o]);
    } else {
      g = bnf[o]; b = bnf[O + o]; m = bnf[2 * O + o]; v = bnf[3 * O + o];
    }
    sc = g * rsqrtf(v + 1e-5f);
    sh = b - m * sc;
  }
  Y[idx] = s * sc + sh;
}

// ---------------- bilinear 2x upsample, align_corners=True ----------------
__global__ __launch_bounds__(256) void upsample2x_kernel(
    const float* __restrict__ in, float* __restrict__ out,
    int h, int w, int total)
{
  int idx = blockIdx.x * 256 + threadIdx.x;
  if (idx >= total) return;
  const int Wd = 2 * w, Hd = 2 * h;
  int xo = idx % Wd;
  int t  = idx / Wd;
  int yo = t % Hd;
  int pl = t / Hd;
  const float rh = (float)(h - 1) / (float)(Hd - 1);
  const float rw = (float)(w - 1) / (float)(Wd - 1);
  float fy = yo * rh, fx = xo * rw;
  int y0 = (int)fy; if (y0 > h - 1) y0 = h - 1;
  int x0 = (int)fx; if (x0 > w - 1) x0 = w - 1;
  int y1 = min(y0 + 1, h - 1), x1 = min(x0 + 1, w - 1);
  float wy = fy - y0, wx = fx - x0;
  const float* p = in + (size_t)pl * h * w;
  float v00 = p[y0 * w + x0], v01 = p[y0 * w + x1];
  float v10 = p[y1 * w + x0], v11 = p[y1 * w + x1];
  out[idx] = (v00 * (1.f - wy) + v10 * wy) * (1.f - wx) +
             (v01 * (1.f - wy) + v11 * wy) * wx;
}

// ---- kd-split attention: partial dots.  pd[((kc*B + n)*9 + j)*S + p] ----
__global__ __launch_bounds__(256) void att_part_kernel(
    const float* __restrict__ q, const float* __restrict__ k,
    float* __restrict__ pd, int kd, int H, int Wd, int KC, int total)
{
  int idx = blockIdx.x * 256 + threadIdx.x;
  if (idx >= total) return;
  const int S = H * Wd;
  int p = idx % S;
  int t = idx / S;
  int n = t % B, kc = t / B;
  int x = p % Wd, y = p / Wd;
  int off[9]; bool ok[9];
#pragma unroll
  for (int j = 0; j < 9; ++j) {
    int dy = (j / 3) * 2 - 2, dx = (j % 3) * 2 - 2;
    int yy = y + dy, xx = x + dx;
    ok[j] = (yy >= 0 && yy < H && xx >= 0 && xx < Wd);
    off[j] = yy * Wd + xx;
  }
  float dot[9] = {0.f,0.f,0.f,0.f,0.f,0.f,0.f,0.f,0.f};
  const int cc = kd / KC;
  const int c0 = kc * cc;
  const float* qp = q + (size_t)n * kd * S + p;
  const float* kp = k + (size_t)n * kd * S;
  for (int c = c0; c < c0 + cc; ++c) {
    float qv = qp[(size_t)c * S];
    const float* kcp = kp + (size_t)c * S;
#pragma unroll
    for (int j = 0; j < 9; ++j)
      if (ok[j]) dot[j] = fmaf(qv, kcp[off[j]], dot[j]);
  }
  float* o = pd + ((size_t)(kc * B + n) * 9) * S + p;
#pragma unroll
  for (int j = 0; j < 9; ++j) o[(size_t)j * S] = dot[j];
}

// sum partial dots + softmax.  total = B*S
__global__ __launch_bounds__(256) void att_fin_kernel(
    const float* __restrict__ pd, float* __restrict__ att,
    int KC, int S, int total)
{
  int idx = blockIdx.x * 256 + threadIdx.x;
  if (idx >= total) return;
  int p = idx % S, n = idx / S;
  float dot[9] = {0.f,0.f,0.f,0.f,0.f,0.f,0.f,0.f,0.f};
  for (int kc = 0; kc < KC; ++kc) {
    const float* o = pd + ((size_t)(kc * B + n) * 9) * S + p;
#pragma unroll
    for (int j = 0; j < 9; ++j) dot[j] += o[(size_t)j * S];
  }
  float m = dot[0];
#pragma unroll
  for (int j = 1; j < 9; ++j) m = fmaxf(m, dot[j]);
  float e[9], ssum = 0.f;
#pragma unroll
  for (int j = 0; j < 9; ++j) { e[j] = __expf(dot[j] - m); ssum += e[j]; }
  float inv = 1.f / ssum;
#pragma unroll
  for (int j = 0; j < 9; ++j)
    att[((size_t)n * 9 + j) * S + p] = e[j] * inv;
}

// -------- apply: 4 channels/thread; out[n,c,p] = sum_j att[n,j,p]*bilerp(prev) -------
__global__ __launch_bounds__(256) void apply_up4_kernel(
    const float* __restrict__ att, const float* __restrict__ prev,
    float* __restrict__ out, int C, int H, int Wd, int h2, int w2, int total4)
{
  int idx = blockIdx.x * 256 + threadIdx.x;
  if (idx >= total4) return;
  const int S = H * Wd;
  const int CQ = C >> 2;
  int p = idx % S;
  int t = idx / S;
  int cq = t % CQ, n = t / CQ;
  int c0 = cq << 2;
  int x = p % Wd, y = p / Wd;
  const float rh = (float)(h2 - 1) / (float)(H - 1);
  const float rw = (float)(w2 - 1) / (float)(Wd - 1);
  const float* ap = att + (size_t)n * 9 * S + p;
  int o00[9], o01[9], o10[9], o11[9];
  float aw00[9], aw01[9], aw10[9], aw11[9];
#pragma unroll
  for (int j = 0; j < 9; ++j) {
    int dy = (j / 3) * 2 - 2, dx = (j % 3) * 2 - 2;
    int yy = y + dy, xx = x + dx;
    bool ok = (yy >= 0 && yy < H && xx >= 0 && xx < Wd);
    float a  = ok ? ap[(size_t)j * S] : 0.f;
    float fy = ok ? yy * rh : 0.f;
    float fx = ok ? xx * rw : 0.f;
    int y0 = (int)fy; if (y0 > h2 - 1) y0 = h2 - 1;
    int x0 = (int)fx; if (x0 > w2 - 1) x0 = w2 - 1;
    int y1 = min(y0 + 1, h2 - 1), x1 = min(x0 + 1, w2 - 1);
    float wy = fy - y0, wx = fx - x0;
    o00[j] = y0 * w2 + x0; o01[j] = y0 * w2 + x1;
    o10[j] = y1 * w2 + x0; o11[j] = y1 * w2 + x1;
    aw00[j] = a * (1.f - wy) * (1.f - wx);
    aw01[j] = a * (1.f - wy) * wx;
    aw10[j] = a * wy * (1.f - wx);
    aw11[j] = a * wy * wx;
  }
  const int cs = h2 * w2;
  const float* pc = prev + ((size_t)n * C + c0) * cs;
  float v0 = 0.f, v1 = 0.f, v2 = 0.f, v3 = 0.f;
#pragma unroll
  for (int j = 0; j < 9; ++j) {
    v0 = fmaf(pc[o00[j]], aw00[j], v0);
    v0 = fmaf(pc[o01[j]], aw01[j], v0);
    v0 = fmaf(pc[o10[j]], aw10[j], v0);
    v0 = fmaf(pc[o11[j]], aw11[j], v0);
    v1 = fmaf(pc[cs + o00[j]], aw00[j], v1);
    v1 = fmaf(pc[cs + o01[j]], aw01[j], v1);
    v1 = fmaf(pc[cs + o10[j]], aw10[j], v1);
    v1 = fmaf(pc[cs + o11[j]], aw11[j], v1);
    v2 = fmaf(pc[2 * cs + o00[j]], aw00[j], v2);
    v2 = fmaf(pc[2 * cs + o01[j]], aw01[j], v2);
    v2 = fmaf(pc[2 * cs + o10[j]], aw10[j], v2);
    v2 = fmaf(pc[2 * cs + o11[j]], aw11[j], v2);
    v3 = fmaf(pc[3 * cs + o00[j]], aw00[j], v3);
    v3 = fmaf(pc[3 * cs + o01[j]], aw01[j], v3);
    v3 = fmaf(pc[3 * cs + o10[j]], aw10[j], v3);
    v3 = fmaf(pc[3 * cs + o11[j]], aw11[j], v3);
  }
  float* op = out + ((size_t)n * C + c0) * S + p;
  op[0] = v0;
  op[(size_t)S] = v1;
  op[(size_t)2 * S] = v2;
  op[(size_t)3 * S] = v3;
}

// -------- final: d_out[n,o,p] = b[o] + sum_j att2[j,p]*bilerp(v6s[n,o],tap_j(p)) -----
__global__ __launch_bounds__(256) void final_kernel(
    const float* __restrict__ att, const float* __restrict__ v6s,
    const float* __restrict__ biasf, const unsigned short* __restrict__ biasb,
    float* __restrict__ outf, unsigned short* __restrict__ outb,
    int total, const int* __restrict__ flag)
{
  const int isbf = flag[0];
  int idx = blockIdx.x * 256 + threadIdx.x;
  if (idx >= total) return;
  const int H = 128, Wd = 128, h2 = 64, w2 = 64;
  const int S = H * Wd;
  int p = idx % S;
  int t = idx / S;
  int o = t % 19, n = t / 19;
  int x = p % Wd, y = p / Wd;
  const float rh = (float)(h2 - 1) / (float)(H - 1);
  const float rw = (float)(w2 - 1) / (float)(Wd - 1);
  const float* ap = att + (size_t)n * 9 * S + p;
  const float* pc = v6s + ((size_t)n * 19 + o) * h2 * w2;
  float v = isbf ? bf2f(biasb[o]) : biasf[o];
#pragma unroll
  for (int j = 0; j < 9; ++j) {
    int dy = (j / 3) * 2 - 2, dx = (j % 3) * 2 - 2;
    int yy = y + dy, xx = x + dx;
    if (yy >= 0 && yy < H && xx >= 0 && xx < Wd) {
      float fy = yy * rh, fx = xx * rw;
      int y0 = (int)fy; if (y0 > h2 - 1) y0 = h2 - 1;
      int x0 = (int)fx; if (x0 > w2 - 1) x0 = w2 - 1;
      int y1 = min(y0 + 1, h2 - 1), x1 = min(x0 + 1, w2 - 1);
      float wy = fy - y0, wx = fx - x0;
      float v00 = pc[y0 * w2 + x0], v01 = pc[y0 * w2 + x1];
      float v10 = pc[y1 * w2 + x0], v11 = pc[y1 * w2 + x1];
      float b = (v00 * (1.f - wy) + v10 * wy) * (1.f - wx) +
                (v01 * (1.f - wy) + v11 * wy) * wx;
      v = fmaf(ap[(size_t)j * S], b, v);
    }
  }
  if (isbf) outb[idx] = f2bf(v);
  else      outf[idx] = v;
}

typedef __hip_bfloat16 bf16;
typedef unsigned short u16;

extern "C" void kernel_launch(void* const* d_in, const int* in_sizes, int n_in,
                              void* d_out, int out_size, void* d_ws, size_t ws_size,
                              hipStream_t stream) {
  (void)in_sizes; (void)n_in; (void)out_size; (void)ws_size;

  float* ws = (float*)d_ws;   // fp32 workspace, 13,584,385 floats = 51.8 MiB
  // persistent stage buffers
  float* t5   = ws + 1048576;    //   262,144
  float* q4   = ws + 1310720;    //   262,144
  float* k4s  = ws + 1572864;    //    65,536
  float* k4   = ws + 1638400;    //   262,144
  float* att4 = ws + 1900544;    //    18,432
  float* o4   = ws + 1918976;    // 1,048,576
  float* q3   = ws + 2967552;    //   524,288
  float* k3s  = ws + 3491840;    //   131,072
  float* k3   = ws + 3622912;    //   524,288
  float* att3 = ws + 4147200;    //    73,728
  float* o3   = ws + 4220928;    // 4,194,304
  float* v6s  = ws + 8415232;    //   155,648
  float* q2   = ws + 8570880;    // 2,097,152
  float* k2s  = ws + 10668032;   //   524,288
  float* k2   = ws + 11192320;   // 2,097,152
  float* att2 = ws + 13289472;   //   294,912
  int*   flag = (int*)(ws + 13584384);

  // conv5 scratch: part8 (8 K-slices) + 4 split buffers; all dead after finalize5.
  float* part8 = ws + 1310720;                       // 2,097,152, ends 3,407,872
  u16* whi = (u16*)(ws + 4147200);                   // each 4,718,592 bf16
  u16* wlo = (u16*)(ws + 6506496);
  u16* xhi = (u16*)(ws + 8865792);
  u16* xlo = (u16*)(ws + 11225088);                  // ends 13,584,384

  // split-C / split-kd scratch (temporally dead regions at their use time):
  float* scQ4   = ws + 4220928;   // 2,097,152 (o3 region)
  float* scK4s  = ws + 6318080;   // 1,048,576 (o3 region)
  float* scQ3   = ws + 8570880;   // 2,097,152 (q2 region)
  float* scK3s  = ws + 11192320;  // 1,048,576 (k2 region)
  float* scQ2   = ws + 0;         // 4,194,304 (p5..att3 regions, all dead)
  float* scK2s  = ws + 11192320;  // 2,097,152 (k2 region)
  float* scV6   = ws + 8570880;   //   622,592 (q2 region, dead after att2)
  float* scAtt  = ws + 0;         // stage4: 294,912; stage3: 589,824; stage2: 2,359,296

  probe_kernel<<<1, 64, 0, stream>>>((const unsigned short*)d_in[0], flag);

  // ---- conv5 + BN + ReLU: split-bf16 MFMA GEMM, 2 phases x 4 K-slices ----
  for (int ph = 0; ph < 2; ++ph) {
    const int k0 = ph * 9216;
    split_w_kernel<<<4608, 256, 0, stream>>>(
        (const float*)d_in[7], (const u16*)d_in[7], whi, wlo, k0, flag);
    im2col_split_kernel<<<18432, 256, 0, stream>>>(
        (const float*)d_in[3], (const u16*)d_in[3], xhi, xlo, k0, flag);
    conv5_gemm_kernel<<<dim3(64, 4), 256, 0, stream>>>(whi, wlo, xhi, xlo, part8, ph * 4);
  }
  finalize5_kernel<<<1024, 256, 0, stream>>>(
      part8, (const float*)d_in[8], (const u16*)d_in[8], t5, flag);

  // ---- localUp stage 4 (H=32, kd=128): c_hi=c3, c_lo=c40, prev=t5 ----
  conv1x1_part_kernel<<<dim3(16, 2, B * 8), 256, 0, stream>>>(
      (const float*)d_in[2], (const u16*)d_in[2],
      (const float*)d_in[11], (const u16*)d_in[11], scQ4, 1024, 128, 1024, 8, 0, flag);
  reduce_bn_kernel<<<1024, 256, 0, stream>>>(
      scQ4, (const float*)d_in[12], (const u16*)d_in[12], 1, q4, 128, 1024, 8, 262144, flag);
  conv1x1_part_kernel<<<dim3(4, 2, B * 16), 256, 0, stream>>>(
      (const float*)d_in[6], (const u16*)d_in[6],
      (const float*)d_in[13], (const u16*)d_in[13], scK4s, 2048, 128, 256, 16, 0, flag);
  reduce_bn_kernel<<<256, 256, 0, stream>>>(
      scK4s, (const float*)d_in[14], (const u16*)d_in[14], 1, k4s, 128, 256, 16, 65536, flag);
  upsample2x_kernel<<<1024, 256, 0, stream>>>(k4s, k4, 16, 16, B * 128 * 1024);
  att_part_kernel<<<128, 256, 0, stream>>>(q4, k4, scAtt, 128, 32, 32, 16, 16 * B * 1024);
  att_fin_kernel<<<8, 256, 0, stream>>>(scAtt, att4, 16, 1024, B * 1024);
  apply_up4_kernel<<<1024, 256, 0, stream>>>(att4, t5, o4, 512, 32, 32, 16, 16, B * 128 * 1024);

  // ---- localUp stage 3 (H=64, kd=64): c_hi=c2, c_lo=c30, prev=o4 ----
  conv1x1_part_kernel<<<dim3(64, 1, B * 4), 256, 0, stream>>>(
      (const float*)d_in[1], (const u16*)d_in[1],
      (const float*)d_in[15], (const u16*)d_in[15], scQ3, 512, 64, 4096, 4, 0, flag);
  reduce_bn_kernel<<<2048, 256, 0, stream>>>(
      scQ3, (const float*)d_in[16], (const u16*)d_in[16], 1, q3, 64, 4096, 4, 524288, flag);
  conv1x1_part_kernel<<<dim3(16, 1, B * 8), 256, 0, stream>>>(
      (const float*)d_in[5], (const u16*)d_in[5],
      (const float*)d_in[17], (const u16*)d_in[17], scK3s, 1024, 64, 1024, 8, 0, flag);
  reduce_bn_kernel<<<512, 256, 0, stream>>>(
      scK3s, (const float*)d_in[18], (const u16*)d_in[18], 1, k3s, 64, 1024, 8, 131072, flag);
  upsample2x_kernel<<<2048, 256, 0, stream>>>(k3s, k3, 32, 32, B * 64 * 4096);
  att_part_kernel<<<256, 256, 0, stream>>>(q3, k3, scAtt, 64, 64, 64, 8, 8 * B * 4096);
  att_fin_kernel<<<32, 256, 0, stream>>>(scAtt, att3, 8, 4096, B * 4096);
  apply_up4_kernel<<<4096, 256, 0, stream>>>(att3, o4, o3, 512, 64, 64, 32, 32, B * 128 * 4096);

  // ---- localUp stage 2 (H=128, kd=64): c_hi=c1, c_lo=c2, prev=o3; conv6 commuted ----
  conv1x1_part_kernel<<<dim3(256, 1, B * 2), 256, 0, stream>>>(
      (const float*)d_in[0], (const u16*)d_in[0],
      (const float*)d_in[19], (const u16*)d_in[19], scQ2, 256, 64, 16384, 2, 0, flag);
  reduce_bn_kernel<<<8192, 256, 0, stream>>>(
      scQ2, (const float*)d_in[20], (const u16*)d_in[20], 1, q2, 64, 16384, 2, 2097152, flag);
  conv1x1_part_kernel<<<dim3(64, 1, B * 4), 256, 0, stream>>>(
      (const float*)d_in[1], (const u16*)d_in[1],
      (const float*)d_in[21], (const u16*)d_in[21], scK2s, 512, 64, 4096, 4, 0, flag);
  reduce_bn_kernel<<<2048, 256, 0, stream>>>(
      scK2s, (const float*)d_in[22], (const u16*)d_in[22], 1, k2s, 64, 4096, 4, 524288, flag);
  upsample2x_kernel<<<8192, 256, 0, stream>>>(k2s, k2, 64, 64, B * 64 * 16384);
  att_part_kernel<<<1024, 256, 0, stream>>>(q2, k2, scAtt, 64, 128, 128, 8, 8 * B * 16384);
  att_fin_kernel<<<128, 256, 0, stream>>>(scAtt, att2, 8, 16384, B * 16384);
  // v6s = conv6(o3) at 64x64 (conv6 commutes with upsample AND the 9-tap gather)
  conv1x1_part_kernel<<<dim3(64, 1, B * 4), 256, 0, stream>>>(
      o3, (const u16*)nullptr,
      (const float*)d_in[9], (const u16*)d_in[9], scV6, 512, 19, 4096, 4, 1, flag);
  reduce_bn_kernel<<<608, 256, 0, stream>>>(
      scV6, (const float*)nullptr, (const u16*)nullptr, 0, v6s, 19, 4096, 4, 155648, flag);
  final_kernel<<<2432, 256, 0, stream>>>(
      att2, v6s, (const float*)d_in[10], (const u16*)d_in[10],
      (float*)d_out, (u16*)d_out, B * 19 * 16384, flag);
}

// Round 7
// 620.098 us; speedup vs baseline: 3.1493x; 1.0934x over previous
//
#include <hip/hip_runtime.h>
#include <hip/hip_bf16.h>
#include <math.h>

#define B 2

typedef __attribute__((ext_vector_type(8))) short bf16x8;
typedef __attribute__((ext_vector_type(4))) float f32x4;

// bf16 RNE on raw bits (inputs have no NaN/Inf)
__device__ __forceinline__ unsigned short f2bf(float f) {
  unsigned int u = __float_as_uint(f);
  return (unsigned short)((u + 0x7FFFu + ((u >> 16) & 1u)) >> 16);
}
__device__ __forceinline__ float bf2f(unsigned short h) {
  return __uint_as_float((unsigned int)h << 16);
}

// ---------------- dtype probe: flag=1 if buffer is bf16, 0 if f32 ----------------
__global__ void probe_kernel(const unsigned short* __restrict__ x, int* __restrict__ flag) {
  if (threadIdx.x == 0 && blockIdx.x == 0) {
    int sane = 0;
    for (int i = 0; i < 512; ++i) {
      int e = (x[i] >> 7) & 0xFF;
      if (e >= 97 && e <= 157) ++sane;
    }
    flag[0] = (sane >= 480) ? 1 : 0;
  }
}

// =============== conv5 via split-bf16 MFMA (f32 AND bf16 inputs, unified) ===========
// x -> hi = bf16(x), lo = bf16(x - hi); A.B ~= Ah.Bh + Ah.Bl + Al.Bh

__global__ __launch_bounds__(256) void split_w_kernel(
    const float* __restrict__ wf, const unsigned short* __restrict__ wb,
    unsigned short* __restrict__ hi, unsigned short* __restrict__ lo,
    int k0, const int* __restrict__ flag)
{
  const int isbf = flag[0];
  int e = (blockIdx.x * 256 + threadIdx.x) * 4;     // 4,718,592 total elements
  int row = e / 9216, kl = e % 9216;
  size_t src = (size_t)row * 18432 + k0 + kl;
  ushort4 h, l;
  if (isbf) {
    h = *(const ushort4*)(wb + src);
    l.x = 0; l.y = 0; l.z = 0; l.w = 0;
  } else {
    float4 x = *(const float4*)(wf + src);
    float xs[4] = {x.x, x.y, x.z, x.w};
    unsigned short hs[4], ls[4];
#pragma unroll
    for (int i = 0; i < 4; ++i) {
      hs[i] = f2bf(xs[i]);
      ls[i] = f2bf(xs[i] - bf2f(hs[i]));
    }
    h.x = hs[0]; h.y = hs[1]; h.z = hs[2]; h.w = hs[3];
    l.x = ls[0]; l.y = ls[1]; l.z = ls[2]; l.w = ls[3];
  }
  *(ushort4*)(hi + e) = h;
  *(ushort4*)(lo + e) = l;
}

// im2col split: X[r=n*256+px][kl], K=k0+kl=c*9+t, 3x3 pad 1
__global__ __launch_bounds__(256) void im2col_split_kernel(
    const float* __restrict__ cf, const unsigned short* __restrict__ cb,
    unsigned short* __restrict__ xhi, unsigned short* __restrict__ xlo,
    int k0, const int* __restrict__ flag)
{
  const int isbf = flag[0];
  int idx = blockIdx.x * 256 + threadIdx.x;         // 4,718,592 total
  int kl = idx % 9216, r = idx / 9216;
  int K = k0 + kl;
  int c = K / 9, t = K - c * 9;
  int n = r >> 8, px = r & 255;
  int x = px & 15, y = px >> 4;
  int yy = y + t / 3 - 1, xx = x + t % 3 - 1;
  bool in = (yy >= 0 && yy < 16 && xx >= 0 && xx < 16);
  size_t src = (((size_t)n * 2048 + c) << 8) + yy * 16 + xx;
  unsigned short h, l;
  if (isbf) {
    h = in ? cb[src] : (unsigned short)0;
    l = 0;
  } else {
    float v = in ? cf[src] : 0.f;
    h = f2bf(v);
    l = f2bf(v - bf2f(h));
  }
  xhi[idx] = h;
  xlo[idx] = l;
}

// LDS XOR swizzle: permute 16B slots within each 128B row (involution, both sides).
__device__ __forceinline__ int swz(int b) { return b ^ (((b >> 7) & 7) << 4); }

// GEMM: part[q][oc][r] over K-slice; M=N=512, slice K=2304 (36 steps). 64x64 tiles.
__global__ __launch_bounds__(256) void conv5_gemm_kernel(
    const unsigned short* __restrict__ Ah, const unsigned short* __restrict__ Al,
    const unsigned short* __restrict__ Bh, const unsigned short* __restrict__ Bl,
    float* __restrict__ part, int qbase)
{
  const int tile = blockIdx.x;            // 0..63 over 8x8 tiles
  const int ks   = blockIdx.y;            // 0..3 split-K within phase
  const int mo = (tile >> 3) * 64;        // oc tile base
  const int no = (tile & 7) * 64;         // r tile base
  const int kb = ks * 2304;
  const int tid = threadIdx.x;
  const int w = tid >> 6, lane = tid & 63;
  const int wr = w >> 1, wc = w & 1;      // 2x2 wave grid, each wave 32x32 out

  __shared__ unsigned short sAh[4096], sAl[4096], sBh[4096], sBl[4096];  // 32 KB

  const int row0 = tid >> 3, slot = tid & 7;
  const size_t a0 = (size_t)(mo + row0) * 9216 + kb + slot * 8;
  const size_t a1 = a0 + (size_t)32 * 9216;
  const size_t b0 = (size_t)(no + row0) * 9216 + kb + slot * 8;
  const size_t b1 = b0 + (size_t)32 * 9216;
  const int w0 = swz(row0 * 128 + slot * 16);
  const int w1 = swz((row0 + 32) * 128 + slot * 16);

  f32x4 acc[2][2];
#pragma unroll
  for (int m = 0; m < 2; ++m)
#pragma unroll
    for (int nn = 0; nn < 2; ++nn) acc[m][nn] = (f32x4){0.f, 0.f, 0.f, 0.f};

  bf16x8 rah0 = *(const bf16x8*)(Ah + a0), rah1 = *(const bf16x8*)(Ah + a1);
  bf16x8 ral0 = *(const bf16x8*)(Al + a0), ral1 = *(const bf16x8*)(Al + a1);
  bf16x8 rbh0 = *(const bf16x8*)(Bh + b0), rbh1 = *(const bf16x8*)(Bh + b1);
  bf16x8 rbl0 = *(const bf16x8*)(Bl + b0), rbl1 = *(const bf16x8*)(Bl + b1);

  const int arow = wr * 32 + (lane & 15);
  const int brow = wc * 32 + (lane & 15);
  const int cb = (lane >> 4) * 16;

  for (int kk = 0; kk < 2304; kk += 64) {
    *(bf16x8*)((char*)sAh + w0) = rah0;  *(bf16x8*)((char*)sAh + w1) = rah1;
    *(bf16x8*)((char*)sAl + w0) = ral0;  *(bf16x8*)((char*)sAl + w1) = ral1;
    *(bf16x8*)((char*)sBh + w0) = rbh0;  *(bf16x8*)((char*)sBh + w1) = rbh1;
    *(bf16x8*)((char*)sBl + w0) = rbl0;  *(bf16x8*)((char*)sBl + w1) = rbl1;
    if (kk + 64 < 2304) {
      rah0 = *(const bf16x8*)(Ah + a0 + kk + 64);
      rah1 = *(const bf16x8*)(Ah + a1 + kk + 64);
      ral0 = *(const bf16x8*)(Al + a0 + kk + 64);
      ral1 = *(const bf16x8*)(Al + a1 + kk + 64);
      rbh0 = *(const bf16x8*)(Bh + b0 + kk + 64);
      rbh1 = *(const bf16x8*)(Bh + b1 + kk + 64);
      rbl0 = *(const bf16x8*)(Bl + b0 + kk + 64);
      rbl1 = *(const bf16x8*)(Bl + b1 + kk + 64);
    }
    __syncthreads();
#pragma unroll
    for (int k2 = 0; k2 < 2; ++k2) {
      const int colb = k2 * 64 + cb;
      bf16x8 fah[2], fal[2], fbh[2], fbl[2];
#pragma unroll
      for (int m = 0; m < 2; ++m) {
        fah[m] = *(const bf16x8*)((char*)sAh + swz((arow + m * 16) * 128 + colb));
        fal[m] = *(const bf16x8*)((char*)sAl + swz((arow + m * 16) * 128 + colb));
      }
#pragma unroll
      for (int nn = 0; nn < 2; ++nn) {
        fbh[nn] = *(const bf16x8*)((char*)sBh + swz((brow + nn * 16) * 128 + colb));
        fbl[nn] = *(const bf16x8*)((char*)sBl + swz((brow + nn * 16) * 128 + colb));
      }
#pragma unroll
      for (int m = 0; m < 2; ++m)
#pragma unroll
        for (int nn = 0; nn < 2; ++nn) {
          acc[m][nn] = __builtin_amdgcn_mfma_f32_16x16x32_bf16(fah[m], fbh[nn], acc[m][nn], 0, 0, 0);
          acc[m][nn] = __builtin_amdgcn_mfma_f32_16x16x32_bf16(fah[m], fbl[nn], acc[m][nn], 0, 0, 0);
          acc[m][nn] = __builtin_amdgcn_mfma_f32_16x16x32_bf16(fal[m], fbh[nn], acc[m][nn], 0, 0, 0);
        }
    }
    __syncthreads();
  }

  // C/D layout: col = lane&15 (-> r), row = (lane>>4)*4 + j (-> oc)
  const int quarter = qbase + ks;       // 0..7
#pragma unroll
  for (int m = 0; m < 2; ++m)
#pragma unroll
    for (int nn = 0; nn < 2; ++nn) {
      const int r = no + wc * 32 + nn * 16 + (lane & 15);
      const int n = r >> 8, px = r & 255;
#pragma unroll
      for (int j = 0; j < 4; ++j) {
        const int oc = mo + wr * 32 + m * 16 + (lane >> 4) * 4 + j;
        part[(size_t)quarter * 262144 + ((size_t)n * 512 + oc) * 256 + px] = acc[m][nn][j];
      }
    }
}

// sum 8 K-slices + BN + ReLU -> t5
__global__ __launch_bounds__(256) void finalize5_kernel(
    const float* __restrict__ part, const float* __restrict__ bnf,
    const unsigned short* __restrict__ bnb, float* __restrict__ t5,
    const int* __restrict__ flag)
{
  int idx = blockIdx.x * 256 + threadIdx.x;   // 262144 total
  int oc = (idx >> 8) & 511;
  float s = 0.f;
#pragma unroll
  for (int q = 0; q < 8; ++q) s += part[(size_t)q * 262144 + idx];
  float g, b, m, v;
  if (flag[0]) {
    g = bf2f(bnb[oc]); b = bf2f(bnb[512 + oc]);
    m = bf2f(bnb[1024 + oc]); v = bf2f(bnb[1536 + oc]);
  } else {
    g = bnf[oc]; b = bnf[512 + oc]; m = bnf[1024 + oc]; v = bnf[1536 + oc];
  }
  float sc = g * rsqrtf(v + 1e-5f);
  float val = s * sc + (b - m * sc);
  t5[idx] = fmaxf(val, 0.f);
}

// ---------------- split-C 1x1 conv partials (unified dtype) ----------------
// blockIdx.z = n*KS + kc; part[kc*(B*O*S) + (n*O + o)*S + s]
__global__ __launch_bounds__(256) void conv1x1_part_kernel(
    const float* __restrict__ Xf, const unsigned short* __restrict__ Xb,
    const float* __restrict__ Wf, const unsigned short* __restrict__ Wb,
    float* __restrict__ part, int C, int O, int S, int KS, int xf32,
    const int* __restrict__ flag)
{
  const int isbf = flag[0];
  const int xbf = xf32 ? 0 : isbf;
  const int tid = threadIdx.x;
  const int sg = tid & 15, og = tid >> 4;
  const int s0 = blockIdx.x * 64;
  const int o0 = blockIdx.y * 64;
  const int n  = blockIdx.z / KS;
  const int kc = blockIdx.z % KS;
  const int CC = C / KS;
  const int cbase = kc * CC;

  __shared__ float xs[16][64];
  __shared__ float wsT[16][68];

  float acc[4][4];
#pragma unroll
  for (int i = 0; i < 4; ++i)
#pragma unroll
    for (int j = 0; j < 4; ++j) acc[i][j] = 0.f;

  for (int c0 = cbase; c0 < cbase + CC; c0 += 16) {
    if (xbf) {
#pragma unroll
      for (int r = 0; r < 4; ++r) {
        int e = tid + r * 256, cc = e >> 6, ssv = e & 63;
        xs[cc][ssv] = bf2f(Xb[((size_t)n * C + c0 + cc) * S + s0 + ssv]);
      }
    } else {
#pragma unroll
      for (int r = 0; r < 4; ++r) {
        int e = tid + r * 256, cc = e >> 6, ssv = e & 63;
        xs[cc][ssv] = Xf[((size_t)n * C + c0 + cc) * S + s0 + ssv];
      }
    }
    if (isbf) {
#pragma unroll
      for (int r = 0; r < 4; ++r) {
        int e = tid + r * 256, oo = e >> 4, cc = e & 15;
        int o = o0 + oo;
        wsT[cc][oo] = (o < O) ? bf2f(Wb[(size_t)o * C + c0 + cc]) : 0.f;
      }
    } else {
#pragma unroll
      for (int r = 0; r < 4; ++r) {
        int e = tid + r * 256, oo = e >> 4, cc = e & 15;
        int o = o0 + oo;
        wsT[cc][oo] = (o < O) ? Wf[(size_t)o * C + c0 + cc] : 0.f;
      }
    }
    __syncthreads();
#pragma unroll
    for (int c = 0; c < 16; ++c) {
      const float4 xv = *(const float4*)&xs[c][sg * 4];
      const float4 wv = *(const float4*)&wsT[c][og * 4];
      acc[0][0] = fmaf(wv.x, xv.x, acc[0][0]);
      acc[0][1] = fmaf(wv.x, xv.y, acc[0][1]);
      acc[0][2] = fmaf(wv.x, xv.z, acc[0][2]);
      acc[0][3] = fmaf(wv.x, xv.w, acc[0][3]);
      acc[1][0] = fmaf(wv.y, xv.x, acc[1][0]);
      acc[1][1] = fmaf(wv.y, xv.y, acc[1][1]);
      acc[1][2] = fmaf(wv.y, xv.z, acc[1][2]);
      acc[1][3] = fmaf(wv.y, xv.w, acc[1][3]);
      acc[2][0] = fmaf(wv.z, xv.x, acc[2][0]);
      acc[2][1] = fmaf(wv.z, xv.y, acc[2][1]);
      acc[2][2] = fmaf(wv.z, xv.z, acc[2][2]);
      acc[2][3] = fmaf(wv.z, xv.w, acc[2][3]);
      acc[3][0] = fmaf(wv.w, xv.x, acc[3][0]);
      acc[3][1] = fmaf(wv.w, xv.y, acc[3][1]);
      acc[3][2] = fmaf(wv.w, xv.z, acc[3][2]);
      acc[3][3] = fmaf(wv.w, xv.w, acc[3][3]);
    }
    __syncthreads();
  }

  const size_t BOS = (size_t)B * O * S;
#pragma unroll
  for (int i = 0; i < 4; ++i) {
    int o = o0 + og * 4 + i;
    if (o < O) {
      float4 r;
      r.x = acc[i][0]; r.y = acc[i][1]; r.z = acc[i][2]; r.w = acc[i][3];
      *(float4*)(part + (size_t)kc * BOS + ((size_t)n * O + o) * S + s0 + sg * 4) = r;
    }
  }
}

// sum KS partials + optional BN -> Y.  total = B*O*S
__global__ __launch_bounds__(256) void reduce_bn_kernel(
    const float* __restrict__ part, const float* __restrict__ bnf,
    const unsigned short* __restrict__ bnb, int hasbn,
    float* __restrict__ Y, int O, int S, int KS, int total,
    const int* __restrict__ flag)
{
  int idx = blockIdx.x * 256 + threadIdx.x;
  if (idx >= total) return;
  float s = 0.f;
  for (int kc = 0; kc < KS; ++kc) s += part[(size_t)kc * total + idx];
  float sc = 1.f, sh = 0.f;
  if (hasbn) {
    int o = (idx / S) % O;
    float g, b, m, v;
    if (flag[0]) {
      g = bf2f(bnb[o]); b = bf2f(bnb[O + o]);
      m = bf2f(bnb[2 * O + o]); v = bf2f(bnb[3 * O + o]);
    } else {
      g = bnf[o]; b = bnf[O + o]; m = bnf[2 * O + o]; v = bnf[3 * O + o];
    }
    sc = g * rsqrtf(v + 1e-5f);
    sh = b - m * sc;
  }
  Y[idx] = s * sc + sh;
}

// ---------------- bilinear 2x upsample, align_corners=True ----------------
__global__ __launch_bounds__(256) void upsample2x_kernel(
    const float* __restrict__ in, float* __restrict__ out,
    int h, int w, int total)
{
  int idx = blockIdx.x * 256 + threadIdx.x;
  if (idx >= total) return;
  const int Wd = 2 * w, Hd = 2 * h;
  int xo = idx % Wd;
  int t  = idx / Wd;
  int yo = t % Hd;
  int pl = t / Hd;
  const float rh = (float)(h - 1) / (float)(Hd - 1);
  const float rw = (float)(w - 1) / (float)(Wd - 1);
  float fy = yo * rh, fx = xo * rw;
  int y0 = (int)fy; if (y0 > h - 1) y0 = h - 1;
  int x0 = (int)fx; if (x0 > w - 1) x0 = w - 1;
  int y1 = min(y0 + 1, h - 1), x1 = min(x0 + 1, w - 1);
  float wy = fy - y0, wx = fx - x0;
  const float* p = in + (size_t)pl * h * w;
  float v00 = p[y0 * w + x0], v01 = p[y0 * w + x1];
  float v10 = p[y1 * w + x0], v11 = p[y1 * w + x1];
  out[idx] = (v00 * (1.f - wy) + v10 * wy) * (1.f - wx) +
             (v01 * (1.f - wy) + v11 * wy) * wx;
}

// ---- kd-split attention: partial dots.  pd[((kc*B + n)*9 + j)*S + p] ----
__global__ __launch_bounds__(256) void att_part_kernel(
    const float* __restrict__ q, const float* __restrict__ k,
    float* __restrict__ pd, int kd, int H, int Wd, int KC, int total)
{
  int idx = blockIdx.x * 256 + threadIdx.x;
  if (idx >= total) return;
  const int S = H * Wd;
  int p = idx % S;
  int t = idx / S;
  int n = t % B, kc = t / B;
  int x = p % Wd, y = p / Wd;
  int off[9]; bool ok[9];
#pragma unroll
  for (int j = 0; j < 9; ++j) {
    int dy = (j / 3) * 2 - 2, dx = (j % 3) * 2 - 2;
    int yy = y + dy, xx = x + dx;
    ok[j] = (yy >= 0 && yy < H && xx >= 0 && xx < Wd);
    off[j] = yy * Wd + xx;
  }
  float dot[9] = {0.f,0.f,0.f,0.f,0.f,0.f,0.f,0.f,0.f};
  const int cc = kd / KC;
  const int c0 = kc * cc;
  const float* qp = q + (size_t)n * kd * S + p;
  const float* kp = k + (size_t)n * kd * S;
  for (int c = c0; c < c0 + cc; ++c) {
    float qv = qp[(size_t)c * S];
    const float* kcp = kp + (size_t)c * S;
#pragma unroll
    for (int j = 0; j < 9; ++j)
      if (ok[j]) dot[j] = fmaf(qv, kcp[off[j]], dot[j]);
  }
  float* o = pd + ((size_t)(kc * B + n) * 9) * S + p;
#pragma unroll
  for (int j = 0; j < 9; ++j) o[(size_t)j * S] = dot[j];
}

// sum partial dots + softmax.  total = B*S
__global__ __launch_bounds__(256) void att_fin_kernel(
    const float* __restrict__ pd, float* __restrict__ att,
    int KC, int S, int total)
{
  int idx = blockIdx.x * 256 + threadIdx.x;
  if (idx >= total) return;
  int p = idx % S, n = idx / S;
  float dot[9] = {0.f,0.f,0.f,0.f,0.f,0.f,0.f,0.f,0.f};
  for (int kc = 0; kc < KC; ++kc) {
    const float* o = pd + ((size_t)(kc * B + n) * 9) * S + p;
#pragma unroll
    for (int j = 0; j < 9; ++j) dot[j] += o[(size_t)j * S];
  }
  float m = dot[0];
#pragma unroll
  for (int j = 1; j < 9; ++j) m = fmaxf(m, dot[j]);
  float e[9], ssum = 0.f;
#pragma unroll
  for (int j = 0; j < 9; ++j) { e[j] = __expf(dot[j] - m); ssum += e[j]; }
  float inv = 1.f / ssum;
#pragma unroll
  for (int j = 0; j < 9; ++j)
    att[((size_t)n * 9 + j) * S + p] = e[j] * inv;
}

// ---- tap-apply on PRE-UPSAMPLED prev: out[n,c,p] = sum_j att_j[p]*prevUp[n,c,p+D_j]
// 4 channels/thread; taps are dilation-2 shifts at the SAME resolution (coalesced).
__global__ __launch_bounds__(256) void apply_tap4_kernel(
    const float* __restrict__ att, const float* __restrict__ prevUp,
    float* __restrict__ out, int C, int H, int Wd, int total4)
{
  int idx = blockIdx.x * 256 + threadIdx.x;
  if (idx >= total4) return;
  const int S = H * Wd;
  const int CQ = C >> 2;
  int p = idx % S;
  int t = idx / S;
  int cq = t % CQ, n = t / CQ;
  int c0 = cq << 2;
  int x = p % Wd, y = p / Wd;
  const float* ap = att + (size_t)n * 9 * S + p;
  float a[9]; int off[9];
#pragma unroll
  for (int j = 0; j < 9; ++j) {
    int dy = (j / 3) * 2 - 2, dx = (j % 3) * 2 - 2;
    int yy = y + dy, xx = x + dx;
    bool ok = (yy >= 0 && yy < H && xx >= 0 && xx < Wd);
    a[j]   = ok ? ap[(size_t)j * S] : 0.f;
    off[j] = ok ? yy * Wd + xx : 0;
  }
  const float* pc = prevUp + ((size_t)n * C + c0) * S;
  float v0 = 0.f, v1 = 0.f, v2 = 0.f, v3 = 0.f;
#pragma unroll
  for (int j = 0; j < 9; ++j) {
    v0 = fmaf(pc[off[j]], a[j], v0);
    v1 = fmaf(pc[(size_t)S + off[j]], a[j], v1);
    v2 = fmaf(pc[(size_t)2 * S + off[j]], a[j], v2);
    v3 = fmaf(pc[(size_t)3 * S + off[j]], a[j], v3);
  }
  float* op = out + ((size_t)n * C + c0) * S + p;
  op[0] = v0;
  op[(size_t)S] = v1;
  op[(size_t)2 * S] = v2;
  op[(size_t)3 * S] = v3;
}

// ---- final on pre-upsampled v6up: d_out[n,o,p] = bias[o] + sum_j att_j*v6up[tap] ----
__global__ __launch_bounds__(256) void final_tap_kernel(
    const float* __restrict__ att, const float* __restrict__ v6up,
    const float* __restrict__ biasf, const unsigned short* __restrict__ biasb,
    float* __restrict__ outf, unsigned short* __restrict__ outb,
    int total, const int* __restrict__ flag)
{
  const int isbf = flag[0];
  int idx = blockIdx.x * 256 + threadIdx.x;
  if (idx >= total) return;
  const int H = 128, Wd = 128;
  const int S = H * Wd;
  int p = idx % S;
  int t = idx / S;
  int o = t % 19, n = t / 19;
  int x = p % Wd, y = p / Wd;
  const float* ap = att + (size_t)n * 9 * S + p;
  const float* pc = v6up + ((size_t)n * 19 + o) * S;
  float v = isbf ? bf2f(biasb[o]) : biasf[o];
#pragma unroll
  for (int j = 0; j < 9; ++j) {
    int dy = (j / 3) * 2 - 2, dx = (j % 3) * 2 - 2;
    int yy = y + dy, xx = x + dx;
    if (yy >= 0 && yy < H && xx >= 0 && xx < Wd)
      v = fmaf(ap[(size_t)j * S], pc[yy * Wd + xx], v);
  }
  if (isbf) outb[idx] = f2bf(v);
  else      outf[idx] = v;
}

typedef __hip_bfloat16 bf16;
typedef unsigned short u16;

extern "C" void kernel_launch(void* const* d_in, const int* in_sizes, int n_in,
                              void* d_out, int out_size, void* d_ws, size_t ws_size,
                              hipStream_t stream) {
  (void)in_sizes; (void)n_in; (void)out_size; (void)ws_size;

  float* ws = (float*)d_ws;   // fp32 workspace, 13,584,385 floats = 51.8 MiB
  // persistent stage buffers
  float* t5   = ws + 1048576;    //   262,144
  float* q4   = ws + 1310720;    //   262,144
  float* k4s  = ws + 1572864;    //    65,536
  float* k4   = ws + 1638400;    //   262,144
  float* att4 = ws + 1900544;    //    18,432
  float* o4   = ws + 1918976;    // 1,048,576
  float* q3   = ws + 2967552;    //   524,288
  float* k3s  = ws + 3491840;    //   131,072
  float* k3   = ws + 3622912;    //   524,288
  float* att3 = ws + 4147200;    //    73,728
  float* o3   = ws + 4220928;    // 4,194,304
  float* v6s  = ws + 8415232;    //   155,648
  float* q2   = ws + 8570880;    // 2,097,152
  float* k2s  = ws + 10668032;   //   524,288
  float* k2   = ws + 11192320;   // 2,097,152
  float* att2 = ws + 13289472;   //   294,912
  int*   flag = (int*)(ws + 13584384);

  // conv5 scratch: part8 (8 K-slices) + 4 split buffers; all dead after finalize5.
  float* part8 = ws + 1310720;                       // 2,097,152, ends 3,407,872
  u16* whi = (u16*)(ws + 4147200);                   // each 4,718,592 bf16
  u16* wlo = (u16*)(ws + 6506496);
  u16* xhi = (u16*)(ws + 8865792);
  u16* xlo = (u16*)(ws + 11225088);                  // ends 13,584,384

  // split-C / split-kd scratch (temporally dead regions at their use time):
  float* scQ4   = ws + 4220928;   // 2,097,152 (o3 region)
  float* scK4s  = ws + 6318080;   // 1,048,576 (o3 region)
  float* scQ3   = ws + 8570880;   // 2,097,152 (q2 region)
  float* scK3s  = ws + 11192320;  // 1,048,576 (k2 region)
  float* scQ2   = ws + 0;         // 4,194,304 (p5..att3 regions, all dead)
  float* scK2s  = ws + 11192320;  // 2,097,152 (k2 region)
  float* scV6   = ws + 8570880;   //   622,592 (q2 region, dead after att2)
  float* scAtt  = ws + 0;         // stage4: 294,912; stage3: 589,824; stage2: 2,359,296

  // pre-upsampled prev buffers (each alive only between its upsample and apply):
  float* t5up = ws + 0;           // 1,048,576 (scAtt4 dead after att_fin4)
  float* o4up = ws + 8415232;     // 4,194,304 (v6s/q2 regions, written later)
  float* v6up = ws + 0;           //   622,592 (scAtt2 dead after att_fin2)

  probe_kernel<<<1, 64, 0, stream>>>((const unsigned short*)d_in[0], flag);

  // ---- conv5 + BN + ReLU: split-bf16 MFMA GEMM, 2 phases x 4 K-slices ----
  for (int ph = 0; ph < 2; ++ph) {
    const int k0 = ph * 9216;
    split_w_kernel<<<4608, 256, 0, stream>>>(
        (const float*)d_in[7], (const u16*)d_in[7], whi, wlo, k0, flag);
    im2col_split_kernel<<<18432, 256, 0, stream>>>(
        (const float*)d_in[3], (const u16*)d_in[3], xhi, xlo, k0, flag);
    conv5_gemm_kernel<<<dim3(64, 4), 256, 0, stream>>>(whi, wlo, xhi, xlo, part8, ph * 4);
  }
  finalize5_kernel<<<1024, 256, 0, stream>>>(
      part8, (const float*)d_in[8], (const u16*)d_in[8], t5, flag);

  // ---- localUp stage 4 (H=32, kd=128): c_hi=c3, c_lo=c40, prev=t5 ----
  conv1x1_part_kernel<<<dim3(16, 2, B * 8), 256, 0, stream>>>(
      (const float*)d_in[2], (const u16*)d_in[2],
      (const float*)d_in[11], (const u16*)d_in[11], scQ4, 1024, 128, 1024, 8, 0, flag);
  reduce_bn_kernel<<<1024, 256, 0, stream>>>(
      scQ4, (const float*)d_in[12], (const u16*)d_in[12], 1, q4, 128, 1024, 8, 262144, flag);
  conv1x1_part_kernel<<<dim3(4, 2, B * 16), 256, 0, stream>>>(
      (const float*)d_in[6], (const u16*)d_in[6],
      (const float*)d_in[13], (const u16*)d_in[13], scK4s, 2048, 128, 256, 16, 0, flag);
  reduce_bn_kernel<<<256, 256, 0, stream>>>(
      scK4s, (const float*)d_in[14], (const u16*)d_in[14], 1, k4s, 128, 256, 16, 65536, flag);
  upsample2x_kernel<<<1024, 256, 0, stream>>>(k4s, k4, 16, 16, B * 128 * 1024);
  att_part_kernel<<<128, 256, 0, stream>>>(q4, k4, scAtt, 128, 32, 32, 16, 16 * B * 1024);
  att_fin_kernel<<<8, 256, 0, stream>>>(scAtt, att4, 16, 1024, B * 1024);
  upsample2x_kernel<<<4096, 256, 0, stream>>>(t5, t5up, 16, 16, B * 512 * 1024);
  apply_tap4_kernel<<<1024, 256, 0, stream>>>(att4, t5up, o4, 512, 32, 32, B * 128 * 1024);

  // ---- localUp stage 3 (H=64, kd=64): c_hi=c2, c_lo=c30, prev=o4 ----
  conv1x1_part_kernel<<<dim3(64, 1, B * 4), 256, 0, stream>>>(
      (const float*)d_in[1], (const u16*)d_in[1],
      (const float*)d_in[15], (const u16*)d_in[15], scQ3, 512, 64, 4096, 4, 0, flag);
  reduce_bn_kernel<<<2048, 256, 0, stream>>>(
      scQ3, (const float*)d_in[16], (const u16*)d_in[16], 1, q3, 64, 4096, 4, 524288, flag);
  conv1x1_part_kernel<<<dim3(16, 1, B * 8), 256, 0, stream>>>(
      (const float*)d_in[5], (const u16*)d_in[5],
      (const float*)d_in[17], (const u16*)d_in[17], scK3s, 1024, 64, 1024, 8, 0, flag);
  reduce_bn_kernel<<<512, 256, 0, stream>>>(
      scK3s, (const float*)d_in[18], (const u16*)d_in[18], 1, k3s, 64, 1024, 8, 131072, flag);
  upsample2x_kernel<<<2048, 256, 0, stream>>>(k3s, k3, 32, 32, B * 64 * 4096);
  att_part_kernel<<<256, 256, 0, stream>>>(q3, k3, scAtt, 64, 64, 64, 8, 8 * B * 4096);
  att_fin_kernel<<<32, 256, 0, stream>>>(scAtt, att3, 8, 4096, B * 4096);
  upsample2x_kernel<<<16384, 256, 0, stream>>>(o4, o4up, 32, 32, B * 512 * 4096);
  apply_tap4_kernel<<<4096, 256, 0, stream>>>(att3, o4up, o3, 512, 64, 64, B * 128 * 4096);

  // ---- localUp stage 2 (H=128, kd=64): c_hi=c1, c_lo=c2, prev=o3; conv6 commuted ----
  conv1x1_part_kernel<<<dim3(256, 1, B * 2), 256, 0, stream>>>(
      (const float*)d_in[0], (const u16*)d_in[0],
      (const float*)d_in[19], (const u16*)d_in[19], scQ2, 256, 64, 16384, 2, 0, flag);
  reduce_bn_kernel<<<8192, 256, 0, stream>>>(
      scQ2, (const float*)d_in[20], (const u16*)d_in[20], 1, q2, 64, 16384, 2, 2097152, flag);
  conv1x1_part_kernel<<<dim3(64, 1, B * 4), 256, 0, stream>>>(
      (const float*)d_in[1], (const u16*)d_in[1],
      (const float*)d_in[21], (const u16*)d_in[21], scK2s, 512, 64, 4096, 4, 0, flag);
  reduce_bn_kernel<<<2048, 256, 0, stream>>>(
      scK2s, (const float*)d_in[22], (const u16*)d_in[22], 1, k2s, 64, 4096, 4, 524288, flag);
  upsample2x_kernel<<<8192, 256, 0, stream>>>(k2s, k2, 64, 64, B * 64 * 16384);
  att_part_kernel<<<1024, 256, 0, stream>>>(q2, k2, scAtt, 64, 128, 128, 8, 8 * B * 16384);
  att_fin_kernel<<<128, 256, 0, stream>>>(scAtt, att2, 8, 16384, B * 16384);
  // v6s = conv6(o3) at 64x64 (conv6 commutes with upsample AND the 9-tap gather)
  conv1x1_part_kernel<<<dim3(64, 1, B * 4), 256, 0, stream>>>(
      o3, (const u16*)nullptr,
      (const float*)d_in[9], (const u16*)d_in[9], scV6, 512, 19, 4096, 4, 1, flag);
  reduce_bn_kernel<<<608, 256, 0, stream>>>(
      scV6, (const float*)nullptr, (const u16*)nullptr, 0, v6s, 19, 4096, 4, 155648, flag);
  upsample2x_kernel<<<2432, 256, 0, stream>>>(v6s, v6up, 64, 64, B * 19 * 16384);
  final_tap_kernel<<<2432, 256, 0, stream>>>(
      att2, v6up, (const float*)d_in[10], (const u16*)d_in[10],
      (float*)d_out, (u16*)d_out, B * 19 * 16384, flag);
}

// Round 8
// 528.348 us; speedup vs baseline: 3.6961x; 1.1737x over previous
//
#include <hip/hip_runtime.h>
#include <hip/hip_bf16.h>
#include <math.h>

#define B 2

typedef __attribute__((ext_vector_type(8))) short bf16x8;
typedef __attribute__((ext_vector_type(4))) float f32x4;

// bf16 RNE on raw bits (inputs have no NaN/Inf)
__device__ __forceinline__ unsigned short f2bf(float f) {
  unsigned int u = __float_as_uint(f);
  return (unsigned short)((u + 0x7FFFu + ((u >> 16) & 1u)) >> 16);
}
__device__ __forceinline__ float bf2f(unsigned short h) {
  return __uint_as_float((unsigned int)h << 16);
}

// ---------------- dtype probe: flag=1 if buffer is bf16, 0 if f32 ----------------
__global__ void probe_kernel(const unsigned short* __restrict__ x, int* __restrict__ flag) {
  if (threadIdx.x == 0 && blockIdx.x == 0) {
    int sane = 0;
    for (int i = 0; i < 512; ++i) {
      int e = (x[i] >> 7) & 0xFF;
      if (e >= 97 && e <= 157) ++sane;
    }
    flag[0] = (sane >= 480) ? 1 : 0;
  }
}

// =============== conv5 via split-bf16 MFMA (f32 AND bf16 inputs, unified) ===========
// x -> hi = bf16(x), lo = bf16(x - hi); A.B ~= Ah.Bh + Ah.Bl + Al.Bh

__global__ __launch_bounds__(256) void split_w_kernel(
    const float* __restrict__ wf, const unsigned short* __restrict__ wb,
    unsigned short* __restrict__ hi, unsigned short* __restrict__ lo,
    int k0, const int* __restrict__ flag)
{
  const int isbf = flag[0];
  int e = (blockIdx.x * 256 + threadIdx.x) * 4;     // 4,718,592 total elements
  int row = e / 9216, kl = e % 9216;
  size_t src = (size_t)row * 18432 + k0 + kl;
  ushort4 h, l;
  if (isbf) {
    h = *(const ushort4*)(wb + src);
    l.x = 0; l.y = 0; l.z = 0; l.w = 0;
  } else {
    float4 x = *(const float4*)(wf + src);
    float xs[4] = {x.x, x.y, x.z, x.w};
    unsigned short hs[4], ls[4];
#pragma unroll
    for (int i = 0; i < 4; ++i) {
      hs[i] = f2bf(xs[i]);
      ls[i] = f2bf(xs[i] - bf2f(hs[i]));
    }
    h.x = hs[0]; h.y = hs[1]; h.z = hs[2]; h.w = hs[3];
    l.x = ls[0]; l.y = ls[1]; l.z = ls[2]; l.w = ls[3];
  }
  *(ushort4*)(hi + e) = h;
  *(ushort4*)(lo + e) = l;
}

// im2col split: X[r=n*256+px][kl], K=k0+kl=c*9+t, 3x3 pad 1
__global__ __launch_bounds__(256) void im2col_split_kernel(
    const float* __restrict__ cf, const unsigned short* __restrict__ cb,
    unsigned short* __restrict__ xhi, unsigned short* __restrict__ xlo,
    int k0, const int* __restrict__ flag)
{
  const int isbf = flag[0];
  int idx = blockIdx.x * 256 + threadIdx.x;         // 4,718,592 total
  int kl = idx % 9216, r = idx / 9216;
  int K = k0 + kl;
  int c = K / 9, t = K - c * 9;
  int n = r >> 8, px = r & 255;
  int x = px & 15, y = px >> 4;
  int yy = y + t / 3 - 1, xx = x + t % 3 - 1;
  bool in = (yy >= 0 && yy < 16 && xx >= 0 && xx < 16);
  size_t src = (((size_t)n * 2048 + c) << 8) + yy * 16 + xx;
  unsigned short h, l;
  if (isbf) {
    h = in ? cb[src] : (unsigned short)0;
    l = 0;
  } else {
    float v = in ? cf[src] : 0.f;
    h = f2bf(v);
    l = f2bf(v - bf2f(h));
  }
  xhi[idx] = h;
  xlo[idx] = l;
}

// LDS XOR swizzle: permute 16B slots within each 128B row (involution, both sides).
__device__ __forceinline__ int swz(int b) { return b ^ (((b >> 7) & 7) << 4); }

// GEMM: part[q][oc][r] over K-slice; M=N=512, slice K=2304 (36 steps). 64x64 tiles.
__global__ __launch_bounds__(256) void conv5_gemm_kernel(
    const unsigned short* __restrict__ Ah, const unsigned short* __restrict__ Al,
    const unsigned short* __restrict__ Bh, const unsigned short* __restrict__ Bl,
    float* __restrict__ part, int qbase)
{
  const int tile = blockIdx.x;            // 0..63 over 8x8 tiles
  const int ks   = blockIdx.y;            // 0..3 split-K within phase
  const int mo = (tile >> 3) * 64;        // oc tile base
  const int no = (tile & 7) * 64;         // r tile base
  const int kb = ks * 2304;
  const int tid = threadIdx.x;
  const int w = tid >> 6, lane = tid & 63;
  const int wr = w >> 1, wc = w & 1;      // 2x2 wave grid, each wave 32x32 out

  __shared__ unsigned short sAh[4096], sAl[4096], sBh[4096], sBl[4096];  // 32 KB

  const int row0 = tid >> 3, slot = tid & 7;
  const size_t a0 = (size_t)(mo + row0) * 9216 + kb + slot * 8;
  const size_t a1 = a0 + (size_t)32 * 9216;
  const size_t b0 = (size_t)(no + row0) * 9216 + kb + slot * 8;
  const size_t b1 = b0 + (size_t)32 * 9216;
  const int w0 = swz(row0 * 128 + slot * 16);
  const int w1 = swz((row0 + 32) * 128 + slot * 16);

  f32x4 acc[2][2];
#pragma unroll
  for (int m = 0; m < 2; ++m)
#pragma unroll
    for (int nn = 0; nn < 2; ++nn) acc[m][nn] = (f32x4){0.f, 0.f, 0.f, 0.f};

  bf16x8 rah0 = *(const bf16x8*)(Ah + a0), rah1 = *(const bf16x8*)(Ah + a1);
  bf16x8 ral0 = *(const bf16x8*)(Al + a0), ral1 = *(const bf16x8*)(Al + a1);
  bf16x8 rbh0 = *(const bf16x8*)(Bh + b0), rbh1 = *(const bf16x8*)(Bh + b1);
  bf16x8 rbl0 = *(const bf16x8*)(Bl + b0), rbl1 = *(const bf16x8*)(Bl + b1);

  const int arow = wr * 32 + (lane & 15);
  const int brow = wc * 32 + (lane & 15);
  const int cb = (lane >> 4) * 16;

  for (int kk = 0; kk < 2304; kk += 64) {
    *(bf16x8*)((char*)sAh + w0) = rah0;  *(bf16x8*)((char*)sAh + w1) = rah1;
    *(bf16x8*)((char*)sAl + w0) = ral0;  *(bf16x8*)((char*)sAl + w1) = ral1;
    *(bf16x8*)((char*)sBh + w0) = rbh0;  *(bf16x8*)((char*)sBh + w1) = rbh1;
    *(bf16x8*)((char*)sBl + w0) = rbl0;  *(bf16x8*)((char*)sBl + w1) = rbl1;
    if (kk + 64 < 2304) {
      rah0 = *(const bf16x8*)(Ah + a0 + kk + 64);
      rah1 = *(const bf16x8*)(Ah + a1 + kk + 64);
      ral0 = *(const bf16x8*)(Al + a0 + kk + 64);
      ral1 = *(const bf16x8*)(Al + a1 + kk + 64);
      rbh0 = *(const bf16x8*)(Bh + b0 + kk + 64);
      rbh1 = *(const bf16x8*)(Bh + b1 + kk + 64);
      rbl0 = *(const bf16x8*)(Bl + b0 + kk + 64);
      rbl1 = *(const bf16x8*)(Bl + b1 + kk + 64);
    }
    __syncthreads();
#pragma unroll
    for (int k2 = 0; k2 < 2; ++k2) {
      const int colb = k2 * 64 + cb;
      bf16x8 fah[2], fal[2], fbh[2], fbl[2];
#pragma unroll
      for (int m = 0; m < 2; ++m) {
        fah[m] = *(const bf16x8*)((char*)sAh + swz((arow + m * 16) * 128 + colb));
        fal[m] = *(const bf16x8*)((char*)sAl + swz((arow + m * 16) * 128 + colb));
      }
#pragma unroll
      for (int nn = 0; nn < 2; ++nn) {
        fbh[nn] = *(const bf16x8*)((char*)sBh + swz((brow + nn * 16) * 128 + colb));
        fbl[nn] = *(const bf16x8*)((char*)sBl + swz((brow + nn * 16) * 128 + colb));
      }
#pragma unroll
      for (int m = 0; m < 2; ++m)
#pragma unroll
        for (int nn = 0; nn < 2; ++nn) {
          acc[m][nn] = __builtin_amdgcn_mfma_f32_16x16x32_bf16(fah[m], fbh[nn], acc[m][nn], 0, 0, 0);
          acc[m][nn] = __builtin_amdgcn_mfma_f32_16x16x32_bf16(fah[m], fbl[nn], acc[m][nn], 0, 0, 0);
          acc[m][nn] = __builtin_amdgcn_mfma_f32_16x16x32_bf16(fal[m], fbh[nn], acc[m][nn], 0, 0, 0);
        }
    }
    __syncthreads();
  }

  // C/D layout: col = lane&15 (-> r), row = (lane>>4)*4 + j (-> oc)
  const int quarter = qbase + ks;       // 0..7
#pragma unroll
  for (int m = 0; m < 2; ++m)
#pragma unroll
    for (int nn = 0; nn < 2; ++nn) {
      const int r = no + wc * 32 + nn * 16 + (lane & 15);
      const int n = r >> 8, px = r & 255;
#pragma unroll
      for (int j = 0; j < 4; ++j) {
        const int oc = mo + wr * 32 + m * 16 + (lane >> 4) * 4 + j;
        part[(size_t)quarter * 262144 + ((size_t)n * 512 + oc) * 256 + px] = acc[m][nn][j];
      }
    }
}

// sum 8 K-slices + BN + ReLU -> t5
__global__ __launch_bounds__(256) void finalize5_kernel(
    const float* __restrict__ part, const float* __restrict__ bnf,
    const unsigned short* __restrict__ bnb, float* __restrict__ t5,
    const int* __restrict__ flag)
{
  int idx = blockIdx.x * 256 + threadIdx.x;   // 262144 total
  int oc = (idx >> 8) & 511;
  float s = 0.f;
#pragma unroll
  for (int q = 0; q < 8; ++q) s += part[(size_t)q * 262144 + idx];
  float g, b, m, v;
  if (flag[0]) {
    g = bf2f(bnb[oc]); b = bf2f(bnb[512 + oc]);
    m = bf2f(bnb[1024 + oc]); v = bf2f(bnb[1536 + oc]);
  } else {
    g = bnf[oc]; b = bnf[512 + oc]; m = bnf[1024 + oc]; v = bnf[1536 + oc];
  }
  float sc = g * rsqrtf(v + 1e-5f);
  float val = s * sc + (b - m * sc);
  t5[idx] = fmaxf(val, 0.f);
}

// ---------------- split-C 1x1 conv partials (vectorized + reg double-buffer) --------
// blockIdx.z = n*KS + kc; part[kc*(B*O*S) + (n*O + o)*S + s]
__global__ __launch_bounds__(256) void conv1x1_part_kernel(
    const float* __restrict__ Xf, const unsigned short* __restrict__ Xb,
    const float* __restrict__ Wf, const unsigned short* __restrict__ Wb,
    float* __restrict__ part, int C, int O, int S, int KS, int xf32,
    const int* __restrict__ flag)
{
  const int isbf = flag[0];
  const int xbf = xf32 ? 0 : isbf;
  const int tid = threadIdx.x;
  const int sg = tid & 15, og = tid >> 4;
  const int s0 = blockIdx.x * 64;
  const int o0 = blockIdx.y * 64;
  const int n  = blockIdx.z / KS;
  const int kc = blockIdx.z % KS;
  const int CC = C / KS;
  const int cbase = kc * CC;

  __shared__ float xs[16][64];
  __shared__ float wsT[16][68];

  // load map: X tile = 256 x float4 (16B/lane), W tile likewise
  const int xc  = tid >> 4;          // 0..15 channel within tile
  const int xs4 = (tid & 15) * 4;    // s offset
  const int wo  = tid >> 2;          // 0..63 o within tile
  const int wc4 = (tid & 3) * 4;     // c offset within tile
  const int owo = o0 + wo;
  const bool wok = (owo < O);

  float acc[4][4];
#pragma unroll
  for (int i = 0; i < 4; ++i)
#pragma unroll
    for (int j = 0; j < 4; ++j) acc[i][j] = 0.f;

  // ---- prefetch first tile into registers ----
  float4 xr, wr_;
  {
    const int c0 = cbase;
    if (xbf) {
      ushort4 u = *(const ushort4*)(Xb + ((size_t)n * C + c0 + xc) * S + s0 + xs4);
      xr.x = bf2f(u.x); xr.y = bf2f(u.y); xr.z = bf2f(u.z); xr.w = bf2f(u.w);
    } else {
      xr = *(const float4*)(Xf + ((size_t)n * C + c0 + xc) * S + s0 + xs4);
    }
    if (wok) {
      if (isbf) {
        ushort4 u = *(const ushort4*)(Wb + (size_t)owo * C + c0 + wc4);
        wr_.x = bf2f(u.x); wr_.y = bf2f(u.y); wr_.z = bf2f(u.z); wr_.w = bf2f(u.w);
      } else {
        wr_ = *(const float4*)(Wf + (size_t)owo * C + c0 + wc4);
      }
    } else { wr_.x = 0.f; wr_.y = 0.f; wr_.z = 0.f; wr_.w = 0.f; }
  }

  for (int c0 = cbase; c0 < cbase + CC; c0 += 16) {
    // write staged regs -> LDS
    *(float4*)&xs[xc][xs4] = xr;
    wsT[wc4 + 0][wo] = wr_.x;
    wsT[wc4 + 1][wo] = wr_.y;
    wsT[wc4 + 2][wo] = wr_.z;
    wsT[wc4 + 3][wo] = wr_.w;
    __syncthreads();
    // issue next-tile loads early; they fly under the FMA block
    if (c0 + 16 < cbase + CC) {
      const int c1 = c0 + 16;
      if (xbf) {
        ushort4 u = *(const ushort4*)(Xb + ((size_t)n * C + c1 + xc) * S + s0 + xs4);
        xr.x = bf2f(u.x); xr.y = bf2f(u.y); xr.z = bf2f(u.z); xr.w = bf2f(u.w);
      } else {
        xr = *(const float4*)(Xf + ((size_t)n * C + c1 + xc) * S + s0 + xs4);
      }
      if (wok) {
        if (isbf) {
          ushort4 u = *(const ushort4*)(Wb + (size_t)owo * C + c1 + wc4);
          wr_.x = bf2f(u.x); wr_.y = bf2f(u.y); wr_.z = bf2f(u.z); wr_.w = bf2f(u.w);
        } else {
          wr_ = *(const float4*)(Wf + (size_t)owo * C + c1 + wc4);
        }
      }
    }
#pragma unroll
    for (int c = 0; c < 16; ++c) {
      const float4 xv = *(const float4*)&xs[c][sg * 4];
      const float4 wv = *(const float4*)&wsT[c][og * 4];
      acc[0][0] = fmaf(wv.x, xv.x, acc[0][0]);
      acc[0][1] = fmaf(wv.x, xv.y, acc[0][1]);
      acc[0][2] = fmaf(wv.x, xv.z, acc[0][2]);
      acc[0][3] = fmaf(wv.x, xv.w, acc[0][3]);
      acc[1][0] = fmaf(wv.y, xv.x, acc[1][0]);
      acc[1][1] = fmaf(wv.y, xv.y, acc[1][1]);
      acc[1][2] = fmaf(wv.y, xv.z, acc[1][2]);
      acc[1][3] = fmaf(wv.y, xv.w, acc[1][3]);
      acc[2][0] = fmaf(wv.z, xv.x, acc[2][0]);
      acc[2][1] = fmaf(wv.z, xv.y, acc[2][1]);
      acc[2][2] = fmaf(wv.z, xv.z, acc[2][2]);
      acc[2][3] = fmaf(wv.z, xv.w, acc[2][3]);
      acc[3][0] = fmaf(wv.w, xv.x, acc[3][0]);
      acc[3][1] = fmaf(wv.w, xv.y, acc[3][1]);
      acc[3][2] = fmaf(wv.w, xv.z, acc[3][2]);
      acc[3][3] = fmaf(wv.w, xv.w, acc[3][3]);
    }
    __syncthreads();
  }

  const size_t BOS = (size_t)B * O * S;
#pragma unroll
  for (int i = 0; i < 4; ++i) {
    int o = o0 + og * 4 + i;
    if (o < O) {
      float4 r;
      r.x = acc[i][0]; r.y = acc[i][1]; r.z = acc[i][2]; r.w = acc[i][3];
      *(float4*)(part + (size_t)kc * BOS + ((size_t)n * O + o) * S + s0 + sg * 4) = r;
    }
  }
}

// sum KS partials + optional BN -> Y.  total = B*O*S
__global__ __launch_bounds__(256) void reduce_bn_kernel(
    const float* __restrict__ part, const float* __restrict__ bnf,
    const unsigned short* __restrict__ bnb, int hasbn,
    float* __restrict__ Y, int O, int S, int KS, int total,
    const int* __restrict__ flag)
{
  int idx = blockIdx.x * 256 + threadIdx.x;
  if (idx >= total) return;
  float s = 0.f;
  for (int kc = 0; kc < KS; ++kc) s += part[(size_t)kc * total + idx];
  float sc = 1.f, sh = 0.f;
  if (hasbn) {
    int o = (idx / S) % O;
    float g, b, m, v;
    if (flag[0]) {
      g = bf2f(bnb[o]); b = bf2f(bnb[O + o]);
      m = bf2f(bnb[2 * O + o]); v = bf2f(bnb[3 * O + o]);
    } else {
      g = bnf[o]; b = bnf[O + o]; m = bnf[2 * O + o]; v = bnf[3 * O + o];
    }
    sc = g * rsqrtf(v + 1e-5f);
    sh = b - m * sc;
  }
  Y[idx] = s * sc + sh;
}

// ---------------- bilinear 2x upsample, align_corners=True ----------------
__global__ __launch_bounds__(256) void upsample2x_kernel(
    const float* __restrict__ in, float* __restrict__ out,
    int h, int w, int total)
{
  int idx = blockIdx.x * 256 + threadIdx.x;
  if (idx >= total) return;
  const int Wd = 2 * w, Hd = 2 * h;
  int xo = idx % Wd;
  int t  = idx / Wd;
  int yo = t % Hd;
  int pl = t / Hd;
  const float rh = (float)(h - 1) / (float)(Hd - 1);
  const float rw = (float)(w - 1) / (float)(Wd - 1);
  float fy = yo * rh, fx = xo * rw;
  int y0 = (int)fy; if (y0 > h - 1) y0 = h - 1;
  int x0 = (int)fx; if (x0 > w - 1) x0 = w - 1;
  int y1 = min(y0 + 1, h - 1), x1 = min(x0 + 1, w - 1);
  float wy = fy - y0, wx = fx - x0;
  const float* p = in + (size_t)pl * h * w;
  float v00 = p[y0 * w + x0], v01 = p[y0 * w + x1];
  float v10 = p[y1 * w + x0], v11 = p[y1 * w + x1];
  out[idx] = (v00 * (1.f - wy) + v10 * wy) * (1.f - wx) +
             (v01 * (1.f - wy) + v11 * wy) * wx;
}

// ---- kd-split attention: partial dots.  pd[((kc*B + n)*9 + j)*S + p] ----
__global__ __launch_bounds__(256) void att_part_kernel(
    const float* __restrict__ q, const float* __restrict__ k,
    float* __restrict__ pd, int kd, int H, int Wd, int KC, int total)
{
  int idx = blockIdx.x * 256 + threadIdx.x;
  if (idx >= total) return;
  const int S = H * Wd;
  int p = idx % S;
  int t = idx / S;
  int n = t % B, kc = t / B;
  int x = p % Wd, y = p / Wd;
  int off[9]; bool ok[9];
#pragma unroll
  for (int j = 0; j < 9; ++j) {
    int dy = (j / 3) * 2 - 2, dx = (j % 3) * 2 - 2;
    int yy = y + dy, xx = x + dx;
    ok[j] = (yy >= 0 && yy < H && xx >= 0 && xx < Wd);
    off[j] = yy * Wd + xx;
  }
  float dot[9] = {0.f,0.f,0.f,0.f,0.f,0.f,0.f,0.f,0.f};
  const int cc = kd / KC;
  const int c0 = kc * cc;
  const float* qp = q + (size_t)n * kd * S + p;
  const float* kp = k + (size_t)n * kd * S;
  for (int c = c0; c < c0 + cc; ++c) {
    float qv = qp[(size_t)c * S];
    const float* kcp = kp + (size_t)c * S;
#pragma unroll
    for (int j = 0; j < 9; ++j)
      if (ok[j]) dot[j] = fmaf(qv, kcp[off[j]], dot[j]);
  }
  float* o = pd + ((size_t)(kc * B + n) * 9) * S + p;
#pragma unroll
  for (int j = 0; j < 9; ++j) o[(size_t)j * S] = dot[j];
}

// sum partial dots + softmax.  total = B*S
__global__ __launch_bounds__(256) void att_fin_kernel(
    const float* __restrict__ pd, float* __restrict__ att,
    int KC, int S, int total)
{
  int idx = blockIdx.x * 256 + threadIdx.x;
  if (idx >= total) return;
  int p = idx % S, n = idx / S;
  float dot[9] = {0.f,0.f,0.f,0.f,0.f,0.f,0.f,0.f,0.f};
  for (int kc = 0; kc < KC; ++kc) {
    const float* o = pd + ((size_t)(kc * B + n) * 9) * S + p;
#pragma unroll
    for (int j = 0; j < 9; ++j) dot[j] += o[(size_t)j * S];
  }
  float m = dot[0];
#pragma unroll
  for (int j = 1; j < 9; ++j) m = fmaxf(m, dot[j]);
  float e[9], ssum = 0.f;
#pragma unroll
  for (int j = 0; j < 9; ++j) { e[j] = __expf(dot[j] - m); ssum += e[j]; }
  float inv = 1.f / ssum;
#pragma unroll
  for (int j = 0; j < 9; ++j)
    att[((size_t)n * 9 + j) * S + p] = e[j] * inv;
}

// ---- tap-apply on PRE-UPSAMPLED prev: out[n,c,p] = sum_j att_j[p]*prevUp[n,c,p+D_j]
// 4 channels/thread; taps are dilation-2 shifts at the SAME resolution (coalesced).
__global__ __launch_bounds__(256) void apply_tap4_kernel(
    const float* __restrict__ att, const float* __restrict__ prevUp,
    float* __restrict__ out, int C, int H, int Wd, int total4)
{
  int idx = blockIdx.x * 256 + threadIdx.x;
  if (idx >= total4) return;
  const int S = H * Wd;
  const int CQ = C >> 2;
  int p = idx % S;
  int t = idx / S;
  int cq = t % CQ, n = t / CQ;
  int c0 = cq << 2;
  int x = p % Wd, y = p / Wd;
  const float* ap = att + (size_t)n * 9 * S + p;
  float a[9]; int off[9];
#pragma unroll
  for (int j = 0; j < 9; ++j) {
    int dy = (j / 3) * 2 - 2, dx = (j % 3) * 2 - 2;
    int yy = y + dy, xx = x + dx;
    bool ok = (yy >= 0 && yy < H && xx >= 0 && xx < Wd);
    a[j]   = ok ? ap[(size_t)j * S] : 0.f;
    off[j] = ok ? yy * Wd + xx : 0;
  }
  const float* pc = prevUp + ((size_t)n * C + c0) * S;
  float v0 = 0.f, v1 = 0.f, v2 = 0.f, v3 = 0.f;
#pragma unroll
  for (int j = 0; j < 9; ++j) {
    v0 = fmaf(pc[off[j]], a[j], v0);
    v1 = fmaf(pc[(size_t)S + off[j]], a[j], v1);
    v2 = fmaf(pc[(size_t)2 * S + off[j]], a[j], v2);
    v3 = fmaf(pc[(size_t)3 * S + off[j]], a[j], v3);
  }
  float* op = out + ((size_t)n * C + c0) * S + p;
  op[0] = v0;
  op[(size_t)S] = v1;
  op[(size_t)2 * S] = v2;
  op[(size_t)3 * S] = v3;
}

// ---- final on pre-upsampled v6up: d_out[n,o,p] = bias[o] + sum_j att_j*v6up[tap] ----
__global__ __launch_bounds__(256) void final_tap_kernel(
    const float* __restrict__ att, const float* __restrict__ v6up,
    const float* __restrict__ biasf, const unsigned short* __restrict__ biasb,
    float* __restrict__ outf, unsigned short* __restrict__ outb,
    int total, const int* __restrict__ flag)
{
  const int isbf = flag[0];
  int idx = blockIdx.x * 256 + threadIdx.x;
  if (idx >= total) return;
  const int H = 128, Wd = 128;
  const int S = H * Wd;
  int p = idx % S;
  int t = idx / S;
  int o = t % 19, n = t / 19;
  int x = p % Wd, y = p / Wd;
  const float* ap = att + (size_t)n * 9 * S + p;
  const float* pc = v6up + ((size_t)n * 19 + o) * S;
  float v = isbf ? bf2f(biasb[o]) : biasf[o];
#pragma unroll
  for (int j = 0; j < 9; ++j) {
    int dy = (j / 3) * 2 - 2, dx = (j % 3) * 2 - 2;
    int yy = y + dy, xx = x + dx;
    if (yy >= 0 && yy < H && xx >= 0 && xx < Wd)
      v = fmaf(ap[(size_t)j * S], pc[yy * Wd + xx], v);
  }
  if (isbf) outb[idx] = f2bf(v);
  else      outf[idx] = v;
}

typedef __hip_bfloat16 bf16;
typedef unsigned short u16;

extern "C" void kernel_launch(void* const* d_in, const int* in_sizes, int n_in,
                              void* d_out, int out_size, void* d_ws, size_t ws_size,
                              hipStream_t stream) {
  (void)in_sizes; (void)n_in; (void)out_size; (void)ws_size;

  float* ws = (float*)d_ws;   // fp32 workspace, 13,584,385 floats = 51.8 MiB
  // persistent stage buffers
  float* t5   = ws + 1048576;    //   262,144
  float* q4   = ws + 1310720;    //   262,144
  float* k4s  = ws + 1572864;    //    65,536
  float* k4   = ws + 1638400;    //   262,144
  float* att4 = ws + 1900544;    //    18,432
  float* o4   = ws + 1918976;    // 1,048,576
  float* q3   = ws + 2967552;    //   524,288
  float* k3s  = ws + 3491840;    //   131,072
  float* k3   = ws + 3622912;    //   524,288
  float* att3 = ws + 4147200;    //    73,728
  float* o3   = ws + 4220928;    // 4,194,304
  float* v6s  = ws + 8415232;    //   155,648
  float* q2   = ws + 8570880;    // 2,097,152
  float* k2s  = ws + 10668032;   //   524,288
  float* k2   = ws + 11192320;   // 2,097,152
  float* att2 = ws + 13289472;   //   294,912
  int*   flag = (int*)(ws + 13584384);

  // conv5 scratch: part8 (8 K-slices) + 4 split buffers; all dead after finalize5.
  float* part8 = ws + 1310720;                       // 2,097,152, ends 3,407,872
  u16* whi = (u16*)(ws + 4147200);                   // each 4,718,592 bf16
  u16* wlo = (u16*)(ws + 6506496);
  u16* xhi = (u16*)(ws + 8865792);
  u16* xlo = (u16*)(ws + 11225088);                  // ends 13,584,384

  // split-C / split-kd scratch (temporally dead regions at their use time):
  float* scQ4   = ws + 4220928;   // 2,097,152 (o3 region)
  float* scK4s  = ws + 6318080;   // 1,048,576 (o3 region)
  float* scQ3   = ws + 8570880;   // 2,097,152 (q2 region)
  float* scK3s  = ws + 11192320;  // 1,048,576 (k2 region)
  float* scQ2   = ws + 0;         // 4,194,304 (p5..att3 regions, all dead)
  float* scK2s  = ws + 11192320;  // 2,097,152 (k2 region)
  float* scV6   = ws + 8570880;   //   622,592 (q2 region, dead after att2)
  float* scAtt  = ws + 0;         // stage4: 294,912; stage3: 589,824; stage2: 2,359,296

  // pre-upsampled prev buffers (each alive only between its upsample and apply):
  float* t5up = ws + 0;           // 1,048,576 (scAtt4 dead after att_fin4)
  float* o4up = ws + 8415232;     // 4,194,304 (v6s/q2 regions, written later)
  float* v6up = ws + 0;           //   622,592 (scAtt2 dead after att_fin2)

  probe_kernel<<<1, 64, 0, stream>>>((const unsigned short*)d_in[0], flag);

  // ---- conv5 + BN + ReLU: split-bf16 MFMA GEMM, 2 phases x 4 K-slices ----
  for (int ph = 0; ph < 2; ++ph) {
    const int k0 = ph * 9216;
    split_w_kernel<<<4608, 256, 0, stream>>>(
        (const float*)d_in[7], (const u16*)d_in[7], whi, wlo, k0, flag);
    im2col_split_kernel<<<18432, 256, 0, stream>>>(
        (const float*)d_in[3], (const u16*)d_in[3], xhi, xlo, k0, flag);
    conv5_gemm_kernel<<<dim3(64, 4), 256, 0, stream>>>(whi, wlo, xhi, xlo, part8, ph * 4);
  }
  finalize5_kernel<<<1024, 256, 0, stream>>>(
      part8, (const float*)d_in[8], (const u16*)d_in[8], t5, flag);

  // ---- localUp stage 4 (H=32, kd=128): c_hi=c3, c_lo=c40, prev=t5 ----
  conv1x1_part_kernel<<<dim3(16, 2, B * 8), 256, 0, stream>>>(
      (const float*)d_in[2], (const u16*)d_in[2],
      (const float*)d_in[11], (const u16*)d_in[11], scQ4, 1024, 128, 1024, 8, 0, flag);
  reduce_bn_kernel<<<1024, 256, 0, stream>>>(
      scQ4, (const float*)d_in[12], (const u16*)d_in[12], 1, q4, 128, 1024, 8, 262144, flag);
  conv1x1_part_kernel<<<dim3(4, 2, B * 16), 256, 0, stream>>>(
      (const float*)d_in[6], (const u16*)d_in[6],
      (const float*)d_in[13], (const u16*)d_in[13], scK4s, 2048, 128, 256, 16, 0, flag);
  reduce_bn_kernel<<<256, 256, 0, stream>>>(
      scK4s, (const float*)d_in[14], (const u16*)d_in[14], 1, k4s, 128, 256, 16, 65536, flag);
  upsample2x_kernel<<<1024, 256, 0, stream>>>(k4s, k4, 16, 16, B * 128 * 1024);
  att_part_kernel<<<128, 256, 0, stream>>>(q4, k4, scAtt, 128, 32, 32, 16, 16 * B * 1024);
  att_fin_kernel<<<8, 256, 0, stream>>>(scAtt, att4, 16, 1024, B * 1024);
  upsample2x_kernel<<<4096, 256, 0, stream>>>(t5, t5up, 16, 16, B * 512 * 1024);
  apply_tap4_kernel<<<1024, 256, 0, stream>>>(att4, t5up, o4, 512, 32, 32, B * 128 * 1024);

  // ---- localUp stage 3 (H=64, kd=64): c_hi=c2, c_lo=c30, prev=o4 ----
  conv1x1_part_kernel<<<dim3(64, 1, B * 4), 256, 0, stream>>>(
      (const float*)d_in[1], (const u16*)d_in[1],
      (const float*)d_in[15], (const u16*)d_in[15], scQ3, 512, 64, 4096, 4, 0, flag);
  reduce_bn_kernel<<<2048, 256, 0, stream>>>(
      scQ3, (const float*)d_in[16], (const u16*)d_in[16], 1, q3, 64, 4096, 4, 524288, flag);
  conv1x1_part_kernel<<<dim3(16, 1, B * 8), 256, 0, stream>>>(
      (const float*)d_in[5], (const u16*)d_in[5],
      (const float*)d_in[17], (const u16*)d_in[17], scK3s, 1024, 64, 1024, 8, 0, flag);
  reduce_bn_kernel<<<512, 256, 0, stream>>>(
      scK3s, (const float*)d_in[18], (const u16*)d_in[18], 1, k3s, 64, 1024, 8, 131072, flag);
  upsample2x_kernel<<<2048, 256, 0, stream>>>(k3s, k3, 32, 32, B * 64 * 4096);
  att_part_kernel<<<256, 256, 0, stream>>>(q3, k3, scAtt, 64, 64, 64, 8, 8 * B * 4096);
  att_fin_kernel<<<32, 256, 0, stream>>>(scAtt, att3, 8, 4096, B * 4096);
  upsample2x_kernel<<<16384, 256, 0, stream>>>(o4, o4up, 32, 32, B * 512 * 4096);
  apply_tap4_kernel<<<4096, 256, 0, stream>>>(att3, o4up, o3, 512, 64, 64, B * 128 * 4096);

  // ---- localUp stage 2 (H=128, kd=64): c_hi=c1, c_lo=c2, prev=o3; conv6 commuted ----
  conv1x1_part_kernel<<<dim3(256, 1, B * 2), 256, 0, stream>>>(
      (const float*)d_in[0], (const u16*)d_in[0],
      (const float*)d_in[19], (const u16*)d_in[19], scQ2, 256, 64, 16384, 2, 0, flag);
  reduce_bn_kernel<<<8192, 256, 0, stream>>>(
      scQ2, (const float*)d_in[20], (const u16*)d_in[20], 1, q2, 64, 16384, 2, 2097152, flag);
  conv1x1_part_kernel<<<dim3(64, 1, B * 4), 256, 0, stream>>>(
      (const float*)d_in[1], (const u16*)d_in[1],
      (const float*)d_in[21], (const u16*)d_in[21], scK2s, 512, 64, 4096, 4, 0, flag);
  reduce_bn_kernel<<<2048, 256, 0, stream>>>(
      scK2s, (const float*)d_in[22], (const u16*)d_in[22], 1, k2s, 64, 4096, 4, 524288, flag);
  upsample2x_kernel<<<8192, 256, 0, stream>>>(k2s, k2, 64, 64, B * 64 * 16384);
  att_part_kernel<<<1024, 256, 0, stream>>>(q2, k2, scAtt, 64, 128, 128, 8, 8 * B * 16384);
  att_fin_kernel<<<128, 256, 0, stream>>>(scAtt, att2, 8, 16384, B * 16384);
  // v6s = conv6(o3) at 64x64 (conv6 commutes with upsample AND the 9-tap gather)
  conv1x1_part_kernel<<<dim3(64, 1, B * 4), 256, 0, stream>>>(
      o3, (const u16*)nullptr,
      (const float*)d_in[9], (const u16*)d_in[9], scV6, 512, 19, 4096, 4, 1, flag);
  reduce_bn_kernel<<<608, 256, 0, stream>>>(
      scV6, (const float*)nullptr, (const u16*)nullptr, 0, v6s, 19, 4096, 4, 155648, flag);
  upsample2x_kernel<<<2432, 256, 0, stream>>>(v6s, v6up, 64, 64, B * 19 * 16384);
  final_tap_kernel<<<2432, 256, 0, stream>>>(
      att2, v6up, (const float*)d_in[10], (const u16*)d_in[10],
      (float*)d_out, (u16*)d_out, B * 19 * 16384, flag);
}